// Round 1
// baseline (1796.721 us; speedup 1.0000x reference)
//
#include <hip/hip_runtime.h>
#include <math.h>

#define N_NODES   100000
#define N_EDGES   1600000
#define NDIM      64
#define H         128
#define NUM_LAYERS 3
#define NUM_CLASSES 6
#define NUM_GRAPHS 512
#define LN_EPS    1e-5f

// ---------- helpers ----------
__device__ __forceinline__ int idx_at(const int* raw, int is64, int i) {
    // little-endian: int64 low word at 2*i
    return is64 ? raw[2 * (long long)i] : raw[i];
}
__device__ __forceinline__ int enc_f(float f) {
    int i = __float_as_int(f);
    return i >= 0 ? i : (i ^ 0x7fffffff);
}
__device__ __forceinline__ float dec_f(int i) {
    return __int_as_float(i >= 0 ? i : (i ^ 0x7fffffff));
}

// ---------- dtype detection ----------
__global__ void k_detect(const int* eraw, const int* braw, int* flags) {
    if (threadIdx.x == 0 && blockIdx.x == 0) {
        int e64 = 1;
        for (int i = 1; i < 128; i += 2) if (eraw[i] != 0) { e64 = 0; break; }
        flags[0] = e64;
        // if int64: word N-1 is a high word (=0); if int32: last batch id (=511, nonzero)
        flags[1] = (braw[N_NODES - 1] == 0) ? 1 : 0;
    }
}

// ---------- init ----------
__global__ void k_init(int* deg, int* gmax, float* gsum, float* pooled) {
    int i = blockIdx.x * blockDim.x + threadIdx.x;
    if (i < N_NODES) deg[i] = 0;
    if (i < NUM_GRAPHS) { gmax[i] = INT_MIN; gsum[i] = 0.f; }
    if (i < NUM_GRAPHS * H) pooled[i] = 0.f;
}

__global__ void k_conv_batch(const int* braw, const int* flags, int* batch32) {
    int i = blockIdx.x * blockDim.x + threadIdx.x;
    if (i < N_NODES) batch32[i] = idx_at(braw, flags[1], i);
}

// ---------- CSR build ----------
__global__ void k_hist(const int* eraw, const int* flags, int* deg) {
    int e = blockIdx.x * blockDim.x + threadIdx.x;
    if (e < N_EDGES) {
        int d = idx_at(eraw, flags[0], N_EDGES + e);
        atomicAdd(&deg[d], 1);
    }
}

__global__ void k_scan1(const int* deg, int* rowptr, int* bsums) {
    __shared__ int sh[256];
    int tid = threadIdx.x;
    int i0 = blockIdx.x * 512 + tid * 2;
    int a = (i0 < N_NODES) ? deg[i0] : 0;
    int b = (i0 + 1 < N_NODES) ? deg[i0 + 1] : 0;
    int ts = a + b;
    sh[tid] = ts;
    __syncthreads();
    for (int off = 1; off < 256; off <<= 1) {
        int v = (tid >= off) ? sh[tid - off] : 0;
        __syncthreads();
        sh[tid] += v;
        __syncthreads();
    }
    int excl = sh[tid] - ts;
    if (i0 < N_NODES) rowptr[i0] = excl;
    if (i0 + 1 < N_NODES) rowptr[i0 + 1] = excl + a;
    if (tid == 255) bsums[blockIdx.x] = sh[255];
}

__global__ void k_scan2(int* bsums, int nb) {
    __shared__ int sh[256];
    int tid = threadIdx.x;
    int v = (tid < nb) ? bsums[tid] : 0;
    sh[tid] = v;
    __syncthreads();
    for (int off = 1; off < 256; off <<= 1) {
        int u = (tid >= off) ? sh[tid - off] : 0;
        __syncthreads();
        sh[tid] += u;
        __syncthreads();
    }
    if (tid < nb) bsums[tid] = sh[tid] - v;
}

__global__ void k_scan3(int* rowptr, const int* bsums, int* cursor) {
    int i = blockIdx.x * blockDim.x + threadIdx.x;
    if (i < N_NODES) {
        int r = rowptr[i] + bsums[i >> 9];
        rowptr[i] = r;
        cursor[i] = r;
    }
    if (i == 0) rowptr[N_NODES] = N_EDGES;
}

__global__ void k_scatter(const int* eraw, const int* flags, int* cursor, int* col) {
    int e = blockIdx.x * blockDim.x + threadIdx.x;
    if (e < N_EDGES) {
        int f = flags[0];
        int s = idx_at(eraw, f, e);
        int d = idx_at(eraw, f, N_EDGES + e);
        int pos = atomicAdd(&cursor[d], 1);
        col[pos] = s;
    }
}

// ---------- tiled fp32 GEMM: C[n,128] (+)= act(A[n,K] @ W[K,128] + bias) ----------
__global__ __launch_bounds__(256) void k_gemm(const float* __restrict__ A,
                                              const float* __restrict__ W,
                                              const float* __restrict__ bias,
                                              float* __restrict__ C,
                                              int nrows, int K, int act, int acc) {
    __shared__ float As[64][132];
    __shared__ float Ws[32][128];
    int tid = threadIdx.x;
    int row0 = blockIdx.x * 64;
    int kv = K >> 2;
    for (int idx = tid; idx < 64 * kv; idx += 256) {
        int r = idx / kv, c4 = idx % kv;
        float4 v = make_float4(0.f, 0.f, 0.f, 0.f);
        int gr = row0 + r;
        if (gr < nrows) v = *(const float4*)(A + (size_t)gr * K + c4 * 4);
        *(float4*)(&As[r][c4 * 4]) = v;
    }
    int tr = tid >> 4;        // 0..15 row-group
    int tc = tid & 15;        // 0..15 col-group
    int c0 = tc * 8;
    float accv[4][8];
#pragma unroll
    for (int i = 0; i < 4; ++i)
#pragma unroll
        for (int j = 0; j < 8; ++j) accv[i][j] = 0.f;

    for (int kc = 0; kc < K; kc += 32) {
        __syncthreads();
        for (int idx = tid; idx < 32 * 32; idx += 256) {
            int r = idx >> 5, c4 = idx & 31;
            *(float4*)(&Ws[r][c4 * 4]) = *(const float4*)(W + (size_t)(kc + r) * H + c4 * 4);
        }
        __syncthreads();
#pragma unroll 8
        for (int k = 0; k < 32; ++k) {
            float a0 = As[tr * 4 + 0][kc + k];
            float a1 = As[tr * 4 + 1][kc + k];
            float a2 = As[tr * 4 + 2][kc + k];
            float a3 = As[tr * 4 + 3][kc + k];
            float4 w0 = *(float4*)(&Ws[k][c0]);
            float4 w1 = *(float4*)(&Ws[k][c0 + 4]);
            accv[0][0] += a0 * w0.x; accv[0][1] += a0 * w0.y; accv[0][2] += a0 * w0.z; accv[0][3] += a0 * w0.w;
            accv[0][4] += a0 * w1.x; accv[0][5] += a0 * w1.y; accv[0][6] += a0 * w1.z; accv[0][7] += a0 * w1.w;
            accv[1][0] += a1 * w0.x; accv[1][1] += a1 * w0.y; accv[1][2] += a1 * w0.z; accv[1][3] += a1 * w0.w;
            accv[1][4] += a1 * w1.x; accv[1][5] += a1 * w1.y; accv[1][6] += a1 * w1.z; accv[1][7] += a1 * w1.w;
            accv[2][0] += a2 * w0.x; accv[2][1] += a2 * w0.y; accv[2][2] += a2 * w0.z; accv[2][3] += a2 * w0.w;
            accv[2][4] += a2 * w1.x; accv[2][5] += a2 * w1.y; accv[2][6] += a2 * w1.z; accv[2][7] += a2 * w1.w;
            accv[3][0] += a3 * w0.x; accv[3][1] += a3 * w0.y; accv[3][2] += a3 * w0.z; accv[3][3] += a3 * w0.w;
            accv[3][4] += a3 * w1.x; accv[3][5] += a3 * w1.y; accv[3][6] += a3 * w1.z; accv[3][7] += a3 * w1.w;
        }
    }
    float bv[8];
#pragma unroll
    for (int j = 0; j < 8; ++j) bv[j] = bias ? bias[c0 + j] : 0.f;
#pragma unroll
    for (int i = 0; i < 4; ++i) {
        int gr = row0 + tr * 4 + i;
        if (gr < nrows) {
            float out[8];
#pragma unroll
            for (int j = 0; j < 8; ++j) out[j] = accv[i][j] + bv[j];
            if (acc) {
                float4 e0 = *(float4*)(C + (size_t)gr * H + c0);
                float4 e1 = *(float4*)(C + (size_t)gr * H + c0 + 4);
                out[0] += e0.x; out[1] += e0.y; out[2] += e0.z; out[3] += e0.w;
                out[4] += e1.x; out[5] += e1.y; out[6] += e1.z; out[7] += e1.w;
            }
            if (act == 1) {
#pragma unroll
                for (int j = 0; j < 8; ++j) out[j] = fmaxf(out[j], 0.f);
            }
            *(float4*)(C + (size_t)gr * H + c0)     = make_float4(out[0], out[1], out[2], out[3]);
            *(float4*)(C + (size_t)gr * H + c0 + 4) = make_float4(out[4], out[5], out[6], out[7]);
        }
    }
}

// ---------- mean aggregation via CSR: one wave per node ----------
__global__ __launch_bounds__(256) void k_aggr(const float* __restrict__ h,
                                              const int* __restrict__ rowptr,
                                              const int* __restrict__ col,
                                              float* __restrict__ t) {
    int lane = threadIdx.x & 63;
    int node = blockIdx.x * 4 + (threadIdx.x >> 6);
    if (node >= N_NODES) return;
    int e0 = rowptr[node], e1 = rowptr[node + 1];
    float ax = 0.f, ay = 0.f;
    for (int e = e0; e < e1; ++e) {
        int s = col[e];
        float2 v = *(const float2*)(h + (size_t)s * H + lane * 2);
        ax += v.x; ay += v.y;
    }
    int d = e1 - e0;
    float inv = 1.0f / (float)(d > 1 ? d : 1);
    float2 o; o.x = ax * inv; o.y = ay * inv;
    *(float2*)(t + (size_t)node * H + lane * 2) = o;
}

// ---------- LayerNorm + ELU + residual: h = elu(LN(t)) + h ----------
__global__ __launch_bounds__(256) void k_ln(const float* __restrict__ t,
                                            float* __restrict__ h,
                                            const float* __restrict__ g,
                                            const float* __restrict__ b) {
    int lane = threadIdx.x & 63;
    int node = blockIdx.x * 4 + (threadIdx.x >> 6);
    if (node >= N_NODES) return;
    float2 v = *(const float2*)(t + (size_t)node * H + lane * 2);
    float s = v.x + v.y;
    float sq = v.x * v.x + v.y * v.y;
#pragma unroll
    for (int off = 32; off >= 1; off >>= 1) {
        s += __shfl_xor(s, off);
        sq += __shfl_xor(sq, off);
    }
    float mean = s * (1.0f / H);
    float var = sq * (1.0f / H) - mean * mean;
    float rstd = rsqrtf(var + LN_EPS);
    float2 gv = *(const float2*)(g + lane * 2);
    float2 bv = *(const float2*)(b + lane * 2);
    float y0 = (v.x - mean) * rstd * gv.x + bv.x;
    float y1 = (v.y - mean) * rstd * gv.y + bv.y;
    y0 = y0 > 0.f ? y0 : expf(y0) - 1.f;
    y1 = y1 > 0.f ? y1 : expf(y1) - 1.f;
    float2 hv = *(const float2*)(h + (size_t)node * H + lane * 2);
    float2 o; o.x = y0 + hv.x; o.y = y1 + hv.y;
    *(float2*)(h + (size_t)node * H + lane * 2) = o;
}

// ---------- gate MLP + segment max: one wave per node ----------
__global__ __launch_bounds__(256) void k_gate(const float* __restrict__ h,
                                              const float* __restrict__ w1,
                                              const float* __restrict__ b1,
                                              const float* __restrict__ w2,
                                              const float* __restrict__ b2,
                                              const int* __restrict__ batch32,
                                              float* __restrict__ gate,
                                              int* __restrict__ gmax) {
    __shared__ float W1s[H * 64];
    for (int idx = threadIdx.x; idx < H * 64; idx += 256) W1s[idx] = w1[idx];
    __syncthreads();
    int lane = threadIdx.x & 63;
    int node = blockIdx.x * 4 + (threadIdx.x >> 6);
    if (node >= N_NODES) return;
    float r0 = h[(size_t)node * H + lane];
    float r1 = h[(size_t)node * H + 64 + lane];
    float acc = b1[lane];
#pragma unroll 16
    for (int k = 0; k < 64; ++k) acc += __shfl(r0, k) * W1s[k * 64 + lane];
#pragma unroll 16
    for (int k = 0; k < 64; ++k) acc += __shfl(r1, k) * W1s[(64 + k) * 64 + lane];
    float p = fmaxf(acc, 0.f) * w2[lane];
#pragma unroll
    for (int off = 32; off >= 1; off >>= 1) p += __shfl_xor(p, off);
    if (lane == 0) {
        float gv = p + b2[0];
        gate[node] = gv;
        atomicMax(&gmax[batch32[node]], enc_f(gv));
    }
}

// ---------- eg = exp(gate - gmax); gsum += eg ----------
__global__ void k_eg(float* gate, const int* gmax, float* gsum, const int* batch32) {
    int n = blockIdx.x * blockDim.x + threadIdx.x;
    if (n < N_NODES) {
        int g = batch32[n];
        float e = expf(gate[n] - dec_f(gmax[g]));
        gate[n] = e;
        atomicAdd(&gsum[g], e);
    }
}

// ---------- pooled[g,:] += h[n,:] * eg[n]/gsum[g]  (sorted-batch run accumulation) ----------
#define POOL_NPB 256
__global__ __launch_bounds__(128) void k_pool(const float* __restrict__ h,
                                              const float* __restrict__ eg,
                                              const float* __restrict__ gsum,
                                              const int* __restrict__ batch32,
                                              float* __restrict__ pooled) {
    int c = threadIdx.x;
    int n0 = blockIdx.x * POOL_NPB;
    int n1 = n0 + POOL_NPB; if (n1 > N_NODES) n1 = N_NODES;
    if (n0 >= N_NODES) return;
    int cur = batch32[n0];
    float acc = 0.f;
    for (int n = n0; n < n1; ++n) {
        int g = batch32[n];
        if (g != cur) {
            atomicAdd(&pooled[(size_t)cur * H + c], acc);
            acc = 0.f; cur = g;
        }
        float w = eg[n] / gsum[g];
        acc += h[(size_t)n * H + c] * w;
    }
    atomicAdd(&pooled[(size_t)cur * H + c], acc);
}

// ---------- classifier: one wave per graph ----------
__global__ __launch_bounds__(64) void k_cls(const float* __restrict__ pooled,
                                            const float* __restrict__ w1,
                                            const float* __restrict__ b1,
                                            const float* __restrict__ w2,
                                            const float* __restrict__ b2,
                                            float* __restrict__ out) {
    __shared__ float sp[64];
    int g = blockIdx.x;
    int lane = threadIdx.x;
    float r0 = pooled[(size_t)g * H + lane];
    float r1 = pooled[(size_t)g * H + 64 + lane];
    float acc = b1[lane];
#pragma unroll 16
    for (int k = 0; k < 64; ++k) acc += __shfl(r0, k) * w1[k * 64 + lane];
#pragma unroll 16
    for (int k = 0; k < 64; ++k) acc += __shfl(r1, k) * w1[(64 + k) * 64 + lane];
    sp[lane] = fmaxf(acc, 0.f);
    __syncthreads();
    if (lane < NUM_CLASSES) {
        float o = b2[lane];
        for (int c = 0; c < 64; ++c) o += sp[c] * w2[c * NUM_CLASSES + lane];
        out[g * NUM_CLASSES + lane] = o;
    }
}

extern "C" void kernel_launch(void* const* d_in, const int* in_sizes, int n_in,
                              void* d_out, int out_size, void* d_ws, size_t ws_size,
                              hipStream_t stream) {
    const float* x       = (const float*)d_in[0];
    const int*   eraw    = (const int*)d_in[1];
    const int*   braw    = (const int*)d_in[2];
    const float* proj_w  = (const float*)d_in[3];
    const float* proj_b  = (const float*)d_in[4];
    const float* lin_l_w = (const float*)d_in[5];
    const float* lin_l_b = (const float*)d_in[6];
    const float* lin_r_w = (const float*)d_in[7];
    const float* ln_g    = (const float*)d_in[8];
    const float* ln_b    = (const float*)d_in[9];
    const float* gate_w1 = (const float*)d_in[10];
    const float* gate_b1 = (const float*)d_in[11];
    const float* gate_w2 = (const float*)d_in[12];
    const float* gate_b2 = (const float*)d_in[13];
    const float* cls_w1  = (const float*)d_in[14];
    const float* cls_b1  = (const float*)d_in[15];
    const float* cls_w2  = (const float*)d_in[16];
    const float* cls_b2  = (const float*)d_in[17];
    float* out = (float*)d_out;

    // workspace layout
    float* h      = (float*)d_ws;                 // N*H
    float* t      = h + (size_t)N_NODES * H;      // N*H
    float* gate   = t + (size_t)N_NODES * H;      // N
    float* gsum   = gate + N_NODES;               // 512
    float* pooled = gsum + NUM_GRAPHS;            // 512*H
    int* flags    = (int*)(pooled + NUM_GRAPHS * H); // 4
    int* col      = flags + 4;                    // E
    int* batch32  = col + N_EDGES;                // N
    int* deg      = batch32 + N_NODES;            // N
    int* rowptr   = deg + N_NODES;                // N+1
    int* cursor   = rowptr + N_NODES + 1;         // N
    int* bsums    = cursor + N_NODES;             // 256
    int* gmax     = bsums + 256;                  // 512

    const int nbN   = (N_NODES + 255) / 256;
    const int nbE   = (N_EDGES + 255) / 256;
    const int nbS   = (N_NODES + 511) / 512;      // 196
    const int nbW   = (N_NODES + 3) / 4;          // wave-per-node kernels
    const int nbG   = (N_NODES + 63) / 64;        // gemm row tiles

    k_detect<<<1, 1, 0, stream>>>(eraw, braw, flags);
    k_init<<<nbN, 256, 0, stream>>>(deg, gmax, gsum, pooled);
    k_conv_batch<<<nbN, 256, 0, stream>>>(braw, flags, batch32);
    k_hist<<<nbE, 256, 0, stream>>>(eraw, flags, deg);
    k_scan1<<<nbS, 256, 0, stream>>>(deg, rowptr, bsums);
    k_scan2<<<1, 256, 0, stream>>>(bsums, nbS);
    k_scan3<<<nbN, 256, 0, stream>>>(rowptr, bsums, cursor);
    k_scatter<<<nbE, 256, 0, stream>>>(eraw, flags, cursor, col);

    // h = relu(x @ proj_w + proj_b)
    k_gemm<<<nbG, 256, 0, stream>>>(x, proj_w, proj_b, h, N_NODES, NDIM, 1, 0);

    for (int l = 0; l < NUM_LAYERS; ++l) {
        const float* Wl = lin_l_w + (size_t)l * H * H;
        const float* bl = lin_l_b + (size_t)l * H;
        const float* Wr = lin_r_w + (size_t)l * H * H;
        const float* gl = ln_g + (size_t)l * H;
        const float* blb = ln_b + (size_t)l * H;
        k_aggr<<<nbW, 256, 0, stream>>>(h, rowptr, col, t);
        k_gemm<<<nbG, 256, 0, stream>>>(t, Wl, bl, t, N_NODES, H, 0, 0);   // t = t@Wl + bl (in-place)
        k_gemm<<<nbG, 256, 0, stream>>>(h, Wr, nullptr, t, N_NODES, H, 0, 1); // t += h@Wr
        k_ln<<<nbW, 256, 0, stream>>>(t, h, gl, blb);
    }

    k_gate<<<nbW, 256, 0, stream>>>(h, gate_w1, gate_b1, gate_w2, gate_b2, batch32, gate, gmax);
    k_eg<<<nbN, 256, 0, stream>>>(gate, gmax, gsum, batch32);
    k_pool<<<(N_NODES + POOL_NPB - 1) / POOL_NPB, 128, 0, stream>>>(h, gate, gsum, batch32, pooled);
    k_cls<<<NUM_GRAPHS, 64, 0, stream>>>(pooled, cls_w1, cls_b1, cls_w2, cls_b2, out);
}

// Round 2
// 1460.967 us; speedup vs baseline: 1.2298x; 1.2298x over previous
//
#include <hip/hip_runtime.h>
#include <math.h>

#define N_NODES   100000
#define N_EDGES   1600000
#define NDIM      64
#define H         128
#define NUM_LAYERS 3
#define NUM_CLASSES 6
#define NUM_GRAPHS 512
#define LN_EPS    1e-5f

// ---------- helpers ----------
__device__ __forceinline__ int idx_at(const int* raw, int is64, int i) {
    // little-endian: int64 low word at 2*i
    return is64 ? raw[2 * (long long)i] : raw[i];
}
__device__ __forceinline__ int enc_f(float f) {
    int i = __float_as_int(f);
    return i >= 0 ? i : (i ^ 0x7fffffff);
}
__device__ __forceinline__ float dec_f(int i) {
    return __int_as_float(i >= 0 ? i : (i ^ 0x7fffffff));
}

// ---------- dtype detection ----------
__global__ void k_detect(const int* eraw, const int* braw, int* flags) {
    if (threadIdx.x == 0 && blockIdx.x == 0) {
        int e64 = 1;
        for (int i = 1; i < 128; i += 2) if (eraw[i] != 0) { e64 = 0; break; }
        flags[0] = e64;
        flags[1] = (braw[N_NODES - 1] == 0) ? 1 : 0;
    }
}

// ---------- init ----------
__global__ void k_init(int* deg, int* gmax, float* gsum, float* pooled) {
    int i = blockIdx.x * blockDim.x + threadIdx.x;
    if (i < N_NODES) deg[i] = 0;
    if (i < NUM_GRAPHS) { gmax[i] = INT_MIN; gsum[i] = 0.f; }
    if (i < NUM_GRAPHS * H) pooled[i] = 0.f;
}

__global__ void k_conv_batch(const int* braw, const int* flags, int* batch32) {
    int i = blockIdx.x * blockDim.x + threadIdx.x;
    if (i < N_NODES) batch32[i] = idx_at(braw, flags[1], i);
}

// ---------- CSR build ----------
__global__ void k_hist(const int* eraw, const int* flags, int* deg) {
    int e = blockIdx.x * blockDim.x + threadIdx.x;
    if (e < N_EDGES) {
        int d = idx_at(eraw, flags[0], N_EDGES + e);
        atomicAdd(&deg[d], 1);
    }
}

__global__ void k_scan1(const int* deg, int* rowptr, int* bsums) {
    __shared__ int sh[256];
    int tid = threadIdx.x;
    int i0 = blockIdx.x * 512 + tid * 2;
    int a = (i0 < N_NODES) ? deg[i0] : 0;
    int b = (i0 + 1 < N_NODES) ? deg[i0 + 1] : 0;
    int ts = a + b;
    sh[tid] = ts;
    __syncthreads();
    for (int off = 1; off < 256; off <<= 1) {
        int v = (tid >= off) ? sh[tid - off] : 0;
        __syncthreads();
        sh[tid] += v;
        __syncthreads();
    }
    int excl = sh[tid] - ts;
    if (i0 < N_NODES) rowptr[i0] = excl;
    if (i0 + 1 < N_NODES) rowptr[i0 + 1] = excl + a;
    if (tid == 255) bsums[blockIdx.x] = sh[255];
}

__global__ void k_scan2(int* bsums, int nb) {
    __shared__ int sh[256];
    int tid = threadIdx.x;
    int v = (tid < nb) ? bsums[tid] : 0;
    sh[tid] = v;
    __syncthreads();
    for (int off = 1; off < 256; off <<= 1) {
        int u = (tid >= off) ? sh[tid - off] : 0;
        __syncthreads();
        sh[tid] += u;
        __syncthreads();
    }
    if (tid < nb) bsums[tid] = sh[tid] - v;
}

__global__ void k_scan3(int* rowptr, const int* bsums, int* cursor) {
    int i = blockIdx.x * blockDim.x + threadIdx.x;
    if (i < N_NODES) {
        int r = rowptr[i] + bsums[i >> 9];
        rowptr[i] = r;
        cursor[i] = r;
    }
    if (i == 0) rowptr[N_NODES] = N_EDGES;
}

__global__ void k_scatter(const int* eraw, const int* flags, int* cursor, int* col) {
    int e = blockIdx.x * blockDim.x + threadIdx.x;
    if (e < N_EDGES) {
        int f = flags[0];
        int s = idx_at(eraw, f, e);
        int d = idx_at(eraw, f, N_EDGES + e);
        int pos = atomicAdd(&cursor[d], 1);
        col[pos] = s;
    }
}

// ---------- generic tiled fp32 GEMM: C[n,COLS] = act(A[n,K] @ W[K,COLS] + bias) ----------
// chunked A staging (32-col chunks) keeps LDS small -> better occupancy
template<int COLS, int ACT>
__global__ __launch_bounds__(256) void k_gemm_t(const float* __restrict__ A,
                                                const float* __restrict__ W,
                                                const float* __restrict__ bias,
                                                float* __restrict__ C,
                                                int nrows, int K) {
    constexpr int CPT = COLS / 16;   // cols per thread: 8 (COLS=128) or 4 (COLS=64)
    __shared__ float As[64][36];
    __shared__ float Ws[32 * COLS];
    int tid = threadIdx.x;
    int row0 = blockIdx.x * 64;
    int tr = tid >> 4;      // 0..15 (4 rows each)
    int tc = tid & 15;      // 0..15
    int c0 = tc * CPT;
    float acc[4][CPT];
#pragma unroll
    for (int i = 0; i < 4; ++i)
#pragma unroll
        for (int j = 0; j < CPT; ++j) acc[i][j] = 0.f;

    for (int kc = 0; kc < K; kc += 32) {
        __syncthreads();
#pragma unroll
        for (int it = 0; it < 2; ++it) {
            int idx = tid + it * 256;
            int r = idx >> 3, c4 = idx & 7;
            int gr = row0 + r;
            float4 v = make_float4(0.f, 0.f, 0.f, 0.f);
            if (gr < nrows) v = *(const float4*)(A + (size_t)gr * K + kc + c4 * 4);
            *(float4*)(&As[r][c4 * 4]) = v;
        }
#pragma unroll
        for (int it = 0; it < COLS / 32; ++it) {
            int idx = tid + it * 256;
            int r = idx / (COLS / 4), c4 = idx % (COLS / 4);
            *(float4*)(&Ws[r * COLS + c4 * 4]) = *(const float4*)(W + (size_t)(kc + r) * COLS + c4 * 4);
        }
        __syncthreads();
#pragma unroll
        for (int k = 0; k < 32; ++k) {
            float a[4];
#pragma unroll
            for (int i = 0; i < 4; ++i) a[i] = As[tr * 4 + i][k];
            float w[CPT];
            float4 w0 = *(const float4*)(&Ws[k * COLS + c0]);
            w[0] = w0.x; w[1] = w0.y; w[2] = w0.z; w[3] = w0.w;
            if constexpr (CPT == 8) {
                float4 w1 = *(const float4*)(&Ws[k * COLS + c0 + 4]);
                w[4] = w1.x; w[5] = w1.y; w[6] = w1.z; w[7] = w1.w;
            }
#pragma unroll
            for (int i = 0; i < 4; ++i)
#pragma unroll
                for (int j = 0; j < CPT; ++j) acc[i][j] += a[i] * w[j];
        }
    }
    float bv[CPT];
#pragma unroll
    for (int j = 0; j < CPT; ++j) bv[j] = bias[c0 + j];
#pragma unroll
    for (int i = 0; i < 4; ++i) {
        int gr = row0 + tr * 4 + i;
        if (gr < nrows) {
            float o[CPT];
#pragma unroll
            for (int j = 0; j < CPT; ++j) {
                o[j] = acc[i][j] + bv[j];
                if (ACT) o[j] = fmaxf(o[j], 0.f);
            }
#pragma unroll
            for (int j = 0; j < CPT; j += 4)
                *(float4*)(C + (size_t)gr * COLS + c0 + j) = *(float4*)&o[j];
        }
    }
}

// ---------- fused SAGE layer: h = elu(LN(t@Wl + bl + h@Wr)) + h ----------
// K=256 pass over [t|h] @ [Wl;Wr], LN+ELU+residual in epilogue (block covers full row)
__global__ __launch_bounds__(256) void k_layer(const float* __restrict__ t,
                                               float* __restrict__ h,
                                               const float* __restrict__ Wl,
                                               const float* __restrict__ bl,
                                               const float* __restrict__ Wr,
                                               const float* __restrict__ g,
                                               const float* __restrict__ bb) {
    __shared__ float As[64][36];
    __shared__ float Ws[32 * 128];
    __shared__ float redS[64][17];
    __shared__ float redQ[64][17];
    __shared__ float redM[64];
    __shared__ float redR[64];
    int tid = threadIdx.x;
    int row0 = blockIdx.x * 64;
    int tr = tid >> 4;
    int tc = tid & 15;
    int c0 = tc * 8;
    float acc[4][8];
#pragma unroll
    for (int i = 0; i < 4; ++i)
#pragma unroll
        for (int j = 0; j < 8; ++j) acc[i][j] = 0.f;

    for (int kc = 0; kc < 256; kc += 32) {
        const float* Asrc = (kc < 128) ? t : h;
        const float* Wsrc = (kc < 128) ? Wl : Wr;
        int koff = (kc < 128) ? kc : (kc - 128);
        __syncthreads();
#pragma unroll
        for (int it = 0; it < 2; ++it) {
            int idx = tid + it * 256;
            int r = idx >> 3, c4 = idx & 7;
            int gr = row0 + r;
            float4 v = make_float4(0.f, 0.f, 0.f, 0.f);
            if (gr < N_NODES) v = *(const float4*)(Asrc + (size_t)gr * H + koff + c4 * 4);
            *(float4*)(&As[r][c4 * 4]) = v;
        }
#pragma unroll
        for (int it = 0; it < 4; ++it) {
            int idx = tid + it * 256;
            int r = idx >> 5, c4 = idx & 31;
            *(float4*)(&Ws[r * 128 + c4 * 4]) = *(const float4*)(Wsrc + (size_t)(koff + r) * H + c4 * 4);
        }
        __syncthreads();
#pragma unroll
        for (int k = 0; k < 32; ++k) {
            float a[4];
#pragma unroll
            for (int i = 0; i < 4; ++i) a[i] = As[tr * 4 + i][k];
            float4 w0 = *(const float4*)(&Ws[k * 128 + c0]);
            float4 w1 = *(const float4*)(&Ws[k * 128 + c0 + 4]);
            float w[8];
            w[0] = w0.x; w[1] = w0.y; w[2] = w0.z; w[3] = w0.w;
            w[4] = w1.x; w[5] = w1.y; w[6] = w1.z; w[7] = w1.w;
#pragma unroll
            for (int i = 0; i < 4; ++i)
#pragma unroll
                for (int j = 0; j < 8; ++j) acc[i][j] += a[i] * w[j];
        }
    }
    // + bias, row partial sums for LN
    float bv[8];
#pragma unroll
    for (int j = 0; j < 8; ++j) bv[j] = bl[c0 + j];
#pragma unroll
    for (int i = 0; i < 4; ++i) {
        float ps = 0.f, pq = 0.f;
#pragma unroll
        for (int j = 0; j < 8; ++j) {
            acc[i][j] += bv[j];
            ps += acc[i][j];
            pq += acc[i][j] * acc[i][j];
        }
        redS[tr * 4 + i][tc] = ps;
        redQ[tr * 4 + i][tc] = pq;
    }
    __syncthreads();
    if (tid < 64) {
        float s = 0.f, q = 0.f;
#pragma unroll
        for (int j = 0; j < 16; ++j) { s += redS[tid][j]; q += redQ[tid][j]; }
        float mean = s * (1.0f / H);
        float var = q * (1.0f / H) - mean * mean;
        redM[tid] = mean;
        redR[tid] = rsqrtf(var + LN_EPS);
    }
    __syncthreads();
    float gv[8], bbv[8];
#pragma unroll
    for (int j = 0; j < 8; ++j) { gv[j] = g[c0 + j]; bbv[j] = bb[c0 + j]; }
#pragma unroll
    for (int i = 0; i < 4; ++i) {
        int gr = row0 + tr * 4 + i;
        if (gr < N_NODES) {
            float mean = redM[tr * 4 + i];
            float rstd = redR[tr * 4 + i];
            float4 h0 = *(const float4*)(h + (size_t)gr * H + c0);
            float4 h1 = *(const float4*)(h + (size_t)gr * H + c0 + 4);
            float hv[8] = {h0.x, h0.y, h0.z, h0.w, h1.x, h1.y, h1.z, h1.w};
            float o[8];
#pragma unroll
            for (int j = 0; j < 8; ++j) {
                float y = (acc[i][j] - mean) * rstd * gv[j] + bbv[j];
                y = y > 0.f ? y : expf(y) - 1.f;
                o[j] = y + hv[j];
            }
            *(float4*)(h + (size_t)gr * H + c0)     = make_float4(o[0], o[1], o[2], o[3]);
            *(float4*)(h + (size_t)gr * H + c0 + 4) = make_float4(o[4], o[5], o[6], o[7]);
        }
    }
}

// ---------- mean aggregation via CSR: one wave per node ----------
__global__ __launch_bounds__(256) void k_aggr(const float* __restrict__ h,
                                              const int* __restrict__ rowptr,
                                              const int* __restrict__ col,
                                              float* __restrict__ t) {
    int lane = threadIdx.x & 63;
    int node = blockIdx.x * 4 + (threadIdx.x >> 6);
    if (node >= N_NODES) return;
    int e0 = rowptr[node], e1 = rowptr[node + 1];
    float ax = 0.f, ay = 0.f;
    for (int e = e0; e < e1; ++e) {
        int s = col[e];
        float2 v = *(const float2*)(h + (size_t)s * H + lane * 2);
        ax += v.x; ay += v.y;
    }
    int d = e1 - e0;
    float inv = 1.0f / (float)(d > 1 ? d : 1);
    float2 o; o.x = ax * inv; o.y = ay * inv;
    *(float2*)(t + (size_t)node * H + lane * 2) = o;
}

// ---------- gate reduce: gate[n] = p[n,:]·w2 + b2 ; segment max ----------
__global__ void k_gatered(const float* __restrict__ p, const float* __restrict__ w2,
                          const float* __restrict__ b2, const int* __restrict__ batch32,
                          float* __restrict__ gate, int* __restrict__ gmax) {
    int n = blockIdx.x * blockDim.x + threadIdx.x;
    if (n >= N_NODES) return;
    float s = 0.f;
#pragma unroll
    for (int j = 0; j < 64; j += 4) {
        float4 v = *(const float4*)(p + (size_t)n * 64 + j);
        float4 w = *(const float4*)(w2 + j);
        s += v.x * w.x + v.y * w.y + v.z * w.z + v.w * w.w;
    }
    float gv = s + b2[0];
    gate[n] = gv;
    atomicMax(&gmax[batch32[n]], enc_f(gv));
}

// ---------- eg = exp(gate - gmax); gsum += eg ----------
__global__ void k_eg(float* gate, const int* gmax, float* gsum, const int* batch32) {
    int n = blockIdx.x * blockDim.x + threadIdx.x;
    if (n < N_NODES) {
        int g = batch32[n];
        float e = expf(gate[n] - dec_f(gmax[g]));
        gate[n] = e;
        atomicAdd(&gsum[g], e);
    }
}

// ---------- pooled[g,:] += h[n,:] * eg[n]/gsum[g]  (sorted-batch run accumulation) ----------
#define POOL_NPB 256
__global__ __launch_bounds__(128) void k_pool(const float* __restrict__ h,
                                              const float* __restrict__ eg,
                                              const float* __restrict__ gsum,
                                              const int* __restrict__ batch32,
                                              float* __restrict__ pooled) {
    int c = threadIdx.x;
    int n0 = blockIdx.x * POOL_NPB;
    int n1 = n0 + POOL_NPB; if (n1 > N_NODES) n1 = N_NODES;
    if (n0 >= N_NODES) return;
    int cur = batch32[n0];
    float acc = 0.f;
    for (int n = n0; n < n1; ++n) {
        int g = batch32[n];
        if (g != cur) {
            atomicAdd(&pooled[(size_t)cur * H + c], acc);
            acc = 0.f; cur = g;
        }
        float w = eg[n] / gsum[g];
        acc += h[(size_t)n * H + c] * w;
    }
    atomicAdd(&pooled[(size_t)cur * H + c], acc);
}

// ---------- classifier: one wave per graph ----------
__global__ __launch_bounds__(64) void k_cls(const float* __restrict__ pooled,
                                            const float* __restrict__ w1,
                                            const float* __restrict__ b1,
                                            const float* __restrict__ w2,
                                            const float* __restrict__ b2,
                                            float* __restrict__ out) {
    __shared__ float sp[64];
    int g = blockIdx.x;
    int lane = threadIdx.x;
    float r0 = pooled[(size_t)g * H + lane];
    float r1 = pooled[(size_t)g * H + 64 + lane];
    float acc = b1[lane];
#pragma unroll 16
    for (int k = 0; k < 64; ++k) acc += __shfl(r0, k) * w1[k * 64 + lane];
#pragma unroll 16
    for (int k = 0; k < 64; ++k) acc += __shfl(r1, k) * w1[(64 + k) * 64 + lane];
    sp[lane] = fmaxf(acc, 0.f);
    __syncthreads();
    if (lane < NUM_CLASSES) {
        float o = b2[lane];
        for (int c = 0; c < 64; ++c) o += sp[c] * w2[c * NUM_CLASSES + lane];
        out[g * NUM_CLASSES + lane] = o;
    }
}

extern "C" void kernel_launch(void* const* d_in, const int* in_sizes, int n_in,
                              void* d_out, int out_size, void* d_ws, size_t ws_size,
                              hipStream_t stream) {
    const float* x       = (const float*)d_in[0];
    const int*   eraw    = (const int*)d_in[1];
    const int*   braw    = (const int*)d_in[2];
    const float* proj_w  = (const float*)d_in[3];
    const float* proj_b  = (const float*)d_in[4];
    const float* lin_l_w = (const float*)d_in[5];
    const float* lin_l_b = (const float*)d_in[6];
    const float* lin_r_w = (const float*)d_in[7];
    const float* ln_g    = (const float*)d_in[8];
    const float* ln_b    = (const float*)d_in[9];
    const float* gate_w1 = (const float*)d_in[10];
    const float* gate_b1 = (const float*)d_in[11];
    const float* gate_w2 = (const float*)d_in[12];
    const float* gate_b2 = (const float*)d_in[13];
    const float* cls_w1  = (const float*)d_in[14];
    const float* cls_b1  = (const float*)d_in[15];
    const float* cls_w2  = (const float*)d_in[16];
    const float* cls_b2  = (const float*)d_in[17];
    float* out = (float*)d_out;

    // workspace layout
    float* h      = (float*)d_ws;                 // N*H
    float* t      = h + (size_t)N_NODES * H;      // N*H   (p aliases t after layers)
    float* gate   = t + (size_t)N_NODES * H;      // N
    float* gsum   = gate + N_NODES;               // 512
    float* pooled = gsum + NUM_GRAPHS;            // 512*H
    int* flags    = (int*)(pooled + NUM_GRAPHS * H); // 4
    int* col      = flags + 4;                    // E
    int* batch32  = col + N_EDGES;                // N
    int* deg      = batch32 + N_NODES;            // N
    int* rowptr   = deg + N_NODES;                // N+1
    int* cursor   = rowptr + N_NODES + 1;         // N
    int* bsums    = cursor + N_NODES;             // 256
    int* gmax     = bsums + 256;                  // 512
    float* p      = t;                            // N*64, reuses t (free after layers)

    const int nbN   = (N_NODES + 255) / 256;
    const int nbE   = (N_EDGES + 255) / 256;
    const int nbS   = (N_NODES + 511) / 512;      // 196
    const int nbW   = (N_NODES + 3) / 4;          // wave-per-node kernels
    const int nbG   = (N_NODES + 63) / 64;        // gemm row tiles

    k_detect<<<1, 1, 0, stream>>>(eraw, braw, flags);
    k_init<<<nbN, 256, 0, stream>>>(deg, gmax, gsum, pooled);
    k_conv_batch<<<nbN, 256, 0, stream>>>(braw, flags, batch32);
    k_hist<<<nbE, 256, 0, stream>>>(eraw, flags, deg);
    k_scan1<<<nbS, 256, 0, stream>>>(deg, rowptr, bsums);
    k_scan2<<<1, 256, 0, stream>>>(bsums, nbS);
    k_scan3<<<nbN, 256, 0, stream>>>(rowptr, bsums, cursor);
    k_scatter<<<nbE, 256, 0, stream>>>(eraw, flags, cursor, col);

    // h = relu(x @ proj_w + proj_b)
    k_gemm_t<128, 1><<<nbG, 256, 0, stream>>>(x, proj_w, proj_b, h, N_NODES, NDIM);

    for (int l = 0; l < NUM_LAYERS; ++l) {
        const float* Wl  = lin_l_w + (size_t)l * H * H;
        const float* bl  = lin_l_b + (size_t)l * H;
        const float* Wr  = lin_r_w + (size_t)l * H * H;
        const float* gl  = ln_g + (size_t)l * H;
        const float* blb = ln_b + (size_t)l * H;
        k_aggr<<<nbW, 256, 0, stream>>>(h, rowptr, col, t);
        k_layer<<<nbG, 256, 0, stream>>>(t, h, Wl, bl, Wr, gl, blb);
    }

    // gate = relu(h@gate_w1 + b1) @ gate_w2 + b2, then segment softmax-pool
    k_gemm_t<64, 1><<<nbG, 256, 0, stream>>>(h, gate_w1, gate_b1, p, N_NODES, H);
    k_gatered<<<nbN, 256, 0, stream>>>(p, gate_w2, gate_b2, batch32, gate, gmax);
    k_eg<<<nbN, 256, 0, stream>>>(gate, gmax, gsum, batch32);
    k_pool<<<(N_NODES + POOL_NPB - 1) / POOL_NPB, 128, 0, stream>>>(h, gate, gsum, batch32, pooled);
    k_cls<<<NUM_GRAPHS, 64, 0, stream>>>(pooled, cls_w1, cls_b1, cls_w2, cls_b2, out);
}

// Round 3
// 1231.259 us; speedup vs baseline: 1.4593x; 1.1866x over previous
//
#include <hip/hip_runtime.h>
#include <hip/hip_fp16.h>
#include <math.h>

#define N_NODES   100000
#define N_EDGES   1600000
#define NDIM      64
#define H         128
#define NUM_LAYERS 3
#define NUM_CLASSES 6
#define NUM_GRAPHS 512
#define LN_EPS    1e-5f

// ---------- helpers ----------
__device__ __forceinline__ int idx_at(const int* raw, int is64, int i) {
    return is64 ? raw[2 * (long long)i] : raw[i];
}
__device__ __forceinline__ int enc_f(float f) {
    int i = __float_as_int(f);
    return i >= 0 ? i : (i ^ 0x7fffffff);
}
__device__ __forceinline__ float dec_f(int i) {
    return __int_as_float(i >= 0 ? i : (i ^ 0x7fffffff));
}

// ---------- dtype detection ----------
__global__ void k_detect(const int* eraw, const int* braw, int* flags) {
    if (threadIdx.x == 0 && blockIdx.x == 0) {
        int e64 = 1;
        for (int i = 1; i < 128; i += 2) if (eraw[i] != 0) { e64 = 0; break; }
        flags[0] = e64;
        flags[1] = (braw[N_NODES - 1] == 0) ? 1 : 0;
    }
}

// ---------- init ----------
__global__ void k_init(int* deg, int* gmax, float* gsum, float* pooled) {
    int i = blockIdx.x * blockDim.x + threadIdx.x;
    if (i < N_NODES) deg[i] = 0;
    if (i < NUM_GRAPHS) { gmax[i] = INT_MIN; gsum[i] = 0.f; }
    if (i < NUM_GRAPHS * H) pooled[i] = 0.f;
}

__global__ void k_conv_batch(const int* braw, const int* flags, int* batch32) {
    int i = blockIdx.x * blockDim.x + threadIdx.x;
    if (i < N_NODES) batch32[i] = idx_at(braw, flags[1], i);
}

// ---------- CSR build ----------
__global__ void k_hist(const int* eraw, const int* flags, int* deg) {
    int e = blockIdx.x * blockDim.x + threadIdx.x;
    if (e < N_EDGES) {
        int d = idx_at(eraw, flags[0], N_EDGES + e);
        atomicAdd(&deg[d], 1);
    }
}

__global__ void k_scan1(const int* deg, int* rowptr, int* bsums) {
    __shared__ int sh[256];
    int tid = threadIdx.x;
    int i0 = blockIdx.x * 512 + tid * 2;
    int a = (i0 < N_NODES) ? deg[i0] : 0;
    int b = (i0 + 1 < N_NODES) ? deg[i0 + 1] : 0;
    int ts = a + b;
    sh[tid] = ts;
    __syncthreads();
    for (int off = 1; off < 256; off <<= 1) {
        int v = (tid >= off) ? sh[tid - off] : 0;
        __syncthreads();
        sh[tid] += v;
        __syncthreads();
    }
    int excl = sh[tid] - ts;
    if (i0 < N_NODES) rowptr[i0] = excl;
    if (i0 + 1 < N_NODES) rowptr[i0 + 1] = excl + a;
    if (tid == 255) bsums[blockIdx.x] = sh[255];
}

__global__ void k_scan2(int* bsums, int nb) {
    __shared__ int sh[256];
    int tid = threadIdx.x;
    int v = (tid < nb) ? bsums[tid] : 0;
    sh[tid] = v;
    __syncthreads();
    for (int off = 1; off < 256; off <<= 1) {
        int u = (tid >= off) ? sh[tid - off] : 0;
        __syncthreads();
        sh[tid] += u;
        __syncthreads();
    }
    if (tid < nb) bsums[tid] = sh[tid] - v;
}

__global__ void k_scan3(int* rowptr, const int* bsums, int* cursor) {
    int i = blockIdx.x * blockDim.x + threadIdx.x;
    if (i < N_NODES) {
        int r = rowptr[i] + bsums[i >> 9];
        rowptr[i] = r;
        cursor[i] = r;
    }
    if (i == 0) rowptr[N_NODES] = N_EDGES;
}

__global__ void k_scatter(const int* eraw, const int* flags, int* cursor, int* col) {
    int e = blockIdx.x * blockDim.x + threadIdx.x;
    if (e < N_EDGES) {
        int f = flags[0];
        int s = idx_at(eraw, f, e);
        int d = idx_at(eraw, f, N_EDGES + e);
        int pos = atomicAdd(&cursor[d], 1);
        col[pos] = s;
    }
}

// ---------- generic tiled fp32 GEMM: C = act(A[n,K] @ W[K,COLS] + bias) ----------
// A-tile stored TRANSPOSED in LDS (As_t[k][r], stride 68 = 16B-aligned) so the
// per-k A-fragment is a single ds_read_b128 instead of 4 scalar reads.
template<int COLS, int ACT>
__global__ __launch_bounds__(256) void k_gemm_t(const float* __restrict__ A,
                                                const float* __restrict__ W,
                                                const float* __restrict__ bias,
                                                float* __restrict__ C,
                                                __half* __restrict__ C16,
                                                int nrows, int K) {
    constexpr int CPT = COLS / 16;   // 8 (COLS=128) or 4 (COLS=64)
    __shared__ float As_t[32][68];
    __shared__ float Ws[32 * COLS];
    int tid = threadIdx.x;
    int row0 = blockIdx.x * 64;
    int tr = tid >> 4;      // 0..15 (4 rows each)
    int tc = tid & 15;      // 0..15
    int c0 = tc * CPT;
    float acc[4][CPT];
#pragma unroll
    for (int i = 0; i < 4; ++i)
#pragma unroll
        for (int j = 0; j < CPT; ++j) acc[i][j] = 0.f;

    for (int kc = 0; kc < K; kc += 32) {
        __syncthreads();
#pragma unroll
        for (int it = 0; it < 2; ++it) {
            int idx = tid + it * 256;
            int r = idx >> 3, c4 = idx & 7;
            int gr = row0 + r;
            float4 v = make_float4(0.f, 0.f, 0.f, 0.f);
            if (gr < nrows) v = *(const float4*)(A + (size_t)gr * K + kc + c4 * 4);
            As_t[c4 * 4 + 0][r] = v.x;
            As_t[c4 * 4 + 1][r] = v.y;
            As_t[c4 * 4 + 2][r] = v.z;
            As_t[c4 * 4 + 3][r] = v.w;
        }
#pragma unroll
        for (int it = 0; it < COLS / 32; ++it) {
            int idx = tid + it * 256;
            int r = idx / (COLS / 4), c4 = idx % (COLS / 4);
            *(float4*)(&Ws[r * COLS + c4 * 4]) = *(const float4*)(W + (size_t)(kc + r) * COLS + c4 * 4);
        }
        __syncthreads();
#pragma unroll
        for (int k = 0; k < 32; ++k) {
            float4 a4 = *(const float4*)(&As_t[k][tr * 4]);
            float a[4] = {a4.x, a4.y, a4.z, a4.w};
            float w[CPT];
            float4 w0 = *(const float4*)(&Ws[k * COLS + c0]);
            w[0] = w0.x; w[1] = w0.y; w[2] = w0.z; w[3] = w0.w;
            if constexpr (CPT == 8) {
                float4 w1 = *(const float4*)(&Ws[k * COLS + c0 + 4]);
                w[4] = w1.x; w[5] = w1.y; w[6] = w1.z; w[7] = w1.w;
            }
#pragma unroll
            for (int i = 0; i < 4; ++i)
#pragma unroll
                for (int j = 0; j < CPT; ++j) acc[i][j] += a[i] * w[j];
        }
    }
    float bv[CPT];
#pragma unroll
    for (int j = 0; j < CPT; ++j) bv[j] = bias[c0 + j];
#pragma unroll
    for (int i = 0; i < 4; ++i) {
        int gr = row0 + tr * 4 + i;
        if (gr < nrows) {
            float o[CPT];
#pragma unroll
            for (int j = 0; j < CPT; ++j) {
                o[j] = acc[i][j] + bv[j];
                if (ACT) o[j] = fmaxf(o[j], 0.f);
            }
#pragma unroll
            for (int j = 0; j < CPT; j += 4)
                *(float4*)(C + (size_t)gr * COLS + c0 + j) = *(float4*)&o[j];
            if (C16) {
                __half2 p[CPT / 2];
#pragma unroll
                for (int j = 0; j < CPT; j += 2)
                    p[j / 2] = __floats2half2_rn(o[j], o[j + 1]);
                if constexpr (CPT == 8)
                    *(float4*)(C16 + (size_t)gr * COLS + c0) = *(float4*)p;
                else
                    *(float2*)(C16 + (size_t)gr * COLS + c0) = *(float2*)p;
            }
        }
    }
}

// ---------- fused SAGE layer: h = elu(LN(t@Wl + bl + h@Wr)) + h ; also h16 = fp16(h) ----------
__global__ __launch_bounds__(256) void k_layer(const float* __restrict__ t,
                                               float* __restrict__ h,
                                               __half* __restrict__ h16,
                                               const float* __restrict__ Wl,
                                               const float* __restrict__ bl,
                                               const float* __restrict__ Wr,
                                               const float* __restrict__ g,
                                               const float* __restrict__ bb) {
    __shared__ float As_t[32][68];
    __shared__ float Ws[32 * 128];
    __shared__ float redS[64][17];
    __shared__ float redQ[64][17];
    __shared__ float redM[64];
    __shared__ float redR[64];
    int tid = threadIdx.x;
    int row0 = blockIdx.x * 64;
    int tr = tid >> 4;
    int tc = tid & 15;
    int c0 = tc * 8;
    float acc[4][8];
#pragma unroll
    for (int i = 0; i < 4; ++i)
#pragma unroll
        for (int j = 0; j < 8; ++j) acc[i][j] = 0.f;

    for (int kc = 0; kc < 256; kc += 32) {
        const float* Asrc = (kc < 128) ? t : h;
        const float* Wsrc = (kc < 128) ? Wl : Wr;
        int koff = (kc < 128) ? kc : (kc - 128);
        __syncthreads();
#pragma unroll
        for (int it = 0; it < 2; ++it) {
            int idx = tid + it * 256;
            int r = idx >> 3, c4 = idx & 7;
            int gr = row0 + r;
            float4 v = make_float4(0.f, 0.f, 0.f, 0.f);
            if (gr < N_NODES) v = *(const float4*)(Asrc + (size_t)gr * H + koff + c4 * 4);
            As_t[c4 * 4 + 0][r] = v.x;
            As_t[c4 * 4 + 1][r] = v.y;
            As_t[c4 * 4 + 2][r] = v.z;
            As_t[c4 * 4 + 3][r] = v.w;
        }
#pragma unroll
        for (int it = 0; it < 4; ++it) {
            int idx = tid + it * 256;
            int r = idx >> 5, c4 = idx & 31;
            *(float4*)(&Ws[r * 128 + c4 * 4]) = *(const float4*)(Wsrc + (size_t)(koff + r) * H + c4 * 4);
        }
        __syncthreads();
#pragma unroll
        for (int k = 0; k < 32; ++k) {
            float4 a4 = *(const float4*)(&As_t[k][tr * 4]);
            float a[4] = {a4.x, a4.y, a4.z, a4.w};
            float4 w0 = *(const float4*)(&Ws[k * 128 + c0]);
            float4 w1 = *(const float4*)(&Ws[k * 128 + c0 + 4]);
            float w[8];
            w[0] = w0.x; w[1] = w0.y; w[2] = w0.z; w[3] = w0.w;
            w[4] = w1.x; w[5] = w1.y; w[6] = w1.z; w[7] = w1.w;
#pragma unroll
            for (int i = 0; i < 4; ++i)
#pragma unroll
                for (int j = 0; j < 8; ++j) acc[i][j] += a[i] * w[j];
        }
    }
    float bv[8];
#pragma unroll
    for (int j = 0; j < 8; ++j) bv[j] = bl[c0 + j];
#pragma unroll
    for (int i = 0; i < 4; ++i) {
        float ps = 0.f, pq = 0.f;
#pragma unroll
        for (int j = 0; j < 8; ++j) {
            acc[i][j] += bv[j];
            ps += acc[i][j];
            pq += acc[i][j] * acc[i][j];
        }
        redS[tr * 4 + i][tc] = ps;
        redQ[tr * 4 + i][tc] = pq;
    }
    __syncthreads();
    if (tid < 64) {
        float s = 0.f, q = 0.f;
#pragma unroll
        for (int j = 0; j < 16; ++j) { s += redS[tid][j]; q += redQ[tid][j]; }
        float mean = s * (1.0f / H);
        float var = q * (1.0f / H) - mean * mean;
        redM[tid] = mean;
        redR[tid] = rsqrtf(var + LN_EPS);
    }
    __syncthreads();
    float gv[8], bbv[8];
#pragma unroll
    for (int j = 0; j < 8; ++j) { gv[j] = g[c0 + j]; bbv[j] = bb[c0 + j]; }
#pragma unroll
    for (int i = 0; i < 4; ++i) {
        int gr = row0 + tr * 4 + i;
        if (gr < N_NODES) {
            float mean = redM[tr * 4 + i];
            float rstd = redR[tr * 4 + i];
            float4 h0 = *(const float4*)(h + (size_t)gr * H + c0);
            float4 h1 = *(const float4*)(h + (size_t)gr * H + c0 + 4);
            float hv[8] = {h0.x, h0.y, h0.z, h0.w, h1.x, h1.y, h1.z, h1.w};
            float o[8];
#pragma unroll
            for (int j = 0; j < 8; ++j) {
                float y = (acc[i][j] - mean) * rstd * gv[j] + bbv[j];
                y = y > 0.f ? y : expf(y) - 1.f;
                o[j] = y + hv[j];
            }
            *(float4*)(h + (size_t)gr * H + c0)     = make_float4(o[0], o[1], o[2], o[3]);
            *(float4*)(h + (size_t)gr * H + c0 + 4) = make_float4(o[4], o[5], o[6], o[7]);
            __half2 p[4];
#pragma unroll
            for (int j = 0; j < 8; j += 2) p[j / 2] = __floats2half2_rn(o[j], o[j + 1]);
            *(float4*)(h16 + (size_t)gr * H + c0) = *(float4*)p;
        }
    }
}

// ---------- mean aggregation via CSR from fp16 copy: one wave per node ----------
__global__ __launch_bounds__(256) void k_aggr(const __half* __restrict__ h16,
                                              const int* __restrict__ rowptr,
                                              const int* __restrict__ col,
                                              float* __restrict__ t) {
    int lane = threadIdx.x & 63;
    int node = blockIdx.x * 4 + (threadIdx.x >> 6);
    if (node >= N_NODES) return;
    int e0 = rowptr[node], e1 = rowptr[node + 1];
    float ax0 = 0.f, ay0 = 0.f, ax1 = 0.f, ay1 = 0.f;
    int e = e0;
    for (; e + 1 < e1; e += 2) {
        int s0 = col[e], s1 = col[e + 1];
        __half2 v0 = *(const __half2*)(h16 + (size_t)s0 * H + lane * 2);
        __half2 v1 = *(const __half2*)(h16 + (size_t)s1 * H + lane * 2);
        float2 f0 = __half22float2(v0);
        float2 f1 = __half22float2(v1);
        ax0 += f0.x; ay0 += f0.y;
        ax1 += f1.x; ay1 += f1.y;
    }
    if (e < e1) {
        int s0 = col[e];
        __half2 v0 = *(const __half2*)(h16 + (size_t)s0 * H + lane * 2);
        float2 f0 = __half22float2(v0);
        ax0 += f0.x; ay0 += f0.y;
    }
    int d = e1 - e0;
    float inv = 1.0f / (float)(d > 1 ? d : 1);
    float2 o; o.x = (ax0 + ax1) * inv; o.y = (ay0 + ay1) * inv;
    *(float2*)(t + (size_t)node * H + lane * 2) = o;
}

// ---------- gate reduce: gate[n] = p[n,:]·w2 + b2 ; segment max ----------
__global__ void k_gatered(const float* __restrict__ p, const float* __restrict__ w2,
                          const float* __restrict__ b2, const int* __restrict__ batch32,
                          float* __restrict__ gate, int* __restrict__ gmax) {
    int n = blockIdx.x * blockDim.x + threadIdx.x;
    if (n >= N_NODES) return;
    float s = 0.f;
#pragma unroll
    for (int j = 0; j < 64; j += 4) {
        float4 v = *(const float4*)(p + (size_t)n * 64 + j);
        float4 w = *(const float4*)(w2 + j);
        s += v.x * w.x + v.y * w.y + v.z * w.z + v.w * w.w;
    }
    float gv = s + b2[0];
    gate[n] = gv;
    atomicMax(&gmax[batch32[n]], enc_f(gv));
}

// ---------- eg = exp(gate - gmax); gsum += eg ----------
__global__ void k_eg(float* gate, const int* gmax, float* gsum, const int* batch32) {
    int n = blockIdx.x * blockDim.x + threadIdx.x;
    if (n < N_NODES) {
        int g = batch32[n];
        float e = expf(gate[n] - dec_f(gmax[g]));
        gate[n] = e;
        atomicAdd(&gsum[g], e);
    }
}

// ---------- pooled[g,:] += h[n,:] * eg[n]/gsum[g]  (sorted-batch run accumulation) ----------
#define POOL_NPB 256
__global__ __launch_bounds__(128) void k_pool(const float* __restrict__ h,
                                              const float* __restrict__ eg,
                                              const float* __restrict__ gsum,
                                              const int* __restrict__ batch32,
                                              float* __restrict__ pooled) {
    int c = threadIdx.x;
    int n0 = blockIdx.x * POOL_NPB;
    int n1 = n0 + POOL_NPB; if (n1 > N_NODES) n1 = N_NODES;
    if (n0 >= N_NODES) return;
    int cur = batch32[n0];
    float acc = 0.f;
    for (int n = n0; n < n1; ++n) {
        int g = batch32[n];
        if (g != cur) {
            atomicAdd(&pooled[(size_t)cur * H + c], acc);
            acc = 0.f; cur = g;
        }
        float w = eg[n] / gsum[g];
        acc += h[(size_t)n * H + c] * w;
    }
    atomicAdd(&pooled[(size_t)cur * H + c], acc);
}

// ---------- classifier: one wave per graph ----------
__global__ __launch_bounds__(64) void k_cls(const float* __restrict__ pooled,
                                            const float* __restrict__ w1,
                                            const float* __restrict__ b1,
                                            const float* __restrict__ w2,
                                            const float* __restrict__ b2,
                                            float* __restrict__ out) {
    __shared__ float sp[64];
    int g = blockIdx.x;
    int lane = threadIdx.x;
    float r0 = pooled[(size_t)g * H + lane];
    float r1 = pooled[(size_t)g * H + 64 + lane];
    float acc = b1[lane];
#pragma unroll 16
    for (int k = 0; k < 64; ++k) acc += __shfl(r0, k) * w1[k * 64 + lane];
#pragma unroll 16
    for (int k = 0; k < 64; ++k) acc += __shfl(r1, k) * w1[(64 + k) * 64 + lane];
    sp[lane] = fmaxf(acc, 0.f);
    __syncthreads();
    if (lane < NUM_CLASSES) {
        float o = b2[lane];
        for (int c = 0; c < 64; ++c) o += sp[c] * w2[c * NUM_CLASSES + lane];
        out[g * NUM_CLASSES + lane] = o;
    }
}

extern "C" void kernel_launch(void* const* d_in, const int* in_sizes, int n_in,
                              void* d_out, int out_size, void* d_ws, size_t ws_size,
                              hipStream_t stream) {
    const float* x       = (const float*)d_in[0];
    const int*   eraw    = (const int*)d_in[1];
    const int*   braw    = (const int*)d_in[2];
    const float* proj_w  = (const float*)d_in[3];
    const float* proj_b  = (const float*)d_in[4];
    const float* lin_l_w = (const float*)d_in[5];
    const float* lin_l_b = (const float*)d_in[6];
    const float* lin_r_w = (const float*)d_in[7];
    const float* ln_g    = (const float*)d_in[8];
    const float* ln_b    = (const float*)d_in[9];
    const float* gate_w1 = (const float*)d_in[10];
    const float* gate_b1 = (const float*)d_in[11];
    const float* gate_w2 = (const float*)d_in[12];
    const float* gate_b2 = (const float*)d_in[13];
    const float* cls_w1  = (const float*)d_in[14];
    const float* cls_b1  = (const float*)d_in[15];
    const float* cls_w2  = (const float*)d_in[16];
    const float* cls_b2  = (const float*)d_in[17];
    float* out = (float*)d_out;

    // workspace layout
    float* h      = (float*)d_ws;                 // N*H
    float* t      = h + (size_t)N_NODES * H;      // N*H   (p aliases t after layers)
    float* gate   = t + (size_t)N_NODES * H;      // N
    float* gsum   = gate + N_NODES;               // 512
    float* pooled = gsum + NUM_GRAPHS;            // 512*H
    __half* h16   = (__half*)(pooled + NUM_GRAPHS * H); // N*H halves
    int* flags    = (int*)(h16 + (size_t)N_NODES * H);  // 4
    int* col      = flags + 4;                    // E
    int* batch32  = col + N_EDGES;                // N
    int* deg      = batch32 + N_NODES;            // N
    int* rowptr   = deg + N_NODES;                // N+1
    int* cursor   = rowptr + N_NODES + 1;         // N
    int* bsums    = cursor + N_NODES;             // 256
    int* gmax     = bsums + 256;                  // 512
    float* p      = t;                            // N*64, reuses t (free after layers)

    const int nbN   = (N_NODES + 255) / 256;
    const int nbE   = (N_EDGES + 255) / 256;
    const int nbS   = (N_NODES + 511) / 512;
    const int nbW   = (N_NODES + 3) / 4;
    const int nbG   = (N_NODES + 63) / 64;

    k_detect<<<1, 1, 0, stream>>>(eraw, braw, flags);
    k_init<<<nbN, 256, 0, stream>>>(deg, gmax, gsum, pooled);
    k_conv_batch<<<nbN, 256, 0, stream>>>(braw, flags, batch32);
    k_hist<<<nbE, 256, 0, stream>>>(eraw, flags, deg);
    k_scan1<<<nbS, 256, 0, stream>>>(deg, rowptr, bsums);
    k_scan2<<<1, 256, 0, stream>>>(bsums, nbS);
    k_scan3<<<nbN, 256, 0, stream>>>(rowptr, bsums, cursor);
    k_scatter<<<nbE, 256, 0, stream>>>(eraw, flags, cursor, col);

    // h = relu(x @ proj_w + proj_b), also h16
    k_gemm_t<128, 1><<<nbG, 256, 0, stream>>>(x, proj_w, proj_b, h, h16, N_NODES, NDIM);

    for (int l = 0; l < NUM_LAYERS; ++l) {
        const float* Wl  = lin_l_w + (size_t)l * H * H;
        const float* bl  = lin_l_b + (size_t)l * H;
        const float* Wr  = lin_r_w + (size_t)l * H * H;
        const float* gl  = ln_g + (size_t)l * H;
        const float* blb = ln_b + (size_t)l * H;
        k_aggr<<<nbW, 256, 0, stream>>>(h16, rowptr, col, t);
        k_layer<<<nbG, 256, 0, stream>>>(t, h, h16, Wl, bl, Wr, gl, blb);
    }

    // gate = relu(h@gate_w1 + b1) @ gate_w2 + b2, then segment softmax-pool
    k_gemm_t<64, 1><<<nbG, 256, 0, stream>>>(h, gate_w1, gate_b1, p, (__half*)nullptr, N_NODES, H);
    k_gatered<<<nbN, 256, 0, stream>>>(p, gate_w2, gate_b2, batch32, gate, gmax);
    k_eg<<<nbN, 256, 0, stream>>>(gate, gmax, gsum, batch32);
    k_pool<<<(N_NODES + POOL_NPB - 1) / POOL_NPB, 128, 0, stream>>>(h, gate, gsum, batch32, pooled);
    k_cls<<<NUM_GRAPHS, 64, 0, stream>>>(pooled, cls_w1, cls_b1, cls_w2, cls_b2, out);
}

// Round 4
// 1017.240 us; speedup vs baseline: 1.7663x; 1.2104x over previous
//
#include <hip/hip_runtime.h>
#include <hip/hip_fp16.h>
#include <math.h>

#define N_NODES   100000
#define N_EDGES   1600000
#define NDIM      64
#define H         128
#define NUM_LAYERS 3
#define NUM_CLASSES 6
#define NUM_GRAPHS 512
#define LN_EPS    1e-5f
#define NBKT      391           // ceil(N_NODES / 256)
#define SCAP      5376          // phase-B LDS col capacity (bucket mean 4092, std 64)

typedef _Float16 f16x8 __attribute__((ext_vector_type(8)));
typedef float    f32x4 __attribute__((ext_vector_type(4)));

// ---------- helpers ----------
__device__ __forceinline__ int idx_at(const int* raw, int is64, int i) {
    return is64 ? raw[2 * (long long)i] : raw[i];
}
__device__ __forceinline__ int enc_f(float f) {
    int i = __float_as_int(f);
    return i >= 0 ? i : (i ^ 0x7fffffff);
}
__device__ __forceinline__ float dec_f(int i) {
    return __int_as_float(i >= 0 ? i : (i ^ 0x7fffffff));
}

// ---------- dtype detection ----------
__global__ void k_detect(const int* eraw, const int* braw, int* flags) {
    if (threadIdx.x == 0 && blockIdx.x == 0) {
        int e64 = 1;
        for (int i = 1; i < 128; i += 2) if (eraw[i] != 0) { e64 = 0; break; }
        flags[0] = e64;
        flags[1] = (braw[N_NODES - 1] == 0) ? 1 : 0;
    }
}

// ---------- init ----------
__global__ void k_init(int* gmax, float* gsum, float* pooled, int* bcnt) {
    int i = blockIdx.x * blockDim.x + threadIdx.x;
    if (i < NUM_GRAPHS) { gmax[i] = INT_MIN; gsum[i] = 0.f; }
    if (i < NUM_GRAPHS * H) pooled[i] = 0.f;
    if (i < 512) bcnt[i] = 0;
}

__global__ void k_conv_batch(const int* braw, const int* flags, int* batch32) {
    int i = blockIdx.x * blockDim.x + threadIdx.x;
    if (i < N_NODES) batch32[i] = idx_at(braw, flags[1], i);
}

// ---------- bucket histogram (512 buckets by dst>>8), LDS-aggregated ----------
__global__ __launch_bounds__(256) void k_bhist(const int* eraw, const int* flags, int* bcnt) {
    __shared__ int c[512];
    int tid = threadIdx.x;
    for (int i = tid; i < 512; i += 256) c[i] = 0;
    __syncthreads();
    int f = flags[0];
    int stride = gridDim.x * 256;
    for (int e = blockIdx.x * 256 + tid; e < N_EDGES; e += stride) {
        int d = idx_at(eraw, f, N_EDGES + e);
        atomicAdd(&c[d >> 8], 1);
    }
    __syncthreads();
    for (int i = tid; i < 512; i += 256) if (c[i]) atomicAdd(&bcnt[i], c[i]);
}

// ---------- scan of 512 bucket counts -> boff[513], bcursor ----------
__global__ void k_bscan(const int* bcnt, int* boff, int* bcursor) {
    __shared__ int sh[512];
    int tid = threadIdx.x;     // 512 threads
    int v = bcnt[tid];
    sh[tid] = v;
    __syncthreads();
    for (int off = 1; off < 512; off <<= 1) {
        int u = (tid >= off) ? sh[tid - off] : 0;
        __syncthreads();
        sh[tid] += u;
        __syncthreads();
    }
    int excl = sh[tid] - v;
    boff[tid] = excl;
    bcursor[tid] = excl;
    if (tid == 511) boff[512] = sh[511];
}

// ---------- phase A: scatter packed records into bucket-contiguous regions ----------
#define EPB 4096
__global__ __launch_bounds__(256) void k_bucket(const int* eraw, const int* flags,
                                                int* bcursor, unsigned int* br) {
    __shared__ int cnt[512];
    __shared__ int lcur[512];
    int tid = threadIdx.x;
    int f = flags[0];
    int base = blockIdx.x * EPB;
    int se[16], de[16];
#pragma unroll
    for (int j = 0; j < 16; ++j) {
        int e = base + j * 256 + tid;
        if (e < N_EDGES) {
            se[j] = idx_at(eraw, f, e);
            de[j] = idx_at(eraw, f, N_EDGES + e);
        } else de[j] = -1;
    }
    for (int i = tid; i < 512; i += 256) cnt[i] = 0;
    __syncthreads();
#pragma unroll
    for (int j = 0; j < 16; ++j)
        if (de[j] >= 0) atomicAdd(&cnt[de[j] >> 8], 1);
    __syncthreads();
    for (int i = tid; i < 512; i += 256)
        lcur[i] = cnt[i] ? atomicAdd(&bcursor[i], cnt[i]) : 0;
    __syncthreads();
#pragma unroll
    for (int j = 0; j < 16; ++j)
        if (de[j] >= 0) {
            int pos = atomicAdd(&lcur[de[j] >> 8], 1);
            br[pos] = ((unsigned int)(de[j] & 255) << 24) | (unsigned int)se[j];
        }
}

// ---------- per-bucket degree count ----------
__global__ __launch_bounds__(256) void k_bdeg(const unsigned int* br, const int* boff, int* deg) {
    __shared__ int d256[256];
    int b = blockIdx.x;
    int tid = threadIdx.x;
    d256[tid] = 0;
    __syncthreads();
    int lo = boff[b], hi = boff[b + 1];
    for (int i = lo + tid; i < hi; i += 256)
        atomicAdd(&d256[br[i] >> 24], 1);
    __syncthreads();
    int node = (b << 8) + tid;
    if (node < N_NODES) deg[node] = d256[tid];
}

// ---------- scans over deg -> rowptr ----------
__global__ void k_scan1(const int* deg, int* rowptr, int* bsums) {
    __shared__ int sh[256];
    int tid = threadIdx.x;
    int i0 = blockIdx.x * 512 + tid * 2;
    int a = (i0 < N_NODES) ? deg[i0] : 0;
    int b = (i0 + 1 < N_NODES) ? deg[i0 + 1] : 0;
    int ts = a + b;
    sh[tid] = ts;
    __syncthreads();
    for (int off = 1; off < 256; off <<= 1) {
        int v = (tid >= off) ? sh[tid - off] : 0;
        __syncthreads();
        sh[tid] += v;
        __syncthreads();
    }
    int excl = sh[tid] - ts;
    if (i0 < N_NODES) rowptr[i0] = excl;
    if (i0 + 1 < N_NODES) rowptr[i0 + 1] = excl + a;
    if (tid == 255) bsums[blockIdx.x] = sh[255];
}

__global__ void k_scan2(int* bsums, int nb) {
    __shared__ int sh[256];
    int tid = threadIdx.x;
    int v = (tid < nb) ? bsums[tid] : 0;
    sh[tid] = v;
    __syncthreads();
    for (int off = 1; off < 256; off <<= 1) {
        int u = (tid >= off) ? sh[tid - off] : 0;
        __syncthreads();
        sh[tid] += u;
        __syncthreads();
    }
    if (tid < nb) bsums[tid] = sh[tid] - v;
}

__global__ void k_scan3(int* rowptr, const int* bsums, int* cursor) {
    int i = blockIdx.x * blockDim.x + threadIdx.x;
    if (i < N_NODES) {
        int r = rowptr[i] + bsums[i >> 9];
        rowptr[i] = r;
        cursor[i] = r;
    }
    if (i == 0) rowptr[N_NODES] = N_EDGES;
}

// ---------- phase B: per-bucket fine scatter via LDS staging, coalesced writeout ----------
__global__ __launch_bounds__(256) void k_scatter2(const unsigned int* br, const int* boff,
                                                  const int* rowptr, int* cursor, int* col) {
    __shared__ int lcur[256];
    __shared__ int cbuf[SCAP];
    int b = blockIdx.x;
    int tid = threadIdx.x;
    int lo = boff[b], hi = boff[b + 1];
    int wsize = hi - lo;
    int node = (b << 8) + tid;
    lcur[tid] = rowptr[node < N_NODES ? node : N_NODES] - lo;
    __syncthreads();
    if (wsize <= SCAP) {
        for (int i = lo + tid; i < hi; i += 256) {
            unsigned int r = br[i];
            int p = atomicAdd(&lcur[r >> 24], 1);
            cbuf[p] = (int)(r & 0xFFFFFF);
        }
        __syncthreads();
        for (int j = tid; j < wsize; j += 256) col[lo + j] = cbuf[j];
    } else {
        // fallback (statistically unreachable): direct global scatter
        for (int i = lo + tid; i < hi; i += 256) {
            unsigned int r = br[i];
            int d = (b << 8) + (int)(r >> 24);
            int p = atomicAdd(&cursor[d], 1);
            col[p] = (int)(r & 0xFFFFFF);
        }
    }
}

// ---------- weight prep: W16t[l][n*256+k] = fp16 of (k<128 ? Wl[k][n] : Wr[k-128][n]) ----------
__global__ void k_prepw(const float* __restrict__ lin_l_w, const float* __restrict__ lin_r_w,
                        __half* __restrict__ W16t) {
    int i = blockIdx.x * 256 + threadIdx.x;
    if (i >= NUM_LAYERS * 128 * 256) return;
    int l = i >> 15;
    int rem = i & 32767;
    int n = rem >> 8;
    int k = rem & 255;
    float v = (k < 128) ? lin_l_w[(size_t)l * 16384 + k * 128 + n]
                        : lin_r_w[(size_t)l * 16384 + (k - 128) * 128 + n];
    W16t[(size_t)l * 32768 + n * 256 + k] = __float2half(v);
}

// ---------- generic tiled fp32 GEMM: C = act(A[n,K] @ W[K,COLS] + bias), optional fp16 copy ----------
template<int COLS, int ACT>
__global__ __launch_bounds__(256) void k_gemm_t(const float* __restrict__ A,
                                                const float* __restrict__ W,
                                                const float* __restrict__ bias,
                                                float* __restrict__ C,
                                                __half* __restrict__ C16,
                                                int nrows, int K) {
    constexpr int CPT = COLS / 16;
    __shared__ float As_t[32][68];
    __shared__ float Ws[32 * COLS];
    int tid = threadIdx.x;
    int row0 = blockIdx.x * 64;
    int tr = tid >> 4;
    int tc = tid & 15;
    int c0 = tc * CPT;
    float acc[4][CPT];
#pragma unroll
    for (int i = 0; i < 4; ++i)
#pragma unroll
        for (int j = 0; j < CPT; ++j) acc[i][j] = 0.f;

    for (int kc = 0; kc < K; kc += 32) {
        __syncthreads();
#pragma unroll
        for (int it = 0; it < 2; ++it) {
            int idx = tid + it * 256;
            int r = idx >> 3, c4 = idx & 7;
            int gr = row0 + r;
            float4 v = make_float4(0.f, 0.f, 0.f, 0.f);
            if (gr < nrows) v = *(const float4*)(A + (size_t)gr * K + kc + c4 * 4);
            As_t[c4 * 4 + 0][r] = v.x;
            As_t[c4 * 4 + 1][r] = v.y;
            As_t[c4 * 4 + 2][r] = v.z;
            As_t[c4 * 4 + 3][r] = v.w;
        }
#pragma unroll
        for (int it = 0; it < COLS / 32; ++it) {
            int idx = tid + it * 256;
            int r = idx / (COLS / 4), c4 = idx % (COLS / 4);
            *(float4*)(&Ws[r * COLS + c4 * 4]) = *(const float4*)(W + (size_t)(kc + r) * COLS + c4 * 4);
        }
        __syncthreads();
#pragma unroll
        for (int k = 0; k < 32; ++k) {
            float4 a4 = *(const float4*)(&As_t[k][tr * 4]);
            float a[4] = {a4.x, a4.y, a4.z, a4.w};
            float w[CPT];
            float4 w0 = *(const float4*)(&Ws[k * COLS + c0]);
            w[0] = w0.x; w[1] = w0.y; w[2] = w0.z; w[3] = w0.w;
            if constexpr (CPT == 8) {
                float4 w1 = *(const float4*)(&Ws[k * COLS + c0 + 4]);
                w[4] = w1.x; w[5] = w1.y; w[6] = w1.z; w[7] = w1.w;
            }
#pragma unroll
            for (int i = 0; i < 4; ++i)
#pragma unroll
                for (int j = 0; j < CPT; ++j) acc[i][j] += a[i] * w[j];
        }
    }
    float bv[CPT];
#pragma unroll
    for (int j = 0; j < CPT; ++j) bv[j] = bias[c0 + j];
#pragma unroll
    for (int i = 0; i < 4; ++i) {
        int gr = row0 + tr * 4 + i;
        if (gr < nrows) {
            float o[CPT];
#pragma unroll
            for (int j = 0; j < CPT; ++j) {
                o[j] = acc[i][j] + bv[j];
                if (ACT) o[j] = fmaxf(o[j], 0.f);
            }
#pragma unroll
            for (int j = 0; j < CPT; j += 4)
                *(float4*)(C + (size_t)gr * COLS + c0 + j) = *(float4*)&o[j];
            if (C16) {
                __half2 p[CPT / 2];
#pragma unroll
                for (int j = 0; j < CPT; j += 2)
                    p[j / 2] = __floats2half2_rn(o[j], o[j + 1]);
                if constexpr (CPT == 8)
                    *(float4*)(C16 + (size_t)gr * COLS + c0) = *(float4*)p;
                else
                    *(float2*)(C16 + (size_t)gr * COLS + c0) = *(float2*)p;
            }
        }
    }
}

// ---------- MFMA fused SAGE layer: h = elu(LN([t16|h16]@[Wl;Wr] + bl)) + h ----------
// per-wave 16x128 tile, A from fp16 global rows, B from W16t[n][k]; no LDS, no barriers.
__global__ __launch_bounds__(256) void k_layer_mfma(const __half* __restrict__ t16,
                                                    float* __restrict__ h,
                                                    __half* __restrict__ h16,
                                                    const __half* __restrict__ W16t,
                                                    const float* __restrict__ bl,
                                                    const float* __restrict__ g,
                                                    const float* __restrict__ bb) {
    int tid = threadIdx.x;
    int wave = tid >> 6, lane = tid & 63;
    int s = lane & 15, quad = lane >> 4;
    int row0 = blockIdx.x * 64 + wave * 16;
    int arow = row0 + s;
    if (arow >= N_NODES) arow = N_NODES - 1;

    f32x4 acc[8];
#pragma unroll
    for (int c = 0; c < 8; ++c) acc[c] = (f32x4){0.f, 0.f, 0.f, 0.f};

#pragma unroll
    for (int kc = 0; kc < 256; kc += 32) {
        const __half* asrc = (kc < 128) ? t16 : h16;
        int koff = kc & 127;
        f16x8 afrag = *(const f16x8*)(asrc + (size_t)arow * H + koff + quad * 8);
#pragma unroll
        for (int c = 0; c < 8; ++c) {
            f16x8 bfrag = *(const f16x8*)(W16t + (size_t)(c * 16 + s) * 256 + kc + quad * 8);
            acc[c] = __builtin_amdgcn_mfma_f32_16x16x32_f16(afrag, bfrag, acc[c], 0, 0, 0);
        }
    }
    // C/D layout: row_in_tile = quad*4 + i, col = c*16 + s
    float y[8][4];
    float sm[4] = {0.f, 0.f, 0.f, 0.f}, sq[4] = {0.f, 0.f, 0.f, 0.f};
#pragma unroll
    for (int c = 0; c < 8; ++c) {
        float bv = bl[c * 16 + s];
#pragma unroll
        for (int i = 0; i < 4; ++i) {
            float v = acc[c][i] + bv;
            y[c][i] = v;
            sm[i] += v;
            sq[i] += v * v;
        }
    }
#pragma unroll
    for (int off = 1; off < 16; off <<= 1) {
#pragma unroll
        for (int i = 0; i < 4; ++i) {
            sm[i] += __shfl_xor(sm[i], off);
            sq[i] += __shfl_xor(sq[i], off);
        }
    }
    float mean[4], rstd[4];
#pragma unroll
    for (int i = 0; i < 4; ++i) {
        mean[i] = sm[i] * (1.0f / H);
        float var = sq[i] * (1.0f / H) - mean[i] * mean[i];
        rstd[i] = rsqrtf(var + LN_EPS);
    }
#pragma unroll
    for (int i = 0; i < 4; ++i) {
        int r = row0 + quad * 4 + i;
        if (r < N_NODES) {
#pragma unroll
            for (int c = 0; c < 8; ++c) {
                int colj = c * 16 + s;
                float yv = (y[c][i] - mean[i]) * rstd[i] * g[colj] + bb[colj];
                yv = yv > 0.f ? yv : expf(yv) - 1.f;
                float o = yv + h[(size_t)r * H + colj];
                h[(size_t)r * H + colj] = o;
                h16[(size_t)r * H + colj] = __float2half(o);
            }
        }
    }
}

// ---------- mean aggregation via CSR from fp16, writes fp16 t ----------
__global__ __launch_bounds__(256) void k_aggr(const __half* __restrict__ h16,
                                              const int* __restrict__ rowptr,
                                              const int* __restrict__ col,
                                              __half* __restrict__ t16) {
    int lane = threadIdx.x & 63;
    int node = blockIdx.x * 4 + (threadIdx.x >> 6);
    if (node >= N_NODES) return;
    int e0 = rowptr[node], e1 = rowptr[node + 1];
    float ax0 = 0.f, ay0 = 0.f, ax1 = 0.f, ay1 = 0.f;
    int e = e0;
    for (; e + 1 < e1; e += 2) {
        int s0 = col[e], s1 = col[e + 1];
        float2 f0 = __half22float2(*(const __half2*)(h16 + (size_t)s0 * H + lane * 2));
        float2 f1 = __half22float2(*(const __half2*)(h16 + (size_t)s1 * H + lane * 2));
        ax0 += f0.x; ay0 += f0.y;
        ax1 += f1.x; ay1 += f1.y;
    }
    if (e < e1) {
        float2 f0 = __half22float2(*(const __half2*)(h16 + (size_t)col[e] * H + lane * 2));
        ax0 += f0.x; ay0 += f0.y;
    }
    int d = e1 - e0;
    float inv = 1.0f / (float)(d > 1 ? d : 1);
    *(__half2*)(t16 + (size_t)node * H + lane * 2) =
        __floats2half2_rn((ax0 + ax1) * inv, (ay0 + ay1) * inv);
}

// ---------- gate reduce ----------
__global__ void k_gatered(const float* __restrict__ p, const float* __restrict__ w2,
                          const float* __restrict__ b2, const int* __restrict__ batch32,
                          float* __restrict__ gate, int* __restrict__ gmax) {
    int n = blockIdx.x * blockDim.x + threadIdx.x;
    if (n >= N_NODES) return;
    float s = 0.f;
#pragma unroll
    for (int j = 0; j < 64; j += 4) {
        float4 v = *(const float4*)(p + (size_t)n * 64 + j);
        float4 w = *(const float4*)(w2 + j);
        s += v.x * w.x + v.y * w.y + v.z * w.z + v.w * w.w;
    }
    float gv = s + b2[0];
    gate[n] = gv;
    atomicMax(&gmax[batch32[n]], enc_f(gv));
}

__global__ void k_eg(float* gate, const int* gmax, float* gsum, const int* batch32) {
    int n = blockIdx.x * blockDim.x + threadIdx.x;
    if (n < N_NODES) {
        int g = batch32[n];
        float e = expf(gate[n] - dec_f(gmax[g]));
        gate[n] = e;
        atomicAdd(&gsum[g], e);
    }
}

// ---------- pooled[g,:] += h[n,:] * eg[n]/gsum[g] ----------
#define POOL_NPB 256
__global__ __launch_bounds__(128) void k_pool(const float* __restrict__ h,
                                              const float* __restrict__ eg,
                                              const float* __restrict__ gsum,
                                              const int* __restrict__ batch32,
                                              float* __restrict__ pooled) {
    int c = threadIdx.x;
    int n0 = blockIdx.x * POOL_NPB;
    int n1 = n0 + POOL_NPB; if (n1 > N_NODES) n1 = N_NODES;
    if (n0 >= N_NODES) return;
    int cur = batch32[n0];
    float acc = 0.f;
    for (int n = n0; n < n1; ++n) {
        int g = batch32[n];
        if (g != cur) {
            atomicAdd(&pooled[(size_t)cur * H + c], acc);
            acc = 0.f; cur = g;
        }
        float w = eg[n] / gsum[g];
        acc += h[(size_t)n * H + c] * w;
    }
    atomicAdd(&pooled[(size_t)cur * H + c], acc);
}

// ---------- classifier ----------
__global__ __launch_bounds__(64) void k_cls(const float* __restrict__ pooled,
                                            const float* __restrict__ w1,
                                            const float* __restrict__ b1,
                                            const float* __restrict__ w2,
                                            const float* __restrict__ b2,
                                            float* __restrict__ out) {
    __shared__ float sp[64];
    int g = blockIdx.x;
    int lane = threadIdx.x;
    float r0 = pooled[(size_t)g * H + lane];
    float r1 = pooled[(size_t)g * H + 64 + lane];
    float acc = b1[lane];
#pragma unroll 16
    for (int k = 0; k < 64; ++k) acc += __shfl(r0, k) * w1[k * 64 + lane];
#pragma unroll 16
    for (int k = 0; k < 64; ++k) acc += __shfl(r1, k) * w1[(64 + k) * 64 + lane];
    sp[lane] = fmaxf(acc, 0.f);
    __syncthreads();
    if (lane < NUM_CLASSES) {
        float o = b2[lane];
        for (int c = 0; c < 64; ++c) o += sp[c] * w2[c * NUM_CLASSES + lane];
        out[g * NUM_CLASSES + lane] = o;
    }
}

extern "C" void kernel_launch(void* const* d_in, const int* in_sizes, int n_in,
                              void* d_out, int out_size, void* d_ws, size_t ws_size,
                              hipStream_t stream) {
    const float* x       = (const float*)d_in[0];
    const int*   eraw    = (const int*)d_in[1];
    const int*   braw    = (const int*)d_in[2];
    const float* proj_w  = (const float*)d_in[3];
    const float* proj_b  = (const float*)d_in[4];
    const float* lin_l_w = (const float*)d_in[5];
    const float* lin_l_b = (const float*)d_in[6];
    const float* lin_r_w = (const float*)d_in[7];
    const float* ln_g    = (const float*)d_in[8];
    const float* ln_b    = (const float*)d_in[9];
    const float* gate_w1 = (const float*)d_in[10];
    const float* gate_b1 = (const float*)d_in[11];
    const float* gate_w2 = (const float*)d_in[12];
    const float* gate_b2 = (const float*)d_in[13];
    const float* cls_w1  = (const float*)d_in[14];
    const float* cls_b1  = (const float*)d_in[15];
    const float* cls_w2  = (const float*)d_in[16];
    const float* cls_b2  = (const float*)d_in[17];
    float* out = (float*)d_out;

    // workspace layout
    float*  h      = (float*)d_ws;                       // N*H f32
    __half* h16    = (__half*)(h + (size_t)N_NODES * H); // N*H f16
    __half* t16    = h16 + (size_t)N_NODES * H;          // N*H f16
    float*  p      = (float*)t16;                        // alias: N*64 f32 (after layers)
    float*  gate   = (float*)(t16 + (size_t)N_NODES * H); // N
    float*  gsum   = gate + N_NODES;                     // 512
    float*  pooled = gsum + NUM_GRAPHS;                  // 512*H
    __half* W16t   = (__half*)(pooled + NUM_GRAPHS * H); // 3*128*256
    int* flags     = (int*)(W16t + (size_t)NUM_LAYERS * 32768); // 4
    int* col       = flags + 4;                          // E
    int* batch32   = col + N_EDGES;                      // N
    int* deg       = batch32 + N_NODES;                  // N
    int* rowptr    = deg + N_NODES;                      // N+1
    int* cursor    = rowptr + N_NODES + 1;               // N
    int* bsums     = cursor + N_NODES;                   // 256
    int* gmax      = bsums + 256;                        // 512
    int* bcnt      = gmax + 512;                         // 512
    int* boff      = bcnt + 512;                         // 513
    int* bcursor   = boff + 513;                         // 512
    unsigned int* br = (unsigned int*)(bcursor + 512);   // E packed records

    const int nbN = (N_NODES + 255) / 256;
    const int nbE4 = (N_EDGES + EPB - 1) / EPB;          // 391
    const int nbS = (N_NODES + 511) / 512;               // 196
    const int nbW = (N_NODES + 3) / 4;
    const int nbG = (N_NODES + 63) / 64;                 // 1563

    k_detect<<<1, 1, 0, stream>>>(eraw, braw, flags);
    k_init<<<nbN, 256, 0, stream>>>(gmax, gsum, pooled, bcnt);
    k_conv_batch<<<nbN, 256, 0, stream>>>(braw, flags, batch32);
    // CSR build (bucketed, write-amplification-free)
    k_bhist<<<512, 256, 0, stream>>>(eraw, flags, bcnt);
    k_bscan<<<1, 512, 0, stream>>>(bcnt, boff, bcursor);
    k_bucket<<<nbE4, 256, 0, stream>>>(eraw, flags, bcursor, br);
    k_bdeg<<<NBKT, 256, 0, stream>>>(br, boff, deg);
    k_scan1<<<nbS, 256, 0, stream>>>(deg, rowptr, bsums);
    k_scan2<<<1, 256, 0, stream>>>(bsums, nbS);
    k_scan3<<<nbN, 256, 0, stream>>>(rowptr, bsums, cursor);
    k_scatter2<<<NBKT, 256, 0, stream>>>(br, boff, rowptr, cursor, col);
    // weights to fp16 transposed
    k_prepw<<<(NUM_LAYERS * 128 * 256 + 255) / 256, 256, 0, stream>>>(lin_l_w, lin_r_w, W16t);

    // h = relu(x @ proj_w + proj_b), also h16
    k_gemm_t<128, 1><<<nbG, 256, 0, stream>>>(x, proj_w, proj_b, h, h16, N_NODES, NDIM);

    for (int l = 0; l < NUM_LAYERS; ++l) {
        const float* bl  = lin_l_b + (size_t)l * H;
        const float* gl  = ln_g + (size_t)l * H;
        const float* blb = ln_b + (size_t)l * H;
        k_aggr<<<nbW, 256, 0, stream>>>(h16, rowptr, col, t16);
        k_layer_mfma<<<nbG, 256, 0, stream>>>(t16, h, h16, W16t + (size_t)l * 32768, bl, gl, blb);
    }

    // gate = relu(h@gate_w1 + b1) @ gate_w2 + b2, then segment softmax-pool
    k_gemm_t<64, 1><<<nbG, 256, 0, stream>>>(h, gate_w1, gate_b1, p, (__half*)nullptr, N_NODES, H);
    k_gatered<<<nbN, 256, 0, stream>>>(p, gate_w2, gate_b2, batch32, gate, gmax);
    k_eg<<<nbN, 256, 0, stream>>>(gate, gmax, gsum, batch32);
    k_pool<<<(N_NODES + POOL_NPB - 1) / POOL_NPB, 128, 0, stream>>>(h, gate, gsum, batch32, pooled);
    k_cls<<<NUM_GRAPHS, 64, 0, stream>>>(pooled, cls_w1, cls_b1, cls_w2, cls_b2, out);
}

// Round 5
// 951.474 us; speedup vs baseline: 1.8884x; 1.0691x over previous
//
#include <hip/hip_runtime.h>
#include <hip/hip_fp16.h>
#include <math.h>

#define N_NODES   100000
#define N_EDGES   1600000
#define NDIM      64
#define H         128
#define NUM_LAYERS 3
#define NUM_CLASSES 6
#define NUM_GRAPHS 512
#define LN_EPS    1e-5f
#define NBKT      391           // ceil(N_NODES / 256)
#define SCAP      5376          // phase-B LDS col capacity (bucket mean 4092, std 64)

typedef _Float16 f16x8 __attribute__((ext_vector_type(8)));
typedef float    f32x4 __attribute__((ext_vector_type(4)));

// ---------- helpers ----------
__device__ __forceinline__ int idx_at(const int* raw, int is64, int i) {
    return is64 ? raw[2 * (long long)i] : raw[i];
}
__device__ __forceinline__ int enc_f(float f) {
    int i = __float_as_int(f);
    return i >= 0 ? i : (i ^ 0x7fffffff);
}
__device__ __forceinline__ float dec_f(int i) {
    return __int_as_float(i >= 0 ? i : (i ^ 0x7fffffff));
}

// ---------- dtype detection ----------
__global__ void k_detect(const int* eraw, const int* braw, int* flags) {
    if (threadIdx.x == 0 && blockIdx.x == 0) {
        int e64 = 1;
        for (int i = 1; i < 128; i += 2) if (eraw[i] != 0) { e64 = 0; break; }
        flags[0] = e64;
        flags[1] = (braw[N_NODES - 1] == 0) ? 1 : 0;
    }
}

// ---------- init ----------
__global__ void k_init(int* gmax, float* gsum, float* pooled, int* bcnt) {
    int i = blockIdx.x * blockDim.x + threadIdx.x;
    if (i < NUM_GRAPHS) { gmax[i] = INT_MIN; gsum[i] = 0.f; }
    if (i < NUM_GRAPHS * H) pooled[i] = 0.f;
    if (i < 512) bcnt[i] = 0;
}

__global__ void k_conv_batch(const int* braw, const int* flags, int* batch32) {
    int i = blockIdx.x * blockDim.x + threadIdx.x;
    if (i < N_NODES) batch32[i] = idx_at(braw, flags[1], i);
}

// ---------- bucket histogram (512 buckets by dst>>8), LDS-aggregated ----------
__global__ __launch_bounds__(256) void k_bhist(const int* eraw, const int* flags, int* bcnt) {
    __shared__ int c[512];
    int tid = threadIdx.x;
    for (int i = tid; i < 512; i += 256) c[i] = 0;
    __syncthreads();
    int f = flags[0];
    int stride = gridDim.x * 256;
    for (int e = blockIdx.x * 256 + tid; e < N_EDGES; e += stride) {
        int d = idx_at(eraw, f, N_EDGES + e);
        atomicAdd(&c[d >> 8], 1);
    }
    __syncthreads();
    for (int i = tid; i < 512; i += 256) if (c[i]) atomicAdd(&bcnt[i], c[i]);
}

// ---------- scan of 512 bucket counts -> boff[513], bcursor ----------
__global__ void k_bscan(const int* bcnt, int* boff, int* bcursor) {
    __shared__ int sh[512];
    int tid = threadIdx.x;     // 512 threads
    int v = bcnt[tid];
    sh[tid] = v;
    __syncthreads();
    for (int off = 1; off < 512; off <<= 1) {
        int u = (tid >= off) ? sh[tid - off] : 0;
        __syncthreads();
        sh[tid] += u;
        __syncthreads();
    }
    int excl = sh[tid] - v;
    boff[tid] = excl;
    bcursor[tid] = excl;
    if (tid == 511) boff[512] = sh[511];
}

// ---------- phase A: scatter packed records into bucket-contiguous regions ----------
#define EPB 4096
__global__ __launch_bounds__(256) void k_bucket(const int* eraw, const int* flags,
                                                int* bcursor, unsigned int* br) {
    __shared__ int cnt[512];
    __shared__ int lcur[512];
    int tid = threadIdx.x;
    int f = flags[0];
    int base = blockIdx.x * EPB;
    int se[16], de[16];
#pragma unroll
    for (int j = 0; j < 16; ++j) {
        int e = base + j * 256 + tid;
        if (e < N_EDGES) {
            se[j] = idx_at(eraw, f, e);
            de[j] = idx_at(eraw, f, N_EDGES + e);
        } else de[j] = -1;
    }
    for (int i = tid; i < 512; i += 256) cnt[i] = 0;
    __syncthreads();
#pragma unroll
    for (int j = 0; j < 16; ++j)
        if (de[j] >= 0) atomicAdd(&cnt[de[j] >> 8], 1);
    __syncthreads();
    for (int i = tid; i < 512; i += 256)
        lcur[i] = cnt[i] ? atomicAdd(&bcursor[i], cnt[i]) : 0;
    __syncthreads();
#pragma unroll
    for (int j = 0; j < 16; ++j)
        if (de[j] >= 0) {
            int pos = atomicAdd(&lcur[de[j] >> 8], 1);
            br[pos] = ((unsigned int)(de[j] & 255) << 24) | (unsigned int)se[j];
        }
}

// ---------- per-bucket degree count ----------
__global__ __launch_bounds__(256) void k_bdeg(const unsigned int* br, const int* boff, int* deg) {
    __shared__ int d256[256];
    int b = blockIdx.x;
    int tid = threadIdx.x;
    d256[tid] = 0;
    __syncthreads();
    int lo = boff[b], hi = boff[b + 1];
    for (int i = lo + tid; i < hi; i += 256)
        atomicAdd(&d256[br[i] >> 24], 1);
    __syncthreads();
    int node = (b << 8) + tid;
    if (node < N_NODES) deg[node] = d256[tid];
}

// ---------- scans over deg -> rowptr ----------
__global__ void k_scan1(const int* deg, int* rowptr, int* bsums) {
    __shared__ int sh[256];
    int tid = threadIdx.x;
    int i0 = blockIdx.x * 512 + tid * 2;
    int a = (i0 < N_NODES) ? deg[i0] : 0;
    int b = (i0 + 1 < N_NODES) ? deg[i0 + 1] : 0;
    int ts = a + b;
    sh[tid] = ts;
    __syncthreads();
    for (int off = 1; off < 256; off <<= 1) {
        int v = (tid >= off) ? sh[tid - off] : 0;
        __syncthreads();
        sh[tid] += v;
        __syncthreads();
    }
    int excl = sh[tid] - ts;
    if (i0 < N_NODES) rowptr[i0] = excl;
    if (i0 + 1 < N_NODES) rowptr[i0 + 1] = excl + a;
    if (tid == 255) bsums[blockIdx.x] = sh[255];
}

__global__ void k_scan2(int* bsums, int nb) {
    __shared__ int sh[256];
    int tid = threadIdx.x;
    int v = (tid < nb) ? bsums[tid] : 0;
    sh[tid] = v;
    __syncthreads();
    for (int off = 1; off < 256; off <<= 1) {
        int u = (tid >= off) ? sh[tid - off] : 0;
        __syncthreads();
        sh[tid] += u;
        __syncthreads();
    }
    if (tid < nb) bsums[tid] = sh[tid] - v;
}

__global__ void k_scan3(int* rowptr, const int* bsums, int* cursor) {
    int i = blockIdx.x * blockDim.x + threadIdx.x;
    if (i < N_NODES) {
        int r = rowptr[i] + bsums[i >> 9];
        rowptr[i] = r;
        cursor[i] = r;
    }
    if (i == 0) rowptr[N_NODES] = N_EDGES;
}

// ---------- phase B: per-bucket fine scatter via LDS staging, coalesced writeout ----------
__global__ __launch_bounds__(256) void k_scatter2(const unsigned int* br, const int* boff,
                                                  const int* rowptr, int* cursor, int* col) {
    __shared__ int lcur[256];
    __shared__ int cbuf[SCAP];
    int b = blockIdx.x;
    int tid = threadIdx.x;
    int lo = boff[b], hi = boff[b + 1];
    int wsize = hi - lo;
    int node = (b << 8) + tid;
    lcur[tid] = rowptr[node < N_NODES ? node : N_NODES] - lo;
    __syncthreads();
    if (wsize <= SCAP) {
        for (int i = lo + tid; i < hi; i += 256) {
            unsigned int r = br[i];
            int p = atomicAdd(&lcur[r >> 24], 1);
            cbuf[p] = (int)(r & 0xFFFFFF);
        }
        __syncthreads();
        for (int j = tid; j < wsize; j += 256) col[lo + j] = cbuf[j];
    } else {
        for (int i = lo + tid; i < hi; i += 256) {
            unsigned int r = br[i];
            int d = (b << 8) + (int)(r >> 24);
            int p = atomicAdd(&cursor[d], 1);
            col[p] = (int)(r & 0xFFFFFF);
        }
    }
}

// ---------- weight prep: W16t[l][n*256+k] = fp16 of (k<128 ? Wl[k][n] : Wr[k-128][n]) ----------
__global__ void k_prepw(const float* __restrict__ lin_l_w, const float* __restrict__ lin_r_w,
                        __half* __restrict__ W16t) {
    int i = blockIdx.x * 256 + threadIdx.x;
    if (i >= NUM_LAYERS * 128 * 256) return;
    int l = i >> 15;
    int rem = i & 32767;
    int n = rem >> 8;
    int k = rem & 255;
    float v = (k < 128) ? lin_l_w[(size_t)l * 16384 + k * 128 + n]
                        : lin_r_w[(size_t)l * 16384 + (k - 128) * 128 + n];
    W16t[(size_t)l * 32768 + n * 256 + k] = __float2half(v);
}

// ---------- tiled fp32 GEMM (COLS=128): C = relu(A[n,K] @ W + bias), + fp16 copy ----------
__global__ __launch_bounds__(256) void k_gemm_proj(const float* __restrict__ A,
                                                   const float* __restrict__ W,
                                                   const float* __restrict__ bias,
                                                   float* __restrict__ C,
                                                   __half* __restrict__ C16,
                                                   int nrows, int K) {
    __shared__ float As_t[32][68];
    __shared__ float Ws[32 * 128];
    int tid = threadIdx.x;
    int row0 = blockIdx.x * 64;
    int tr = tid >> 4;
    int tc = tid & 15;
    int c0 = tc * 8;
    float acc[4][8];
#pragma unroll
    for (int i = 0; i < 4; ++i)
#pragma unroll
        for (int j = 0; j < 8; ++j) acc[i][j] = 0.f;

    for (int kc = 0; kc < K; kc += 32) {
        __syncthreads();
#pragma unroll
        for (int it = 0; it < 2; ++it) {
            int idx = tid + it * 256;
            int r = idx >> 3, c4 = idx & 7;
            int gr = row0 + r;
            float4 v = make_float4(0.f, 0.f, 0.f, 0.f);
            if (gr < nrows) v = *(const float4*)(A + (size_t)gr * K + kc + c4 * 4);
            As_t[c4 * 4 + 0][r] = v.x;
            As_t[c4 * 4 + 1][r] = v.y;
            As_t[c4 * 4 + 2][r] = v.z;
            As_t[c4 * 4 + 3][r] = v.w;
        }
#pragma unroll
        for (int it = 0; it < 4; ++it) {
            int idx = tid + it * 256;
            int r = idx >> 5, c4 = idx & 31;
            *(float4*)(&Ws[r * 128 + c4 * 4]) = *(const float4*)(W + (size_t)(kc + r) * 128 + c4 * 4);
        }
        __syncthreads();
#pragma unroll
        for (int k = 0; k < 32; ++k) {
            float4 a4 = *(const float4*)(&As_t[k][tr * 4]);
            float a[4] = {a4.x, a4.y, a4.z, a4.w};
            float4 w0 = *(const float4*)(&Ws[k * 128 + c0]);
            float4 w1 = *(const float4*)(&Ws[k * 128 + c0 + 4]);
            float w[8] = {w0.x, w0.y, w0.z, w0.w, w1.x, w1.y, w1.z, w1.w};
#pragma unroll
            for (int i = 0; i < 4; ++i)
#pragma unroll
                for (int j = 0; j < 8; ++j) acc[i][j] += a[i] * w[j];
        }
    }
    float bv[8];
#pragma unroll
    for (int j = 0; j < 8; ++j) bv[j] = bias[c0 + j];
#pragma unroll
    for (int i = 0; i < 4; ++i) {
        int gr = row0 + tr * 4 + i;
        if (gr < nrows) {
            float o[8];
#pragma unroll
            for (int j = 0; j < 8; ++j) o[j] = fmaxf(acc[i][j] + bv[j], 0.f);
            *(float4*)(C + (size_t)gr * 128 + c0)     = make_float4(o[0], o[1], o[2], o[3]);
            *(float4*)(C + (size_t)gr * 128 + c0 + 4) = make_float4(o[4], o[5], o[6], o[7]);
            __half2 p[4];
#pragma unroll
            for (int j = 0; j < 8; j += 2) p[j / 2] = __floats2half2_rn(o[j], o[j + 1]);
            *(float4*)(C16 + (size_t)gr * 128 + c0) = *(float4*)p;
        }
    }
}

// ---------- gate GEMM fused with w2-dot + segment max ----------
// gate[n] = relu(h[n,:]@gate_w1 + b1) . w2 + b2 ; atomicMax per graph. No p round-trip.
__global__ __launch_bounds__(256) void k_gate_gemm(const float* __restrict__ A,      // h [N,128]
                                                   const float* __restrict__ W,      // [128,64]
                                                   const float* __restrict__ bias,   // [64]
                                                   const float* __restrict__ w2,     // [64]
                                                   const float* __restrict__ b2,     // [1]
                                                   const int* __restrict__ batch32,
                                                   float* __restrict__ gate,
                                                   int* __restrict__ gmax) {
    __shared__ float As_t[32][68];
    __shared__ float Ws[32 * 64];
    __shared__ float red[64][16];
    int tid = threadIdx.x;
    int row0 = blockIdx.x * 64;
    int tr = tid >> 4;
    int tc = tid & 15;
    int c0 = tc * 4;
    float acc[4][4];
#pragma unroll
    for (int i = 0; i < 4; ++i)
#pragma unroll
        for (int j = 0; j < 4; ++j) acc[i][j] = 0.f;

    for (int kc = 0; kc < 128; kc += 32) {
        __syncthreads();
#pragma unroll
        for (int it = 0; it < 2; ++it) {
            int idx = tid + it * 256;
            int r = idx >> 3, c4 = idx & 7;
            int gr = row0 + r;
            float4 v = make_float4(0.f, 0.f, 0.f, 0.f);
            if (gr < N_NODES) v = *(const float4*)(A + (size_t)gr * H + kc + c4 * 4);
            As_t[c4 * 4 + 0][r] = v.x;
            As_t[c4 * 4 + 1][r] = v.y;
            As_t[c4 * 4 + 2][r] = v.z;
            As_t[c4 * 4 + 3][r] = v.w;
        }
        {
            int r = tid >> 4, c4 = tid & 15;
            *(float4*)(&Ws[r * 64 + c4 * 4]) = *(const float4*)(W + (size_t)(kc + r) * 64 + c4 * 4);
            r += 16;
            *(float4*)(&Ws[r * 64 + c4 * 4]) = *(const float4*)(W + (size_t)(kc + r) * 64 + c4 * 4);
        }
        __syncthreads();
#pragma unroll
        for (int k = 0; k < 32; ++k) {
            float4 a4 = *(const float4*)(&As_t[k][tr * 4]);
            float a[4] = {a4.x, a4.y, a4.z, a4.w};
            float4 w0 = *(const float4*)(&Ws[k * 64 + c0]);
            float w[4] = {w0.x, w0.y, w0.z, w0.w};
#pragma unroll
            for (int i = 0; i < 4; ++i)
#pragma unroll
                for (int j = 0; j < 4; ++j) acc[i][j] += a[i] * w[j];
        }
    }
    float bv[4], w2v[4];
#pragma unroll
    for (int j = 0; j < 4; ++j) { bv[j] = bias[c0 + j]; w2v[j] = w2[c0 + j]; }
#pragma unroll
    for (int i = 0; i < 4; ++i) {
        float part = 0.f;
#pragma unroll
        for (int j = 0; j < 4; ++j)
            part += fmaxf(acc[i][j] + bv[j], 0.f) * w2v[j];
        red[tr * 4 + i][tc] = part;
    }
    __syncthreads();
    if (tid < 64) {
        int gr = row0 + tid;
        if (gr < N_NODES) {
            float s = 0.f;
#pragma unroll
            for (int j = 0; j < 16; ++j) s += red[tid][j];
            float gv = s + b2[0];
            gate[gr] = gv;
            atomicMax(&gmax[batch32[gr]], enc_f(gv));
        }
    }
}

// ---------- MFMA fused SAGE layer: h = elu(LN([t16|h16]@[Wl;Wr] + bl)) + h ----------
__global__ __launch_bounds__(256) void k_layer_mfma(const __half* __restrict__ t16,
                                                    float* __restrict__ h,
                                                    __half* __restrict__ h16,
                                                    const __half* __restrict__ W16t,
                                                    const float* __restrict__ bl,
                                                    const float* __restrict__ g,
                                                    const float* __restrict__ bb) {
    int tid = threadIdx.x;
    int wave = tid >> 6, lane = tid & 63;
    int s = lane & 15, quad = lane >> 4;
    int row0 = blockIdx.x * 64 + wave * 16;
    int arow = row0 + s;
    if (arow >= N_NODES) arow = N_NODES - 1;

    f32x4 acc[8];
#pragma unroll
    for (int c = 0; c < 8; ++c) acc[c] = (f32x4){0.f, 0.f, 0.f, 0.f};

#pragma unroll
    for (int kc = 0; kc < 256; kc += 32) {
        const __half* asrc = (kc < 128) ? t16 : h16;
        int koff = kc & 127;
        f16x8 afrag = *(const f16x8*)(asrc + (size_t)arow * H + koff + quad * 8);
#pragma unroll
        for (int c = 0; c < 8; ++c) {
            f16x8 bfrag = *(const f16x8*)(W16t + (size_t)(c * 16 + s) * 256 + kc + quad * 8);
            acc[c] = __builtin_amdgcn_mfma_f32_16x16x32_f16(afrag, bfrag, acc[c], 0, 0, 0);
        }
    }
    float y[8][4];
    float sm[4] = {0.f, 0.f, 0.f, 0.f}, sq[4] = {0.f, 0.f, 0.f, 0.f};
#pragma unroll
    for (int c = 0; c < 8; ++c) {
        float bv = bl[c * 16 + s];
#pragma unroll
        for (int i = 0; i < 4; ++i) {
            float v = acc[c][i] + bv;
            y[c][i] = v;
            sm[i] += v;
            sq[i] += v * v;
        }
    }
#pragma unroll
    for (int off = 1; off < 16; off <<= 1) {
#pragma unroll
        for (int i = 0; i < 4; ++i) {
            sm[i] += __shfl_xor(sm[i], off);
            sq[i] += __shfl_xor(sq[i], off);
        }
    }
    float mean[4], rstd[4];
#pragma unroll
    for (int i = 0; i < 4; ++i) {
        mean[i] = sm[i] * (1.0f / H);
        float var = sq[i] * (1.0f / H) - mean[i] * mean[i];
        rstd[i] = rsqrtf(var + LN_EPS);
    }
#pragma unroll
    for (int i = 0; i < 4; ++i) {
        int r = row0 + quad * 4 + i;
        if (r < N_NODES) {
#pragma unroll
            for (int c = 0; c < 8; ++c) {
                int colj = c * 16 + s;
                float yv = (y[c][i] - mean[i]) * rstd[i] * g[colj] + bb[colj];
                yv = yv > 0.f ? yv : expf(yv) - 1.f;
                float o = yv + h[(size_t)r * H + colj];
                h[(size_t)r * H + colj] = o;
                h16[(size_t)r * H + colj] = __float2half(o);
            }
        }
    }
}

// ---------- mean aggregation: wave per node, 2 edges per load-instr, 4 in flight ----------
__global__ __launch_bounds__(256) void k_aggr(const __half* __restrict__ h16,
                                              const int* __restrict__ rowptr,
                                              const int* __restrict__ col,
                                              __half* __restrict__ t16) {
    int lane = threadIdx.x & 63;
    int node = blockIdx.x * 4 + (threadIdx.x >> 6);
    if (node >= N_NODES) return;
    int li = lane & 31;       // covers cols 4li..4li+3 (8 B)
    int pg = lane >> 5;       // edge-parity group
    int e0 = rowptr[node], e1 = rowptr[node + 1];
    float a0 = 0.f, a1 = 0.f, a2 = 0.f, a3 = 0.f;
    float c0 = 0.f, c1 = 0.f, c2 = 0.f, c3 = 0.f;
    int e = e0;
    for (; e + 3 < e1; e += 4) {
        int sA = col[e + pg];
        int sB = col[e + 2 + pg];
        float2 rA = *(const float2*)(h16 + (size_t)sA * H + li * 4);
        float2 rB = *(const float2*)(h16 + (size_t)sB * H + li * 4);
        const __half2* hA = (const __half2*)&rA;
        const __half2* hB = (const __half2*)&rB;
        float2 fA0 = __half22float2(hA[0]), fA1 = __half22float2(hA[1]);
        float2 fB0 = __half22float2(hB[0]), fB1 = __half22float2(hB[1]);
        a0 += fA0.x; a1 += fA0.y; a2 += fA1.x; a3 += fA1.y;
        c0 += fB0.x; c1 += fB0.y; c2 += fB1.x; c3 += fB1.y;
    }
    for (; e + 1 < e1; e += 2) {
        int sA = col[e + pg];
        float2 rA = *(const float2*)(h16 + (size_t)sA * H + li * 4);
        const __half2* hA = (const __half2*)&rA;
        float2 fA0 = __half22float2(hA[0]), fA1 = __half22float2(hA[1]);
        a0 += fA0.x; a1 += fA0.y; a2 += fA1.x; a3 += fA1.y;
    }
    if (e < e1 && pg == 0) {
        int sA = col[e];
        float2 rA = *(const float2*)(h16 + (size_t)sA * H + li * 4);
        const __half2* hA = (const __half2*)&rA;
        float2 fA0 = __half22float2(hA[0]), fA1 = __half22float2(hA[1]);
        a0 += fA0.x; a1 += fA0.y; a2 += fA1.x; a3 += fA1.y;
    }
    a0 += c0; a1 += c1; a2 += c2; a3 += c3;
    a0 += __shfl_xor(a0, 32);
    a1 += __shfl_xor(a1, 32);
    a2 += __shfl_xor(a2, 32);
    a3 += __shfl_xor(a3, 32);
    if (pg == 0) {
        int d = e1 - e0;
        float inv = 1.0f / (float)(d > 1 ? d : 1);
        __half2 h01 = __floats2half2_rn(a0 * inv, a1 * inv);
        __half2 h23 = __floats2half2_rn(a2 * inv, a3 * inv);
        float2 o;
        ((__half2*)&o)[0] = h01;
        ((__half2*)&o)[1] = h23;
        *(float2*)(t16 + (size_t)node * H + li * 4) = o;
    }
}

__global__ void k_eg(float* gate, const int* gmax, float* gsum, const int* batch32) {
    int n = blockIdx.x * blockDim.x + threadIdx.x;
    if (n < N_NODES) {
        int g = batch32[n];
        float e = expf(gate[n] - dec_f(gmax[g]));
        gate[n] = e;
        atomicAdd(&gsum[g], e);
    }
}

// ---------- pooled[g,:] += h[n,:] * eg[n]/gsum[g] ----------
#define POOL_NPB 256
__global__ __launch_bounds__(128) void k_pool(const float* __restrict__ h,
                                              const float* __restrict__ eg,
                                              const float* __restrict__ gsum,
                                              const int* __restrict__ batch32,
                                              float* __restrict__ pooled) {
    int c = threadIdx.x;
    int n0 = blockIdx.x * POOL_NPB;
    int n1 = n0 + POOL_NPB; if (n1 > N_NODES) n1 = N_NODES;
    if (n0 >= N_NODES) return;
    int cur = batch32[n0];
    float acc = 0.f;
    for (int n = n0; n < n1; ++n) {
        int g = batch32[n];
        if (g != cur) {
            atomicAdd(&pooled[(size_t)cur * H + c], acc);
            acc = 0.f; cur = g;
        }
        float w = eg[n] / gsum[g];
        acc += h[(size_t)n * H + c] * w;
    }
    atomicAdd(&pooled[(size_t)cur * H + c], acc);
}

// ---------- classifier ----------
__global__ __launch_bounds__(64) void k_cls(const float* __restrict__ pooled,
                                            const float* __restrict__ w1,
                                            const float* __restrict__ b1,
                                            const float* __restrict__ w2,
                                            const float* __restrict__ b2,
                                            float* __restrict__ out) {
    __shared__ float sp[64];
    int g = blockIdx.x;
    int lane = threadIdx.x;
    float r0 = pooled[(size_t)g * H + lane];
    float r1 = pooled[(size_t)g * H + 64 + lane];
    float acc = b1[lane];
#pragma unroll 16
    for (int k = 0; k < 64; ++k) acc += __shfl(r0, k) * w1[k * 64 + lane];
#pragma unroll 16
    for (int k = 0; k < 64; ++k) acc += __shfl(r1, k) * w1[(64 + k) * 64 + lane];
    sp[lane] = fmaxf(acc, 0.f);
    __syncthreads();
    if (lane < NUM_CLASSES) {
        float o = b2[lane];
        for (int c = 0; c < 64; ++c) o += sp[c] * w2[c * NUM_CLASSES + lane];
        out[g * NUM_CLASSES + lane] = o;
    }
}

extern "C" void kernel_launch(void* const* d_in, const int* in_sizes, int n_in,
                              void* d_out, int out_size, void* d_ws, size_t ws_size,
                              hipStream_t stream) {
    const float* x       = (const float*)d_in[0];
    const int*   eraw    = (const int*)d_in[1];
    const int*   braw    = (const int*)d_in[2];
    const float* proj_w  = (const float*)d_in[3];
    const float* proj_b  = (const float*)d_in[4];
    const float* lin_l_w = (const float*)d_in[5];
    const float* lin_l_b = (const float*)d_in[6];
    const float* lin_r_w = (const float*)d_in[7];
    const float* ln_g    = (const float*)d_in[8];
    const float* ln_b    = (const float*)d_in[9];
    const float* gate_w1 = (const float*)d_in[10];
    const float* gate_b1 = (const float*)d_in[11];
    const float* gate_w2 = (const float*)d_in[12];
    const float* gate_b2 = (const float*)d_in[13];
    const float* cls_w1  = (const float*)d_in[14];
    const float* cls_b1  = (const float*)d_in[15];
    const float* cls_w2  = (const float*)d_in[16];
    const float* cls_b2  = (const float*)d_in[17];
    float* out = (float*)d_out;

    // workspace layout
    float*  h      = (float*)d_ws;                        // N*H f32
    __half* h16    = (__half*)(h + (size_t)N_NODES * H);  // N*H f16
    __half* t16    = h16 + (size_t)N_NODES * H;           // N*H f16
    float*  gate   = (float*)(t16 + (size_t)N_NODES * H); // N
    float*  gsum   = gate + N_NODES;                      // 512
    float*  pooled = gsum + NUM_GRAPHS;                   // 512*H
    __half* W16t   = (__half*)(pooled + NUM_GRAPHS * H);  // 3*128*256
    int* flags     = (int*)(W16t + (size_t)NUM_LAYERS * 32768); // 4
    int* col       = flags + 4;                           // E
    int* batch32   = col + N_EDGES;                       // N
    int* deg       = batch32 + N_NODES;                   // N
    int* rowptr    = deg + N_NODES;                       // N+1
    int* cursor    = rowptr + N_NODES + 1;                // N
    int* bsums     = cursor + N_NODES;                    // 256
    int* gmax      = bsums + 256;                         // 512
    int* bcnt      = gmax + 512;                          // 512
    int* boff      = bcnt + 512;                          // 513
    int* bcursor   = boff + 513;                          // 512
    unsigned int* br = (unsigned int*)(bcursor + 512);    // E packed records

    const int nbN = (N_NODES + 255) / 256;
    const int nbE4 = (N_EDGES + EPB - 1) / EPB;           // 391
    const int nbS = (N_NODES + 511) / 512;                // 196
    const int nbW = (N_NODES + 3) / 4;
    const int nbG = (N_NODES + 63) / 64;                  // 1563

    k_detect<<<1, 1, 0, stream>>>(eraw, braw, flags);
    k_init<<<nbN, 256, 0, stream>>>(gmax, gsum, pooled, bcnt);
    k_conv_batch<<<nbN, 256, 0, stream>>>(braw, flags, batch32);
    // CSR build (bucketed)
    k_bhist<<<512, 256, 0, stream>>>(eraw, flags, bcnt);
    k_bscan<<<1, 512, 0, stream>>>(bcnt, boff, bcursor);
    k_bucket<<<nbE4, 256, 0, stream>>>(eraw, flags, bcursor, br);
    k_bdeg<<<NBKT, 256, 0, stream>>>(br, boff, deg);
    k_scan1<<<nbS, 256, 0, stream>>>(deg, rowptr, bsums);
    k_scan2<<<1, 256, 0, stream>>>(bsums, nbS);
    k_scan3<<<nbN, 256, 0, stream>>>(rowptr, bsums, cursor);
    k_scatter2<<<NBKT, 256, 0, stream>>>(br, boff, rowptr, cursor, col);
    // weights to fp16 transposed
    k_prepw<<<(NUM_LAYERS * 128 * 256 + 255) / 256, 256, 0, stream>>>(lin_l_w, lin_r_w, W16t);

    // h = relu(x @ proj_w + proj_b), also h16
    k_gemm_proj<<<nbG, 256, 0, stream>>>(x, proj_w, proj_b, h, h16, N_NODES, NDIM);

    for (int l = 0; l < NUM_LAYERS; ++l) {
        const float* bl  = lin_l_b + (size_t)l * H;
        const float* gl  = ln_g + (size_t)l * H;
        const float* blb = ln_b + (size_t)l * H;
        k_aggr<<<nbW, 256, 0, stream>>>(h16, rowptr, col, t16);
        k_layer_mfma<<<nbG, 256, 0, stream>>>(t16, h, h16, W16t + (size_t)l * 32768, bl, gl, blb);
    }

    // gate (fused GEMM + dot + segment max), then segment softmax-pool
    k_gate_gemm<<<nbG, 256, 0, stream>>>(h, gate_w1, gate_b1, gate_w2, gate_b2, batch32, gate, gmax);
    k_eg<<<nbN, 256, 0, stream>>>(gate, gmax, gsum, batch32);
    k_pool<<<(N_NODES + POOL_NPB - 1) / POOL_NPB, 128, 0, stream>>>(h, gate, gsum, batch32, pooled);
    k_cls<<<NUM_GRAPHS, 64, 0, stream>>>(pooled, cls_w1, cls_b1, cls_w2, cls_b2, out);
}

// Round 6
// 873.471 us; speedup vs baseline: 2.0570x; 1.0893x over previous
//
#include <hip/hip_runtime.h>
#include <hip/hip_fp16.h>
#include <math.h>

#define N_NODES   100000
#define N_EDGES   1600000
#define NDIM      64
#define H         128
#define NUM_LAYERS 3
#define NUM_CLASSES 6
#define NUM_GRAPHS 512
#define LN_EPS    1e-5f
#define NBKT      391           // ceil(N_NODES / 256)
#define SCAP      5376          // phase-B LDS col capacity (bucket mean 4092, std 64)

typedef _Float16 f16x8 __attribute__((ext_vector_type(8)));
typedef float    f32x4 __attribute__((ext_vector_type(4)));

// ---------- helpers ----------
__device__ __forceinline__ int idx_at(const int* raw, int is64, int i) {
    return is64 ? raw[2 * (long long)i] : raw[i];
}
__device__ __forceinline__ int enc_f(float f) {
    int i = __float_as_int(f);
    return i >= 0 ? i : (i ^ 0x7fffffff);
}
__device__ __forceinline__ float dec_f(int i) {
    return __int_as_float(i >= 0 ? i : (i ^ 0x7fffffff));
}

// ---------- dtype detection ----------
__global__ void k_detect(const int* eraw, const int* braw, int* flags) {
    if (threadIdx.x == 0 && blockIdx.x == 0) {
        int e64 = 1;
        for (int i = 1; i < 128; i += 2) if (eraw[i] != 0) { e64 = 0; break; }
        flags[0] = e64;
        flags[1] = (braw[N_NODES - 1] == 0) ? 1 : 0;
    }
}

// ---------- init ----------
__global__ void k_init(int* gmax, float* gsum, float* pooled, int* bcnt) {
    int i = blockIdx.x * blockDim.x + threadIdx.x;
    if (i < NUM_GRAPHS) { gmax[i] = INT_MIN; gsum[i] = 0.f; }
    if (i < NUM_GRAPHS * H) pooled[i] = 0.f;
    if (i < 512) bcnt[i] = 0;
}

__global__ void k_conv_batch(const int* braw, const int* flags, int* batch32) {
    int i = blockIdx.x * blockDim.x + threadIdx.x;
    if (i < N_NODES) batch32[i] = idx_at(braw, flags[1], i);
}

// ---------- bucket histogram (512 buckets by dst>>8), LDS-aggregated ----------
__global__ __launch_bounds__(256) void k_bhist(const int* eraw, const int* flags, int* bcnt) {
    __shared__ int c[512];
    int tid = threadIdx.x;
    for (int i = tid; i < 512; i += 256) c[i] = 0;
    __syncthreads();
    int f = flags[0];
    int stride = gridDim.x * 256;
    for (int e = blockIdx.x * 256 + tid; e < N_EDGES; e += stride) {
        int d = idx_at(eraw, f, N_EDGES + e);
        atomicAdd(&c[d >> 8], 1);
    }
    __syncthreads();
    for (int i = tid; i < 512; i += 256) if (c[i]) atomicAdd(&bcnt[i], c[i]);
}

// ---------- scan of 512 bucket counts -> boff[513], bcursor ----------
__global__ void k_bscan(const int* bcnt, int* boff, int* bcursor) {
    __shared__ int sh[512];
    int tid = threadIdx.x;     // 512 threads
    int v = bcnt[tid];
    sh[tid] = v;
    __syncthreads();
    for (int off = 1; off < 512; off <<= 1) {
        int u = (tid >= off) ? sh[tid - off] : 0;
        __syncthreads();
        sh[tid] += u;
        __syncthreads();
    }
    int excl = sh[tid] - v;
    boff[tid] = excl;
    bcursor[tid] = excl;
    if (tid == 511) boff[512] = sh[511];
}

// ---------- phase A: scatter packed records into bucket-contiguous regions ----------
#define EPB 4096
__global__ __launch_bounds__(256) void k_bucket(const int* eraw, const int* flags,
                                                int* bcursor, unsigned int* br) {
    __shared__ int cnt[512];
    __shared__ int lcur[512];
    int tid = threadIdx.x;
    int f = flags[0];
    int base = blockIdx.x * EPB;
    int se[16], de[16];
#pragma unroll
    for (int j = 0; j < 16; ++j) {
        int e = base + j * 256 + tid;
        if (e < N_EDGES) {
            se[j] = idx_at(eraw, f, e);
            de[j] = idx_at(eraw, f, N_EDGES + e);
        } else de[j] = -1;
    }
    for (int i = tid; i < 512; i += 256) cnt[i] = 0;
    __syncthreads();
#pragma unroll
    for (int j = 0; j < 16; ++j)
        if (de[j] >= 0) atomicAdd(&cnt[de[j] >> 8], 1);
    __syncthreads();
    for (int i = tid; i < 512; i += 256)
        lcur[i] = cnt[i] ? atomicAdd(&bcursor[i], cnt[i]) : 0;
    __syncthreads();
#pragma unroll
    for (int j = 0; j < 16; ++j)
        if (de[j] >= 0) {
            int pos = atomicAdd(&lcur[de[j] >> 8], 1);
            br[pos] = ((unsigned int)(de[j] & 255) << 24) | (unsigned int)se[j];
        }
}

// ---------- per-bucket degree count ----------
__global__ __launch_bounds__(256) void k_bdeg(const unsigned int* br, const int* boff, int* deg) {
    __shared__ int d256[256];
    int b = blockIdx.x;
    int tid = threadIdx.x;
    d256[tid] = 0;
    __syncthreads();
    int lo = boff[b], hi = boff[b + 1];
    for (int i = lo + tid; i < hi; i += 256)
        atomicAdd(&d256[br[i] >> 24], 1);
    __syncthreads();
    int node = (b << 8) + tid;
    if (node < N_NODES) deg[node] = d256[tid];
}

// ---------- scans over deg -> rowptr ----------
__global__ void k_scan1(const int* deg, int* rowptr, int* bsums) {
    __shared__ int sh[256];
    int tid = threadIdx.x;
    int i0 = blockIdx.x * 512 + tid * 2;
    int a = (i0 < N_NODES) ? deg[i0] : 0;
    int b = (i0 + 1 < N_NODES) ? deg[i0 + 1] : 0;
    int ts = a + b;
    sh[tid] = ts;
    __syncthreads();
    for (int off = 1; off < 256; off <<= 1) {
        int v = (tid >= off) ? sh[tid - off] : 0;
        __syncthreads();
        sh[tid] += v;
        __syncthreads();
    }
    int excl = sh[tid] - ts;
    if (i0 < N_NODES) rowptr[i0] = excl;
    if (i0 + 1 < N_NODES) rowptr[i0 + 1] = excl + a;
    if (tid == 255) bsums[blockIdx.x] = sh[255];
}

__global__ void k_scan2(int* bsums, int nb) {
    __shared__ int sh[256];
    int tid = threadIdx.x;
    int v = (tid < nb) ? bsums[tid] : 0;
    sh[tid] = v;
    __syncthreads();
    for (int off = 1; off < 256; off <<= 1) {
        int u = (tid >= off) ? sh[tid - off] : 0;
        __syncthreads();
        sh[tid] += u;
        __syncthreads();
    }
    if (tid < nb) bsums[tid] = sh[tid] - v;
}

__global__ void k_scan3(int* rowptr, const int* bsums, int* cursor) {
    int i = blockIdx.x * blockDim.x + threadIdx.x;
    if (i < N_NODES) {
        int r = rowptr[i] + bsums[i >> 9];
        rowptr[i] = r;
        cursor[i] = r;
    }
    if (i == 0) rowptr[N_NODES] = N_EDGES;
}

// ---------- phase B: per-bucket fine scatter via LDS staging, coalesced writeout ----------
__global__ __launch_bounds__(256) void k_scatter2(const unsigned int* br, const int* boff,
                                                  const int* rowptr, int* cursor, int* col) {
    __shared__ int lcur[256];
    __shared__ int cbuf[SCAP];
    int b = blockIdx.x;
    int tid = threadIdx.x;
    int lo = boff[b], hi = boff[b + 1];
    int wsize = hi - lo;
    int node = (b << 8) + tid;
    lcur[tid] = rowptr[node < N_NODES ? node : N_NODES] - lo;
    __syncthreads();
    if (wsize <= SCAP) {
        for (int i = lo + tid; i < hi; i += 256) {
            unsigned int r = br[i];
            int p = atomicAdd(&lcur[r >> 24], 1);
            cbuf[p] = (int)(r & 0xFFFFFF);
        }
        __syncthreads();
        for (int j = tid; j < wsize; j += 256) col[lo + j] = cbuf[j];
    } else {
        for (int i = lo + tid; i < hi; i += 256) {
            unsigned int r = br[i];
            int d = (b << 8) + (int)(r >> 24);
            int p = atomicAdd(&cursor[d], 1);
            col[p] = (int)(r & 0xFFFFFF);
        }
    }
}

// ---------- weight prep ----------
// W16t[l][n*256+k] = fp16 of (k<128 ? Wl[k][n] : Wr[k-128][n])   (3*32768 elems)
// W16g[n*128+k]    = fp16 of gate_w1[k][n]                       (8192 elems)
__global__ void k_prepw(const float* __restrict__ lin_l_w, const float* __restrict__ lin_r_w,
                        const float* __restrict__ gate_w1,
                        __half* __restrict__ W16t, __half* __restrict__ W16g) {
    int i = blockIdx.x * 256 + threadIdx.x;
    if (i < NUM_LAYERS * 128 * 256) {
        int l = i >> 15;
        int rem = i & 32767;
        int n = rem >> 8;
        int k = rem & 255;
        float v = (k < 128) ? lin_l_w[(size_t)l * 16384 + k * 128 + n]
                            : lin_r_w[(size_t)l * 16384 + (k - 128) * 128 + n];
        W16t[(size_t)l * 32768 + n * 256 + k] = __float2half(v);
    } else if (i < NUM_LAYERS * 128 * 256 + 64 * 128) {
        int idx = i - NUM_LAYERS * 128 * 256;
        int n = idx >> 7;      // 0..63
        int k = idx & 127;     // 0..127
        W16g[n * 128 + k] = __float2half(gate_w1[k * 64 + n]);
    }
}

// ---------- tiled fp32 GEMM (COLS=128): C = relu(A[n,K] @ W + bias), + fp16 copy ----------
__global__ __launch_bounds__(256) void k_gemm_proj(const float* __restrict__ A,
                                                   const float* __restrict__ W,
                                                   const float* __restrict__ bias,
                                                   float* __restrict__ C,
                                                   __half* __restrict__ C16,
                                                   int nrows, int K) {
    __shared__ float As_t[32][68];
    __shared__ float Ws[32 * 128];
    int tid = threadIdx.x;
    int row0 = blockIdx.x * 64;
    int tr = tid >> 4;
    int tc = tid & 15;
    int c0 = tc * 8;
    float acc[4][8];
#pragma unroll
    for (int i = 0; i < 4; ++i)
#pragma unroll
        for (int j = 0; j < 8; ++j) acc[i][j] = 0.f;

    for (int kc = 0; kc < K; kc += 32) {
        __syncthreads();
#pragma unroll
        for (int it = 0; it < 2; ++it) {
            int idx = tid + it * 256;
            int r = idx >> 3, c4 = idx & 7;
            int gr = row0 + r;
            float4 v = make_float4(0.f, 0.f, 0.f, 0.f);
            if (gr < nrows) v = *(const float4*)(A + (size_t)gr * K + kc + c4 * 4);
            As_t[c4 * 4 + 0][r] = v.x;
            As_t[c4 * 4 + 1][r] = v.y;
            As_t[c4 * 4 + 2][r] = v.z;
            As_t[c4 * 4 + 3][r] = v.w;
        }
#pragma unroll
        for (int it = 0; it < 4; ++it) {
            int idx = tid + it * 256;
            int r = idx >> 5, c4 = idx & 31;
            *(float4*)(&Ws[r * 128 + c4 * 4]) = *(const float4*)(W + (size_t)(kc + r) * 128 + c4 * 4);
        }
        __syncthreads();
#pragma unroll
        for (int k = 0; k < 32; ++k) {
            float4 a4 = *(const float4*)(&As_t[k][tr * 4]);
            float a[4] = {a4.x, a4.y, a4.z, a4.w};
            float4 w0 = *(const float4*)(&Ws[k * 128 + c0]);
            float4 w1 = *(const float4*)(&Ws[k * 128 + c0 + 4]);
            float w[8] = {w0.x, w0.y, w0.z, w0.w, w1.x, w1.y, w1.z, w1.w};
#pragma unroll
            for (int i = 0; i < 4; ++i)
#pragma unroll
                for (int j = 0; j < 8; ++j) acc[i][j] += a[i] * w[j];
        }
    }
    float bv[8];
#pragma unroll
    for (int j = 0; j < 8; ++j) bv[j] = bias[c0 + j];
#pragma unroll
    for (int i = 0; i < 4; ++i) {
        int gr = row0 + tr * 4 + i;
        if (gr < nrows) {
            float o[8];
#pragma unroll
            for (int j = 0; j < 8; ++j) o[j] = fmaxf(acc[i][j] + bv[j], 0.f);
            *(float4*)(C + (size_t)gr * 128 + c0)     = make_float4(o[0], o[1], o[2], o[3]);
            *(float4*)(C + (size_t)gr * 128 + c0 + 4) = make_float4(o[4], o[5], o[6], o[7]);
            __half2 p[4];
#pragma unroll
            for (int j = 0; j < 8; j += 2) p[j / 2] = __floats2half2_rn(o[j], o[j + 1]);
            *(float4*)(C16 + (size_t)gr * 128 + c0) = *(float4*)p;
        }
    }
}

// ---------- MFMA gate: gate[n] = relu(h16[n,:]@W16g^T + b1) . w2 + b2 ; segment max ----------
// per-wave 16x64 tile, LDS-free, same structure as k_layer_mfma.
__global__ __launch_bounds__(256) void k_gate_mfma(const __half* __restrict__ h16,
                                                   const __half* __restrict__ W16g,
                                                   const float* __restrict__ b1,
                                                   const float* __restrict__ w2,
                                                   const float* __restrict__ b2,
                                                   const int* __restrict__ batch32,
                                                   float* __restrict__ gate,
                                                   int* __restrict__ gmax) {
    int tid = threadIdx.x;
    int wave = tid >> 6, lane = tid & 63;
    int s = lane & 15, quad = lane >> 4;
    int row0 = blockIdx.x * 64 + wave * 16;
    int arow = row0 + s;
    if (arow >= N_NODES) arow = N_NODES - 1;

    f32x4 acc[4];
#pragma unroll
    for (int c = 0; c < 4; ++c) acc[c] = (f32x4){0.f, 0.f, 0.f, 0.f};

#pragma unroll
    for (int kc = 0; kc < 128; kc += 32) {
        f16x8 afrag = *(const f16x8*)(h16 + (size_t)arow * H + kc + quad * 8);
#pragma unroll
        for (int c = 0; c < 4; ++c) {
            f16x8 bfrag = *(const f16x8*)(W16g + (size_t)(c * 16 + s) * 128 + kc + quad * 8);
            acc[c] = __builtin_amdgcn_mfma_f32_16x16x32_f16(afrag, bfrag, acc[c], 0, 0, 0);
        }
    }
    // D[row=quad*4+i][col=c*16+s] in acc[c][i]
    float part[4] = {0.f, 0.f, 0.f, 0.f};
#pragma unroll
    for (int c = 0; c < 4; ++c) {
        float bv = b1[c * 16 + s];
        float wv = w2[c * 16 + s];
#pragma unroll
        for (int i = 0; i < 4; ++i)
            part[i] += fmaxf(acc[c][i] + bv, 0.f) * wv;
    }
#pragma unroll
    for (int off = 1; off < 16; off <<= 1) {
#pragma unroll
        for (int i = 0; i < 4; ++i) part[i] += __shfl_xor(part[i], off);
    }
    if (s == 0) {
        float b2v = b2[0];
#pragma unroll
        for (int i = 0; i < 4; ++i) {
            int r = row0 + quad * 4 + i;
            if (r < N_NODES) {
                float gv = part[i] + b2v;
                gate[r] = gv;
                atomicMax(&gmax[batch32[r]], enc_f(gv));
            }
        }
    }
}

// ---------- MFMA fused SAGE layer: h = elu(LN([t16|h16]@[Wl;Wr] + bl)) + h ----------
__global__ __launch_bounds__(256) void k_layer_mfma(const __half* __restrict__ t16,
                                                    float* __restrict__ h,
                                                    __half* __restrict__ h16,
                                                    const __half* __restrict__ W16t,
                                                    const float* __restrict__ bl,
                                                    const float* __restrict__ g,
                                                    const float* __restrict__ bb) {
    int tid = threadIdx.x;
    int wave = tid >> 6, lane = tid & 63;
    int s = lane & 15, quad = lane >> 4;
    int row0 = blockIdx.x * 64 + wave * 16;
    int arow = row0 + s;
    if (arow >= N_NODES) arow = N_NODES - 1;

    f32x4 acc[8];
#pragma unroll
    for (int c = 0; c < 8; ++c) acc[c] = (f32x4){0.f, 0.f, 0.f, 0.f};

#pragma unroll
    for (int kc = 0; kc < 256; kc += 32) {
        const __half* asrc = (kc < 128) ? t16 : h16;
        int koff = kc & 127;
        f16x8 afrag = *(const f16x8*)(asrc + (size_t)arow * H + koff + quad * 8);
#pragma unroll
        for (int c = 0; c < 8; ++c) {
            f16x8 bfrag = *(const f16x8*)(W16t + (size_t)(c * 16 + s) * 256 + kc + quad * 8);
            acc[c] = __builtin_amdgcn_mfma_f32_16x16x32_f16(afrag, bfrag, acc[c], 0, 0, 0);
        }
    }
    float y[8][4];
    float sm[4] = {0.f, 0.f, 0.f, 0.f}, sq[4] = {0.f, 0.f, 0.f, 0.f};
#pragma unroll
    for (int c = 0; c < 8; ++c) {
        float bv = bl[c * 16 + s];
#pragma unroll
        for (int i = 0; i < 4; ++i) {
            float v = acc[c][i] + bv;
            y[c][i] = v;
            sm[i] += v;
            sq[i] += v * v;
        }
    }
#pragma unroll
    for (int off = 1; off < 16; off <<= 1) {
#pragma unroll
        for (int i = 0; i < 4; ++i) {
            sm[i] += __shfl_xor(sm[i], off);
            sq[i] += __shfl_xor(sq[i], off);
        }
    }
    float mean[4], rstd[4];
#pragma unroll
    for (int i = 0; i < 4; ++i) {
        mean[i] = sm[i] * (1.0f / H);
        float var = sq[i] * (1.0f / H) - mean[i] * mean[i];
        rstd[i] = rsqrtf(var + LN_EPS);
    }
#pragma unroll
    for (int i = 0; i < 4; ++i) {
        int r = row0 + quad * 4 + i;
        if (r < N_NODES) {
#pragma unroll
            for (int c = 0; c < 8; ++c) {
                int colj = c * 16 + s;
                float yv = (y[c][i] - mean[i]) * rstd[i] * g[colj] + bb[colj];
                yv = yv > 0.f ? yv : expf(yv) - 1.f;
                float o = yv + h[(size_t)r * H + colj];
                h[(size_t)r * H + colj] = o;
                h16[(size_t)r * H + colj] = __float2half(o);
            }
        }
    }
}

// ---------- mean aggregation: wave per node, 32-lane groups, 4 edges in flight each ----------
__global__ __launch_bounds__(256) void k_aggr(const __half* __restrict__ h16,
                                              const int* __restrict__ rowptr,
                                              const int* __restrict__ col,
                                              __half* __restrict__ t16) {
    int lane = threadIdx.x & 63;
    int node = blockIdx.x * 4 + (threadIdx.x >> 6);
    if (node >= N_NODES) return;
    int li = lane & 31;       // covers cols 4li..4li+3 (8 B)
    int pg = lane >> 5;       // edge-parity group
    int e0 = rowptr[node], e1 = rowptr[node + 1];
    float a0[4] = {0.f, 0.f, 0.f, 0.f};
    float b0[4] = {0.f, 0.f, 0.f, 0.f};
    float c0[4] = {0.f, 0.f, 0.f, 0.f};
    float d0[4] = {0.f, 0.f, 0.f, 0.f};
    int e = e0;
    for (; e + 7 < e1; e += 8) {
        int sA = col[e + pg];
        int sB = col[e + 2 + pg];
        int sC = col[e + 4 + pg];
        int sD = col[e + 6 + pg];
        float2 rA = *(const float2*)(h16 + (size_t)sA * H + li * 4);
        float2 rB = *(const float2*)(h16 + (size_t)sB * H + li * 4);
        float2 rC = *(const float2*)(h16 + (size_t)sC * H + li * 4);
        float2 rD = *(const float2*)(h16 + (size_t)sD * H + li * 4);
        const __half2* hA = (const __half2*)&rA;
        const __half2* hB = (const __half2*)&rB;
        const __half2* hC = (const __half2*)&rC;
        const __half2* hD = (const __half2*)&rD;
        float2 f0, f1;
        f0 = __half22float2(hA[0]); f1 = __half22float2(hA[1]);
        a0[0] += f0.x; a0[1] += f0.y; a0[2] += f1.x; a0[3] += f1.y;
        f0 = __half22float2(hB[0]); f1 = __half22float2(hB[1]);
        b0[0] += f0.x; b0[1] += f0.y; b0[2] += f1.x; b0[3] += f1.y;
        f0 = __half22float2(hC[0]); f1 = __half22float2(hC[1]);
        c0[0] += f0.x; c0[1] += f0.y; c0[2] += f1.x; c0[3] += f1.y;
        f0 = __half22float2(hD[0]); f1 = __half22float2(hD[1]);
        d0[0] += f0.x; d0[1] += f0.y; d0[2] += f1.x; d0[3] += f1.y;
    }
    for (; e + 3 < e1; e += 4) {
        int sA = col[e + pg];
        int sB = col[e + 2 + pg];
        float2 rA = *(const float2*)(h16 + (size_t)sA * H + li * 4);
        float2 rB = *(const float2*)(h16 + (size_t)sB * H + li * 4);
        const __half2* hA = (const __half2*)&rA;
        const __half2* hB = (const __half2*)&rB;
        float2 f0, f1;
        f0 = __half22float2(hA[0]); f1 = __half22float2(hA[1]);
        a0[0] += f0.x; a0[1] += f0.y; a0[2] += f1.x; a0[3] += f1.y;
        f0 = __half22float2(hB[0]); f1 = __half22float2(hB[1]);
        b0[0] += f0.x; b0[1] += f0.y; b0[2] += f1.x; b0[3] += f1.y;
    }
    for (; e + 1 < e1; e += 2) {
        int sA = col[e + pg];
        float2 rA = *(const float2*)(h16 + (size_t)sA * H + li * 4);
        const __half2* hA = (const __half2*)&rA;
        float2 f0 = __half22float2(hA[0]), f1 = __half22float2(hA[1]);
        a0[0] += f0.x; a0[1] += f0.y; a0[2] += f1.x; a0[3] += f1.y;
    }
    if (e < e1 && pg == 0) {
        int sA = col[e];
        float2 rA = *(const float2*)(h16 + (size_t)sA * H + li * 4);
        const __half2* hA = (const __half2*)&rA;
        float2 f0 = __half22float2(hA[0]), f1 = __half22float2(hA[1]);
        a0[0] += f0.x; a0[1] += f0.y; a0[2] += f1.x; a0[3] += f1.y;
    }
#pragma unroll
    for (int j = 0; j < 4; ++j) a0[j] += b0[j] + c0[j] + d0[j];
#pragma unroll
    for (int j = 0; j < 4; ++j) a0[j] += __shfl_xor(a0[j], 32);
    if (pg == 0) {
        int d = e1 - e0;
        float inv = 1.0f / (float)(d > 1 ? d : 1);
        __half2 h01 = __floats2half2_rn(a0[0] * inv, a0[1] * inv);
        __half2 h23 = __floats2half2_rn(a0[2] * inv, a0[3] * inv);
        float2 o;
        ((__half2*)&o)[0] = h01;
        ((__half2*)&o)[1] = h23;
        *(float2*)(t16 + (size_t)node * H + li * 4) = o;
    }
}

__global__ void k_eg(float* gate, const int* gmax, float* gsum, const int* batch32) {
    int n = blockIdx.x * blockDim.x + threadIdx.x;
    if (n < N_NODES) {
        int g = batch32[n];
        float e = expf(gate[n] - dec_f(gmax[g]));
        gate[n] = e;
        atomicAdd(&gsum[g], e);
    }
}

// ---------- pooled[g,:] += h[n,:] * eg[n]/gsum[g] ----------
#define POOL_NPB 256
__global__ __launch_bounds__(128) void k_pool(const float* __restrict__ h,
                                              const float* __restrict__ eg,
                                              const float* __restrict__ gsum,
                                              const int* __restrict__ batch32,
                                              float* __restrict__ pooled) {
    int c = threadIdx.x;
    int n0 = blockIdx.x * POOL_NPB;
    int n1 = n0 + POOL_NPB; if (n1 > N_NODES) n1 = N_NODES;
    if (n0 >= N_NODES) return;
    int cur = batch32[n0];
    float acc = 0.f;
    for (int n = n0; n < n1; ++n) {
        int g = batch32[n];
        if (g != cur) {
            atomicAdd(&pooled[(size_t)cur * H + c], acc);
            acc = 0.f; cur = g;
        }
        float w = eg[n] / gsum[g];
        acc += h[(size_t)n * H + c] * w;
    }
    atomicAdd(&pooled[(size_t)cur * H + c], acc);
}

// ---------- classifier ----------
__global__ __launch_bounds__(64) void k_cls(const float* __restrict__ pooled,
                                            const float* __restrict__ w1,
                                            const float* __restrict__ b1,
                                            const float* __restrict__ w2,
                                            const float* __restrict__ b2,
                                            float* __restrict__ out) {
    __shared__ float sp[64];
    int g = blockIdx.x;
    int lane = threadIdx.x;
    float r0 = pooled[(size_t)g * H + lane];
    float r1 = pooled[(size_t)g * H + 64 + lane];
    float acc = b1[lane];
#pragma unroll 16
    for (int k = 0; k < 64; ++k) acc += __shfl(r0, k) * w1[k * 64 + lane];
#pragma unroll 16
    for (int k = 0; k < 64; ++k) acc += __shfl(r1, k) * w1[(64 + k) * 64 + lane];
    sp[lane] = fmaxf(acc, 0.f);
    __syncthreads();
    if (lane < NUM_CLASSES) {
        float o = b2[lane];
        for (int c = 0; c < 64; ++c) o += sp[c] * w2[c * NUM_CLASSES + lane];
        out[g * NUM_CLASSES + lane] = o;
    }
}

extern "C" void kernel_launch(void* const* d_in, const int* in_sizes, int n_in,
                              void* d_out, int out_size, void* d_ws, size_t ws_size,
                              hipStream_t stream) {
    const float* x       = (const float*)d_in[0];
    const int*   eraw    = (const int*)d_in[1];
    const int*   braw    = (const int*)d_in[2];
    const float* proj_w  = (const float*)d_in[3];
    const float* proj_b  = (const float*)d_in[4];
    const float* lin_l_w = (const float*)d_in[5];
    const float* lin_l_b = (const float*)d_in[6];
    const float* lin_r_w = (const float*)d_in[7];
    const float* ln_g    = (const float*)d_in[8];
    const float* ln_b    = (const float*)d_in[9];
    const float* gate_w1 = (const float*)d_in[10];
    const float* gate_b1 = (const float*)d_in[11];
    const float* gate_w2 = (const float*)d_in[12];
    const float* gate_b2 = (const float*)d_in[13];
    const float* cls_w1  = (const float*)d_in[14];
    const float* cls_b1  = (const float*)d_in[15];
    const float* cls_w2  = (const float*)d_in[16];
    const float* cls_b2  = (const float*)d_in[17];
    float* out = (float*)d_out;

    // workspace layout
    float*  h      = (float*)d_ws;                        // N*H f32
    __half* h16    = (__half*)(h + (size_t)N_NODES * H);  // N*H f16
    __half* t16    = h16 + (size_t)N_NODES * H;           // N*H f16
    float*  gate   = (float*)(t16 + (size_t)N_NODES * H); // N
    float*  gsum   = gate + N_NODES;                      // 512
    float*  pooled = gsum + NUM_GRAPHS;                   // 512*H
    __half* W16t   = (__half*)(pooled + NUM_GRAPHS * H);  // 3*128*256
    __half* W16g   = W16t + (size_t)NUM_LAYERS * 32768;   // 64*128
    int* flags     = (int*)(W16g + 64 * 128);             // 4
    int* col       = flags + 4;                           // E
    int* batch32   = col + N_EDGES;                       // N
    int* deg       = batch32 + N_NODES;                   // N
    int* rowptr    = deg + N_NODES;                       // N+1
    int* cursor    = rowptr + N_NODES + 1;                // N
    int* bsums     = cursor + N_NODES;                    // 256
    int* gmax      = bsums + 256;                         // 512
    int* bcnt      = gmax + 512;                          // 512
    int* boff      = bcnt + 512;                          // 513
    int* bcursor   = boff + 513;                          // 512
    unsigned int* br = (unsigned int*)(bcursor + 512);    // E packed records

    const int nbN = (N_NODES + 255) / 256;
    const int nbE4 = (N_EDGES + EPB - 1) / EPB;           // 391
    const int nbS = (N_NODES + 511) / 512;                // 196
    const int nbW = (N_NODES + 3) / 4;
    const int nbG = (N_NODES + 63) / 64;                  // 1563
    const int nbP = (NUM_LAYERS * 128 * 256 + 64 * 128 + 255) / 256;

    k_detect<<<1, 1, 0, stream>>>(eraw, braw, flags);
    k_init<<<nbN, 256, 0, stream>>>(gmax, gsum, pooled, bcnt);
    k_conv_batch<<<nbN, 256, 0, stream>>>(braw, flags, batch32);
    // CSR build (bucketed)
    k_bhist<<<512, 256, 0, stream>>>(eraw, flags, bcnt);
    k_bscan<<<1, 512, 0, stream>>>(bcnt, boff, bcursor);
    k_bucket<<<nbE4, 256, 0, stream>>>(eraw, flags, bcursor, br);
    k_bdeg<<<NBKT, 256, 0, stream>>>(br, boff, deg);
    k_scan1<<<nbS, 256, 0, stream>>>(deg, rowptr, bsums);
    k_scan2<<<1, 256, 0, stream>>>(bsums, nbS);
    k_scan3<<<nbN, 256, 0, stream>>>(rowptr, bsums, cursor);
    k_scatter2<<<NBKT, 256, 0, stream>>>(br, boff, rowptr, cursor, col);
    // weights to fp16 transposed
    k_prepw<<<nbP, 256, 0, stream>>>(lin_l_w, lin_r_w, gate_w1, W16t, W16g);

    // h = relu(x @ proj_w + proj_b), also h16
    k_gemm_proj<<<nbG, 256, 0, stream>>>(x, proj_w, proj_b, h, h16, N_NODES, NDIM);

    for (int l = 0; l < NUM_LAYERS; ++l) {
        const float* bl  = lin_l_b + (size_t)l * H;
        const float* gl  = ln_g + (size_t)l * H;
        const float* blb = ln_b + (size_t)l * H;
        k_aggr<<<nbW, 256, 0, stream>>>(h16, rowptr, col, t16);
        k_layer_mfma<<<nbG, 256, 0, stream>>>(t16, h, h16, W16t + (size_t)l * 32768, bl, gl, blb);
    }

    // gate (MFMA fused GEMM + dot + segment max), then segment softmax-pool
    k_gate_mfma<<<nbG, 256, 0, stream>>>(h16, W16g, gate_b1, gate_w2, gate_b2, batch32, gate, gmax);
    k_eg<<<nbN, 256, 0, stream>>>(gate, gmax, gsum, batch32);
    k_pool<<<(N_NODES + POOL_NPB - 1) / POOL_NPB, 128, 0, stream>>>(h, gate, gsum, batch32, pooled);
    k_cls<<<NUM_GRAPHS, 64, 0, stream>>>(pooled, cls_w1, cls_b1, cls_w2, cls_b2, out);
}

// Round 7
// 644.295 us; speedup vs baseline: 2.7887x; 1.3557x over previous
//
#include <hip/hip_runtime.h>
#include <hip/hip_fp16.h>
#include <math.h>

#define N_NODES   100000
#define N_EDGES   1600000
#define NDIM      64
#define H         128
#define NUM_LAYERS 3
#define NUM_CLASSES 6
#define NUM_GRAPHS 512
#define LN_EPS    1e-5f
#define NBKT      391           // ceil(N_NODES / 256)
#define SCAP      5376          // phase-B LDS col capacity (bucket mean 4092, std 64)

typedef _Float16 f16x8 __attribute__((ext_vector_type(8)));
typedef float    f32x4 __attribute__((ext_vector_type(4)));

// ---------- helpers ----------
__device__ __forceinline__ int idx_at(const int* raw, int is64, int i) {
    return is64 ? raw[2 * (long long)i] : raw[i];
}
__device__ __forceinline__ int lower_bound(const int* a, int n, int v) {
    int lo = 0, hi = n;
    while (lo < hi) { int m = (lo + hi) >> 1; if (a[m] < v) lo = m + 1; else hi = m; }
    return lo;
}

// ---------- dtype detection ----------
__global__ void k_detect(const int* eraw, const int* braw, int* flags) {
    if (threadIdx.x == 0 && blockIdx.x == 0) {
        int e64 = 1;
        for (int i = 1; i < 128; i += 2) if (eraw[i] != 0) { e64 = 0; break; }
        flags[0] = e64;
        flags[1] = (braw[N_NODES - 1] == 0) ? 1 : 0;
    }
}

// ---------- init (only bucket counters need zeroing now) ----------
__global__ void k_init(int* bcnt) {
    int i = blockIdx.x * blockDim.x + threadIdx.x;
    if (i < 512) bcnt[i] = 0;
}

__global__ void k_conv_batch(const int* braw, const int* flags, int* batch32) {
    int i = blockIdx.x * blockDim.x + threadIdx.x;
    if (i < N_NODES) batch32[i] = idx_at(braw, flags[1], i);
}

// ---------- bucket histogram (512 buckets by dst>>8), LDS-aggregated ----------
__global__ __launch_bounds__(256) void k_bhist(const int* eraw, const int* flags, int* bcnt) {
    __shared__ int c[512];
    int tid = threadIdx.x;
    for (int i = tid; i < 512; i += 256) c[i] = 0;
    __syncthreads();
    int f = flags[0];
    int stride = gridDim.x * 256;
    for (int e = blockIdx.x * 256 + tid; e < N_EDGES; e += stride) {
        int d = idx_at(eraw, f, N_EDGES + e);
        atomicAdd(&c[d >> 8], 1);
    }
    __syncthreads();
    for (int i = tid; i < 512; i += 256) if (c[i]) atomicAdd(&bcnt[i], c[i]);
}

// ---------- scan of 512 bucket counts -> boff[513], bcursor ----------
__global__ void k_bscan(const int* bcnt, int* boff, int* bcursor) {
    __shared__ int sh[512];
    int tid = threadIdx.x;     // 512 threads
    int v = bcnt[tid];
    sh[tid] = v;
    __syncthreads();
    for (int off = 1; off < 512; off <<= 1) {
        int u = (tid >= off) ? sh[tid - off] : 0;
        __syncthreads();
        sh[tid] += u;
        __syncthreads();
    }
    int excl = sh[tid] - v;
    boff[tid] = excl;
    bcursor[tid] = excl;
    if (tid == 511) boff[512] = sh[511];
}

// ---------- phase A: scatter packed records into bucket-contiguous regions ----------
#define EPB 4096
__global__ __launch_bounds__(256) void k_bucket(const int* eraw, const int* flags,
                                                int* bcursor, unsigned int* br) {
    __shared__ int cnt[512];
    __shared__ int lcur[512];
    int tid = threadIdx.x;
    int f = flags[0];
    int base = blockIdx.x * EPB;
    int se[16], de[16];
#pragma unroll
    for (int j = 0; j < 16; ++j) {
        int e = base + j * 256 + tid;
        if (e < N_EDGES) {
            se[j] = idx_at(eraw, f, e);
            de[j] = idx_at(eraw, f, N_EDGES + e);
        } else de[j] = -1;
    }
    for (int i = tid; i < 512; i += 256) cnt[i] = 0;
    __syncthreads();
#pragma unroll
    for (int j = 0; j < 16; ++j)
        if (de[j] >= 0) atomicAdd(&cnt[de[j] >> 8], 1);
    __syncthreads();
    for (int i = tid; i < 512; i += 256)
        lcur[i] = cnt[i] ? atomicAdd(&bcursor[i], cnt[i]) : 0;
    __syncthreads();
#pragma unroll
    for (int j = 0; j < 16; ++j)
        if (de[j] >= 0) {
            int pos = atomicAdd(&lcur[de[j] >> 8], 1);
            br[pos] = ((unsigned int)(de[j] & 255) << 24) | (unsigned int)se[j];
        }
}

// ---------- per-bucket degree count ----------
__global__ __launch_bounds__(256) void k_bdeg(const unsigned int* br, const int* boff, int* deg) {
    __shared__ int d256[256];
    int b = blockIdx.x;
    int tid = threadIdx.x;
    d256[tid] = 0;
    __syncthreads();
    int lo = boff[b], hi = boff[b + 1];
    for (int i = lo + tid; i < hi; i += 256)
        atomicAdd(&d256[br[i] >> 24], 1);
    __syncthreads();
    int node = (b << 8) + tid;
    if (node < N_NODES) deg[node] = d256[tid];
}

// ---------- scans over deg -> rowptr ----------
__global__ void k_scan1(const int* deg, int* rowptr, int* bsums) {
    __shared__ int sh[256];
    int tid = threadIdx.x;
    int i0 = blockIdx.x * 512 + tid * 2;
    int a = (i0 < N_NODES) ? deg[i0] : 0;
    int b = (i0 + 1 < N_NODES) ? deg[i0 + 1] : 0;
    int ts = a + b;
    sh[tid] = ts;
    __syncthreads();
    for (int off = 1; off < 256; off <<= 1) {
        int v = (tid >= off) ? sh[tid - off] : 0;
        __syncthreads();
        sh[tid] += v;
        __syncthreads();
    }
    int excl = sh[tid] - ts;
    if (i0 < N_NODES) rowptr[i0] = excl;
    if (i0 + 1 < N_NODES) rowptr[i0 + 1] = excl + a;
    if (tid == 255) bsums[blockIdx.x] = sh[255];
}

__global__ void k_scan2(int* bsums, int nb) {
    __shared__ int sh[256];
    int tid = threadIdx.x;
    int v = (tid < nb) ? bsums[tid] : 0;
    sh[tid] = v;
    __syncthreads();
    for (int off = 1; off < 256; off <<= 1) {
        int u = (tid >= off) ? sh[tid - off] : 0;
        __syncthreads();
        sh[tid] += u;
        __syncthreads();
    }
    if (tid < nb) bsums[tid] = sh[tid] - v;
}

__global__ void k_scan3(int* rowptr, const int* bsums, int* cursor) {
    int i = blockIdx.x * blockDim.x + threadIdx.x;
    if (i < N_NODES) {
        int r = rowptr[i] + bsums[i >> 9];
        rowptr[i] = r;
        cursor[i] = r;
    }
    if (i == 0) rowptr[N_NODES] = N_EDGES;
}

// ---------- phase B: per-bucket fine scatter via LDS staging, coalesced writeout ----------
__global__ __launch_bounds__(256) void k_scatter2(const unsigned int* br, const int* boff,
                                                  const int* rowptr, int* cursor, int* col) {
    __shared__ int lcur[256];
    __shared__ int cbuf[SCAP];
    int b = blockIdx.x;
    int tid = threadIdx.x;
    int lo = boff[b], hi = boff[b + 1];
    int wsize = hi - lo;
    int node = (b << 8) + tid;
    lcur[tid] = rowptr[node < N_NODES ? node : N_NODES] - lo;
    __syncthreads();
    if (wsize <= SCAP) {
        for (int i = lo + tid; i < hi; i += 256) {
            unsigned int r = br[i];
            int p = atomicAdd(&lcur[r >> 24], 1);
            cbuf[p] = (int)(r & 0xFFFFFF);
        }
        __syncthreads();
        for (int j = tid; j < wsize; j += 256) col[lo + j] = cbuf[j];
    } else {
        for (int i = lo + tid; i < hi; i += 256) {
            unsigned int r = br[i];
            int d = (b << 8) + (int)(r >> 24);
            int p = atomicAdd(&cursor[d], 1);
            col[p] = (int)(r & 0xFFFFFF);
        }
    }
}

// ---------- weight prep ----------
// W16t[l][n*256+k] = fp16 of (k<128 ? Wl[k][n] : Wr[k-128][n])   (3*32768 elems)
// W16g[n*128+k]    = fp16 of gate_w1[k][n]                       (8192 elems)
__global__ void k_prepw(const float* __restrict__ lin_l_w, const float* __restrict__ lin_r_w,
                        const float* __restrict__ gate_w1,
                        __half* __restrict__ W16t, __half* __restrict__ W16g) {
    int i = blockIdx.x * 256 + threadIdx.x;
    if (i < NUM_LAYERS * 128 * 256) {
        int l = i >> 15;
        int rem = i & 32767;
        int n = rem >> 8;
        int k = rem & 255;
        float v = (k < 128) ? lin_l_w[(size_t)l * 16384 + k * 128 + n]
                            : lin_r_w[(size_t)l * 16384 + (k - 128) * 128 + n];
        W16t[(size_t)l * 32768 + n * 256 + k] = __float2half(v);
    } else if (i < NUM_LAYERS * 128 * 256 + 64 * 128) {
        int idx = i - NUM_LAYERS * 128 * 256;
        int n = idx >> 7;      // 0..63
        int k = idx & 127;     // 0..127
        W16g[n * 128 + k] = __float2half(gate_w1[k * 64 + n]);
    }
}

// ---------- tiled fp32 GEMM (COLS=128): h16 = fp16(relu(A[n,K] @ W + bias)) ----------
__global__ __launch_bounds__(256) void k_gemm_proj(const float* __restrict__ A,
                                                   const float* __restrict__ W,
                                                   const float* __restrict__ bias,
                                                   __half* __restrict__ C16,
                                                   int nrows, int K) {
    __shared__ float As_t[32][68];
    __shared__ float Ws[32 * 128];
    int tid = threadIdx.x;
    int row0 = blockIdx.x * 64;
    int tr = tid >> 4;
    int tc = tid & 15;
    int c0 = tc * 8;
    float acc[4][8];
#pragma unroll
    for (int i = 0; i < 4; ++i)
#pragma unroll
        for (int j = 0; j < 8; ++j) acc[i][j] = 0.f;

    for (int kc = 0; kc < K; kc += 32) {
        __syncthreads();
#pragma unroll
        for (int it = 0; it < 2; ++it) {
            int idx = tid + it * 256;
            int r = idx >> 3, c4 = idx & 7;
            int gr = row0 + r;
            float4 v = make_float4(0.f, 0.f, 0.f, 0.f);
            if (gr < nrows) v = *(const float4*)(A + (size_t)gr * K + kc + c4 * 4);
            As_t[c4 * 4 + 0][r] = v.x;
            As_t[c4 * 4 + 1][r] = v.y;
            As_t[c4 * 4 + 2][r] = v.z;
            As_t[c4 * 4 + 3][r] = v.w;
        }
#pragma unroll
        for (int it = 0; it < 4; ++it) {
            int idx = tid + it * 256;
            int r = idx >> 5, c4 = idx & 31;
            *(float4*)(&Ws[r * 128 + c4 * 4]) = *(const float4*)(W + (size_t)(kc + r) * 128 + c4 * 4);
        }
        __syncthreads();
#pragma unroll
        for (int k = 0; k < 32; ++k) {
            float4 a4 = *(const float4*)(&As_t[k][tr * 4]);
            float a[4] = {a4.x, a4.y, a4.z, a4.w};
            float4 w0 = *(const float4*)(&Ws[k * 128 + c0]);
            float4 w1 = *(const float4*)(&Ws[k * 128 + c0 + 4]);
            float w[8] = {w0.x, w0.y, w0.z, w0.w, w1.x, w1.y, w1.z, w1.w};
#pragma unroll
            for (int i = 0; i < 4; ++i)
#pragma unroll
                for (int j = 0; j < 8; ++j) acc[i][j] += a[i] * w[j];
        }
    }
    float bv[8];
#pragma unroll
    for (int j = 0; j < 8; ++j) bv[j] = bias[c0 + j];
#pragma unroll
    for (int i = 0; i < 4; ++i) {
        int gr = row0 + tr * 4 + i;
        if (gr < nrows) {
            float o[8];
#pragma unroll
            for (int j = 0; j < 8; ++j) o[j] = fmaxf(acc[i][j] + bv[j], 0.f);
            __half2 p[4];
#pragma unroll
            for (int j = 0; j < 8; j += 2) p[j / 2] = __floats2half2_rn(o[j], o[j + 1]);
            *(float4*)(C16 + (size_t)gr * 128 + c0) = *(float4*)p;
        }
    }
}

// ---------- MFMA gate: gate[n] = relu(h16[n,:]@W16g^T + b1) . w2 + b2  (no atomics) ----------
__global__ __launch_bounds__(256) void k_gate_mfma(const __half* __restrict__ h16,
                                                   const __half* __restrict__ W16g,
                                                   const float* __restrict__ b1,
                                                   const float* __restrict__ w2,
                                                   const float* __restrict__ b2,
                                                   float* __restrict__ gate) {
    int tid = threadIdx.x;
    int wave = tid >> 6, lane = tid & 63;
    int s = lane & 15, quad = lane >> 4;
    int row0 = blockIdx.x * 64 + wave * 16;
    int arow = row0 + s;
    if (arow >= N_NODES) arow = N_NODES - 1;

    f32x4 acc[4];
#pragma unroll
    for (int c = 0; c < 4; ++c) acc[c] = (f32x4){0.f, 0.f, 0.f, 0.f};

#pragma unroll
    for (int kc = 0; kc < 128; kc += 32) {
        f16x8 afrag = *(const f16x8*)(h16 + (size_t)arow * H + kc + quad * 8);
#pragma unroll
        for (int c = 0; c < 4; ++c) {
            f16x8 bfrag = *(const f16x8*)(W16g + (size_t)(c * 16 + s) * 128 + kc + quad * 8);
            acc[c] = __builtin_amdgcn_mfma_f32_16x16x32_f16(afrag, bfrag, acc[c], 0, 0, 0);
        }
    }
    float part[4] = {0.f, 0.f, 0.f, 0.f};
#pragma unroll
    for (int c = 0; c < 4; ++c) {
        float bv = b1[c * 16 + s];
        float wv = w2[c * 16 + s];
#pragma unroll
        for (int i = 0; i < 4; ++i)
            part[i] += fmaxf(acc[c][i] + bv, 0.f) * wv;
    }
#pragma unroll
    for (int off = 1; off < 16; off <<= 1) {
#pragma unroll
        for (int i = 0; i < 4; ++i) part[i] += __shfl_xor(part[i], off);
    }
    if (s == 0) {
        float b2v = b2[0];
#pragma unroll
        for (int i = 0; i < 4; ++i) {
            int r = row0 + quad * 4 + i;
            if (r < N_NODES) gate[r] = part[i] + b2v;
        }
    }
}

// ---------- per-graph softmax over sorted batch: gate -> exp(gate-max), gsum[g] ----------
__global__ __launch_bounds__(64) void k_softmax_g(float* __restrict__ gate,
                                                  const int* __restrict__ batch32,
                                                  float* __restrict__ gsum) {
    int g = blockIdx.x;
    int lane = threadIdx.x;
    int n0 = lower_bound(batch32, N_NODES, g);
    int n1 = lower_bound(batch32, N_NODES, g + 1);
    float m = -INFINITY;
    for (int n = n0 + lane; n < n1; n += 64) m = fmaxf(m, gate[n]);
#pragma unroll
    for (int off = 32; off >= 1; off >>= 1) m = fmaxf(m, __shfl_xor(m, off));
    float s = 0.f;
    for (int n = n0 + lane; n < n1; n += 64) {
        float e = expf(gate[n] - m);
        gate[n] = e;
        s += e;
    }
#pragma unroll
    for (int off = 32; off >= 1; off >>= 1) s += __shfl_xor(s, off);
    if (lane == 0) gsum[g] = s;
}

// ---------- per-graph pooling: pooled[g,:] = sum(e_n * h16[n,:]) / gsum[g]  (no atomics) ----------
__global__ __launch_bounds__(256) void k_pool_g(const __half* __restrict__ h16,
                                                const float* __restrict__ eg,
                                                const float* __restrict__ gsum,
                                                const int* __restrict__ batch32,
                                                float* __restrict__ pooled) {
    __shared__ float sacc[256];
    int g = blockIdx.x;
    int tid = threadIdx.x;
    int c = tid & 127;
    int p = tid >> 7;
    int n0 = lower_bound(batch32, N_NODES, g);
    int n1 = lower_bound(batch32, N_NODES, g + 1);
    float acc = 0.f;
    for (int n = n0 + p; n < n1; n += 2)
        acc += eg[n] * __half2float(h16[(size_t)n * H + c]);
    sacc[tid] = acc;
    __syncthreads();
    if (tid < 128) {
        float s = gsum[g];
        float v = sacc[tid] + sacc[tid + 128];
        pooled[(size_t)g * H + tid] = (n1 > n0) ? v / s : 0.f;
    }
}

// ---------- MFMA fused SAGE layer: h16 = fp16(elu(LN([t16|h16]@[Wl;Wr] + bl)) + h16) ----------
__global__ __launch_bounds__(256) void k_layer_mfma(const __half* __restrict__ t16,
                                                    __half* __restrict__ h16,
                                                    const __half* __restrict__ W16t,
                                                    const float* __restrict__ bl,
                                                    const float* __restrict__ g,
                                                    const float* __restrict__ bb) {
    int tid = threadIdx.x;
    int wave = tid >> 6, lane = tid & 63;
    int s = lane & 15, quad = lane >> 4;
    int row0 = blockIdx.x * 64 + wave * 16;
    int arow = row0 + s;
    if (arow >= N_NODES) arow = N_NODES - 1;

    f32x4 acc[8];
#pragma unroll
    for (int c = 0; c < 8; ++c) acc[c] = (f32x4){0.f, 0.f, 0.f, 0.f};

#pragma unroll
    for (int kc = 0; kc < 256; kc += 32) {
        const __half* asrc = (kc < 128) ? t16 : h16;
        int koff = kc & 127;
        f16x8 afrag = *(const f16x8*)(asrc + (size_t)arow * H + koff + quad * 8);
#pragma unroll
        for (int c = 0; c < 8; ++c) {
            f16x8 bfrag = *(const f16x8*)(W16t + (size_t)(c * 16 + s) * 256 + kc + quad * 8);
            acc[c] = __builtin_amdgcn_mfma_f32_16x16x32_f16(afrag, bfrag, acc[c], 0, 0, 0);
        }
    }
    float y[8][4];
    float sm[4] = {0.f, 0.f, 0.f, 0.f}, sq[4] = {0.f, 0.f, 0.f, 0.f};
#pragma unroll
    for (int c = 0; c < 8; ++c) {
        float bv = bl[c * 16 + s];
#pragma unroll
        for (int i = 0; i < 4; ++i) {
            float v = acc[c][i] + bv;
            y[c][i] = v;
            sm[i] += v;
            sq[i] += v * v;
        }
    }
#pragma unroll
    for (int off = 1; off < 16; off <<= 1) {
#pragma unroll
        for (int i = 0; i < 4; ++i) {
            sm[i] += __shfl_xor(sm[i], off);
            sq[i] += __shfl_xor(sq[i], off);
        }
    }
    float mean[4], rstd[4];
#pragma unroll
    for (int i = 0; i < 4; ++i) {
        mean[i] = sm[i] * (1.0f / H);
        float var = sq[i] * (1.0f / H) - mean[i] * mean[i];
        rstd[i] = rsqrtf(var + LN_EPS);
    }
#pragma unroll
    for (int i = 0; i < 4; ++i) {
        int r = row0 + quad * 4 + i;
        if (r < N_NODES) {
#pragma unroll
            for (int c = 0; c < 8; ++c) {
                int colj = c * 16 + s;
                float yv = (y[c][i] - mean[i]) * rstd[i] * g[colj] + bb[colj];
                yv = yv > 0.f ? yv : expf(yv) - 1.f;
                float o = yv + __half2float(h16[(size_t)r * H + colj]);
                h16[(size_t)r * H + colj] = __float2half(o);
            }
        }
    }
}

// ---------- mean aggregation: wave per node, 32-lane groups, 4 edges in flight each ----------
__global__ __launch_bounds__(256) void k_aggr(const __half* __restrict__ h16,
                                              const int* __restrict__ rowptr,
                                              const int* __restrict__ col,
                                              __half* __restrict__ t16) {
    int lane = threadIdx.x & 63;
    int node = blockIdx.x * 4 + (threadIdx.x >> 6);
    if (node >= N_NODES) return;
    int li = lane & 31;       // covers cols 4li..4li+3 (8 B)
    int pg = lane >> 5;       // edge-parity group
    int e0 = rowptr[node], e1 = rowptr[node + 1];
    float a0[4] = {0.f, 0.f, 0.f, 0.f};
    float b0[4] = {0.f, 0.f, 0.f, 0.f};
    float c0[4] = {0.f, 0.f, 0.f, 0.f};
    float d0[4] = {0.f, 0.f, 0.f, 0.f};
    int e = e0;
    for (; e + 7 < e1; e += 8) {
        int sA = col[e + pg];
        int sB = col[e + 2 + pg];
        int sC = col[e + 4 + pg];
        int sD = col[e + 6 + pg];
        float2 rA = *(const float2*)(h16 + (size_t)sA * H + li * 4);
        float2 rB = *(const float2*)(h16 + (size_t)sB * H + li * 4);
        float2 rC = *(const float2*)(h16 + (size_t)sC * H + li * 4);
        float2 rD = *(const float2*)(h16 + (size_t)sD * H + li * 4);
        const __half2* hA = (const __half2*)&rA;
        const __half2* hB = (const __half2*)&rB;
        const __half2* hC = (const __half2*)&rC;
        const __half2* hD = (const __half2*)&rD;
        float2 f0, f1;
        f0 = __half22float2(hA[0]); f1 = __half22float2(hA[1]);
        a0[0] += f0.x; a0[1] += f0.y; a0[2] += f1.x; a0[3] += f1.y;
        f0 = __half22float2(hB[0]); f1 = __half22float2(hB[1]);
        b0[0] += f0.x; b0[1] += f0.y; b0[2] += f1.x; b0[3] += f1.y;
        f0 = __half22float2(hC[0]); f1 = __half22float2(hC[1]);
        c0[0] += f0.x; c0[1] += f0.y; c0[2] += f1.x; c0[3] += f1.y;
        f0 = __half22float2(hD[0]); f1 = __half22float2(hD[1]);
        d0[0] += f0.x; d0[1] += f0.y; d0[2] += f1.x; d0[3] += f1.y;
    }
    for (; e + 3 < e1; e += 4) {
        int sA = col[e + pg];
        int sB = col[e + 2 + pg];
        float2 rA = *(const float2*)(h16 + (size_t)sA * H + li * 4);
        float2 rB = *(const float2*)(h16 + (size_t)sB * H + li * 4);
        const __half2* hA = (const __half2*)&rA;
        const __half2* hB = (const __half2*)&rB;
        float2 f0, f1;
        f0 = __half22float2(hA[0]); f1 = __half22float2(hA[1]);
        a0[0] += f0.x; a0[1] += f0.y; a0[2] += f1.x; a0[3] += f1.y;
        f0 = __half22float2(hB[0]); f1 = __half22float2(hB[1]);
        b0[0] += f0.x; b0[1] += f0.y; b0[2] += f1.x; b0[3] += f1.y;
    }
    for (; e + 1 < e1; e += 2) {
        int sA = col[e + pg];
        float2 rA = *(const float2*)(h16 + (size_t)sA * H + li * 4);
        const __half2* hA = (const __half2*)&rA;
        float2 f0 = __half22float2(hA[0]), f1 = __half22float2(hA[1]);
        a0[0] += f0.x; a0[1] += f0.y; a0[2] += f1.x; a0[3] += f1.y;
    }
    if (e < e1 && pg == 0) {
        int sA = col[e];
        float2 rA = *(const float2*)(h16 + (size_t)sA * H + li * 4);
        const __half2* hA = (const __half2*)&rA;
        float2 f0 = __half22float2(hA[0]), f1 = __half22float2(hA[1]);
        a0[0] += f0.x; a0[1] += f0.y; a0[2] += f1.x; a0[3] += f1.y;
    }
#pragma unroll
    for (int j = 0; j < 4; ++j) a0[j] += b0[j] + c0[j] + d0[j];
#pragma unroll
    for (int j = 0; j < 4; ++j) a0[j] += __shfl_xor(a0[j], 32);
    if (pg == 0) {
        int d = e1 - e0;
        float inv = 1.0f / (float)(d > 1 ? d : 1);
        __half2 h01 = __floats2half2_rn(a0[0] * inv, a0[1] * inv);
        __half2 h23 = __floats2half2_rn(a0[2] * inv, a0[3] * inv);
        float2 o;
        ((__half2*)&o)[0] = h01;
        ((__half2*)&o)[1] = h23;
        *(float2*)(t16 + (size_t)node * H + li * 4) = o;
    }
}

// ---------- classifier ----------
__global__ __launch_bounds__(64) void k_cls(const float* __restrict__ pooled,
                                            const float* __restrict__ w1,
                                            const float* __restrict__ b1,
                                            const float* __restrict__ w2,
                                            const float* __restrict__ b2,
                                            float* __restrict__ out) {
    __shared__ float sp[64];
    int g = blockIdx.x;
    int lane = threadIdx.x;
    float r0 = pooled[(size_t)g * H + lane];
    float r1 = pooled[(size_t)g * H + 64 + lane];
    float acc = b1[lane];
#pragma unroll 16
    for (int k = 0; k < 64; ++k) acc += __shfl(r0, k) * w1[k * 64 + lane];
#pragma unroll 16
    for (int k = 0; k < 64; ++k) acc += __shfl(r1, k) * w1[(64 + k) * 64 + lane];
    sp[lane] = fmaxf(acc, 0.f);
    __syncthreads();
    if (lane < NUM_CLASSES) {
        float o = b2[lane];
        for (int c = 0; c < 64; ++c) o += sp[c] * w2[c * NUM_CLASSES + lane];
        out[g * NUM_CLASSES + lane] = o;
    }
}

extern "C" void kernel_launch(void* const* d_in, const int* in_sizes, int n_in,
                              void* d_out, int out_size, void* d_ws, size_t ws_size,
                              hipStream_t stream) {
    const float* x       = (const float*)d_in[0];
    const int*   eraw    = (const int*)d_in[1];
    const int*   braw    = (const int*)d_in[2];
    const float* proj_w  = (const float*)d_in[3];
    const float* proj_b  = (const float*)d_in[4];
    const float* lin_l_w = (const float*)d_in[5];
    const float* lin_l_b = (const float*)d_in[6];
    const float* lin_r_w = (const float*)d_in[7];
    const float* ln_g    = (const float*)d_in[8];
    const float* ln_b    = (const float*)d_in[9];
    const float* gate_w1 = (const float*)d_in[10];
    const float* gate_b1 = (const float*)d_in[11];
    const float* gate_w2 = (const float*)d_in[12];
    const float* gate_b2 = (const float*)d_in[13];
    const float* cls_w1  = (const float*)d_in[14];
    const float* cls_b1  = (const float*)d_in[15];
    const float* cls_w2  = (const float*)d_in[16];
    const float* cls_b2  = (const float*)d_in[17];
    float* out = (float*)d_out;

    // workspace layout (fp32 h eliminated)
    __half* h16    = (__half*)d_ws;                       // N*H f16
    __half* t16    = h16 + (size_t)N_NODES * H;           // N*H f16
    float*  gate   = (float*)(t16 + (size_t)N_NODES * H); // N
    float*  gsum   = gate + N_NODES;                      // 512
    float*  pooled = gsum + NUM_GRAPHS;                   // 512*H
    __half* W16t   = (__half*)(pooled + NUM_GRAPHS * H);  // 3*128*256
    __half* W16g   = W16t + (size_t)NUM_LAYERS * 32768;   // 64*128
    int* flags     = (int*)(W16g + 64 * 128);             // 4
    int* col       = flags + 4;                           // E
    int* batch32   = col + N_EDGES;                       // N
    int* deg       = batch32 + N_NODES;                   // N
    int* rowptr    = deg + N_NODES;                       // N+1
    int* cursor    = rowptr + N_NODES + 1;                // N
    int* bsums     = cursor + N_NODES;                    // 256
    int* bcnt      = bsums + 256;                         // 512
    int* boff      = bcnt + 512;                          // 513
    int* bcursor   = boff + 513;                          // 512
    unsigned int* br = (unsigned int*)(bcursor + 512);    // E packed records

    const int nbN = (N_NODES + 255) / 256;
    const int nbE4 = (N_EDGES + EPB - 1) / EPB;           // 391
    const int nbS = (N_NODES + 511) / 512;                // 196
    const int nbW = (N_NODES + 3) / 4;
    const int nbG = (N_NODES + 63) / 64;                  // 1563
    const int nbP = (NUM_LAYERS * 128 * 256 + 64 * 128 + 255) / 256;

    k_detect<<<1, 1, 0, stream>>>(eraw, braw, flags);
    k_init<<<2, 256, 0, stream>>>(bcnt);
    k_conv_batch<<<nbN, 256, 0, stream>>>(braw, flags, batch32);
    // CSR build (bucketed)
    k_bhist<<<512, 256, 0, stream>>>(eraw, flags, bcnt);
    k_bscan<<<1, 512, 0, stream>>>(bcnt, boff, bcursor);
    k_bucket<<<nbE4, 256, 0, stream>>>(eraw, flags, bcursor, br);
    k_bdeg<<<NBKT, 256, 0, stream>>>(br, boff, deg);
    k_scan1<<<nbS, 256, 0, stream>>>(deg, rowptr, bsums);
    k_scan2<<<1, 256, 0, stream>>>(bsums, nbS);
    k_scan3<<<nbN, 256, 0, stream>>>(rowptr, bsums, cursor);
    k_scatter2<<<NBKT, 256, 0, stream>>>(br, boff, rowptr, cursor, col);
    // weights to fp16 transposed
    k_prepw<<<nbP, 256, 0, stream>>>(lin_l_w, lin_r_w, gate_w1, W16t, W16g);

    // h16 = fp16(relu(x @ proj_w + proj_b))
    k_gemm_proj<<<nbG, 256, 0, stream>>>(x, proj_w, proj_b, h16, N_NODES, NDIM);

    for (int l = 0; l < NUM_LAYERS; ++l) {
        const float* bl  = lin_l_b + (size_t)l * H;
        const float* gl  = ln_g + (size_t)l * H;
        const float* blb = ln_b + (size_t)l * H;
        k_aggr<<<nbW, 256, 0, stream>>>(h16, rowptr, col, t16);
        k_layer_mfma<<<nbG, 256, 0, stream>>>(t16, h16, W16t + (size_t)l * 32768, bl, gl, blb);
    }

    // gate (atomic-free) -> per-graph softmax -> per-graph pooling -> classifier
    k_gate_mfma<<<nbG, 256, 0, stream>>>(h16, W16g, gate_b1, gate_w2, gate_b2, gate);
    k_softmax_g<<<NUM_GRAPHS, 64, 0, stream>>>(gate, batch32, gsum);
    k_pool_g<<<NUM_GRAPHS, 256, 0, stream>>>(h16, gate, gsum, batch32, pooled);
    k_cls<<<NUM_GRAPHS, 64, 0, stream>>>(pooled, cls_w1, cls_b1, cls_w2, cls_b2, out);
}

// Round 8
// 507.522 us; speedup vs baseline: 3.5402x; 1.2695x over previous
//
#include <hip/hip_runtime.h>
#include <hip/hip_fp16.h>
#include <math.h>

#define N_NODES   100000
#define N_EDGES   1600000
#define NDIM      64
#define H         128
#define NUM_LAYERS 3
#define NUM_CLASSES 6
#define NUM_GRAPHS 512
#define LN_EPS    1e-5f
#define NBKT      391           // ceil(N_NODES / 256)
#define SCAP      5376          // phase-B LDS col capacity (bucket mean 4092, std 64)
#define BPAD      136           // padded LDS row stride (halves): stride 68 dwords == 4 mod 32 -> ~2-way reads

typedef _Float16 f16x8 __attribute__((ext_vector_type(8)));
typedef float    f32x4 __attribute__((ext_vector_type(4)));

// ---------- helpers ----------
__device__ __forceinline__ int idx_at(const int* raw, int is64, int i) {
    return is64 ? raw[2 * (long long)i] : raw[i];
}
__device__ __forceinline__ int lower_bound(const int* a, int n, int v) {
    int lo = 0, hi = n;
    while (lo < hi) { int m = (lo + hi) >> 1; if (a[m] < v) lo = m + 1; else hi = m; }
    return lo;
}

// ---------- dtype detection ----------
__global__ void k_detect(const int* eraw, const int* braw, int* flags) {
    if (threadIdx.x == 0 && blockIdx.x == 0) {
        int e64 = 1;
        for (int i = 1; i < 128; i += 2) if (eraw[i] != 0) { e64 = 0; break; }
        flags[0] = e64;
        flags[1] = (braw[N_NODES - 1] == 0) ? 1 : 0;
    }
}

// ---------- init ----------
__global__ void k_init(int* bcnt) {
    int i = blockIdx.x * blockDim.x + threadIdx.x;
    if (i < 512) bcnt[i] = 0;
}

__global__ void k_conv_batch(const int* braw, const int* flags, int* batch32) {
    int i = blockIdx.x * blockDim.x + threadIdx.x;
    if (i < N_NODES) batch32[i] = idx_at(braw, flags[1], i);
}

// ---------- bucket histogram (512 buckets by dst>>8), LDS-aggregated ----------
__global__ __launch_bounds__(256) void k_bhist(const int* eraw, const int* flags, int* bcnt) {
    __shared__ int c[512];
    int tid = threadIdx.x;
    for (int i = tid; i < 512; i += 256) c[i] = 0;
    __syncthreads();
    int f = flags[0];
    int stride = gridDim.x * 256;
    for (int e = blockIdx.x * 256 + tid; e < N_EDGES; e += stride) {
        int d = idx_at(eraw, f, N_EDGES + e);
        atomicAdd(&c[d >> 8], 1);
    }
    __syncthreads();
    for (int i = tid; i < 512; i += 256) if (c[i]) atomicAdd(&bcnt[i], c[i]);
}

// ---------- scan of 512 bucket counts -> boff[513], bcursor ----------
__global__ void k_bscan(const int* bcnt, int* boff, int* bcursor) {
    __shared__ int sh[512];
    int tid = threadIdx.x;     // 512 threads
    int v = bcnt[tid];
    sh[tid] = v;
    __syncthreads();
    for (int off = 1; off < 512; off <<= 1) {
        int u = (tid >= off) ? sh[tid - off] : 0;
        __syncthreads();
        sh[tid] += u;
        __syncthreads();
    }
    int excl = sh[tid] - v;
    boff[tid] = excl;
    bcursor[tid] = excl;
    if (tid == 511) boff[512] = sh[511];
}

// ---------- phase A: scatter packed records into bucket-contiguous regions ----------
#define EPB 4096
__global__ __launch_bounds__(256) void k_bucket(const int* eraw, const int* flags,
                                                int* bcursor, unsigned int* br) {
    __shared__ int cnt[512];
    __shared__ int lcur[512];
    int tid = threadIdx.x;
    int f = flags[0];
    int base = blockIdx.x * EPB;
    int se[16], de[16];
#pragma unroll
    for (int j = 0; j < 16; ++j) {
        int e = base + j * 256 + tid;
        if (e < N_EDGES) {
            se[j] = idx_at(eraw, f, e);
            de[j] = idx_at(eraw, f, N_EDGES + e);
        } else de[j] = -1;
    }
    for (int i = tid; i < 512; i += 256) cnt[i] = 0;
    __syncthreads();
#pragma unroll
    for (int j = 0; j < 16; ++j)
        if (de[j] >= 0) atomicAdd(&cnt[de[j] >> 8], 1);
    __syncthreads();
    for (int i = tid; i < 512; i += 256)
        lcur[i] = cnt[i] ? atomicAdd(&bcursor[i], cnt[i]) : 0;
    __syncthreads();
#pragma unroll
    for (int j = 0; j < 16; ++j)
        if (de[j] >= 0) {
            int pos = atomicAdd(&lcur[de[j] >> 8], 1);
            br[pos] = ((unsigned int)(de[j] & 255) << 24) | (unsigned int)se[j];
        }
}

// ---------- per-bucket degree count ----------
__global__ __launch_bounds__(256) void k_bdeg(const unsigned int* br, const int* boff, int* deg) {
    __shared__ int d256[256];
    int b = blockIdx.x;
    int tid = threadIdx.x;
    d256[tid] = 0;
    __syncthreads();
    int lo = boff[b], hi = boff[b + 1];
    for (int i = lo + tid; i < hi; i += 256)
        atomicAdd(&d256[br[i] >> 24], 1);
    __syncthreads();
    int node = (b << 8) + tid;
    if (node < N_NODES) deg[node] = d256[tid];
}

// ---------- scans over deg -> rowptr ----------
__global__ void k_scan1(const int* deg, int* rowptr, int* bsums) {
    __shared__ int sh[256];
    int tid = threadIdx.x;
    int i0 = blockIdx.x * 512 + tid * 2;
    int a = (i0 < N_NODES) ? deg[i0] : 0;
    int b = (i0 + 1 < N_NODES) ? deg[i0 + 1] : 0;
    int ts = a + b;
    sh[tid] = ts;
    __syncthreads();
    for (int off = 1; off < 256; off <<= 1) {
        int v = (tid >= off) ? sh[tid - off] : 0;
        __syncthreads();
        sh[tid] += v;
        __syncthreads();
    }
    int excl = sh[tid] - ts;
    if (i0 < N_NODES) rowptr[i0] = excl;
    if (i0 + 1 < N_NODES) rowptr[i0 + 1] = excl + a;
    if (tid == 255) bsums[blockIdx.x] = sh[255];
}

__global__ void k_scan2(int* bsums, int nb) {
    __shared__ int sh[256];
    int tid = threadIdx.x;
    int v = (tid < nb) ? bsums[tid] : 0;
    sh[tid] = v;
    __syncthreads();
    for (int off = 1; off < 256; off <<= 1) {
        int u = (tid >= off) ? sh[tid - off] : 0;
        __syncthreads();
        sh[tid] += u;
        __syncthreads();
    }
    if (tid < nb) bsums[tid] = sh[tid] - v;
}

__global__ void k_scan3(int* rowptr, const int* bsums, int* cursor) {
    int i = blockIdx.x * blockDim.x + threadIdx.x;
    if (i < N_NODES) {
        int r = rowptr[i] + bsums[i >> 9];
        rowptr[i] = r;
        cursor[i] = r;
    }
    if (i == 0) rowptr[N_NODES] = N_EDGES;
}

// ---------- phase B: per-bucket fine scatter via LDS staging, coalesced writeout ----------
__global__ __launch_bounds__(256) void k_scatter2(const unsigned int* br, const int* boff,
                                                  const int* rowptr, int* cursor, int* col) {
    __shared__ int lcur[256];
    __shared__ int cbuf[SCAP];
    int b = blockIdx.x;
    int tid = threadIdx.x;
    int lo = boff[b], hi = boff[b + 1];
    int wsize = hi - lo;
    int node = (b << 8) + tid;
    lcur[tid] = rowptr[node < N_NODES ? node : N_NODES] - lo;
    __syncthreads();
    if (wsize <= SCAP) {
        for (int i = lo + tid; i < hi; i += 256) {
            unsigned int r = br[i];
            int p = atomicAdd(&lcur[r >> 24], 1);
            cbuf[p] = (int)(r & 0xFFFFFF);
        }
        __syncthreads();
        for (int j = tid; j < wsize; j += 256) col[lo + j] = cbuf[j];
    } else {
        for (int i = lo + tid; i < hi; i += 256) {
            unsigned int r = br[i];
            int d = (b << 8) + (int)(r >> 24);
            int p = atomicAdd(&cursor[d], 1);
            col[p] = (int)(r & 0xFFFFFF);
        }
    }
}

// ---------- weight prep ----------
__global__ void k_prepw(const float* __restrict__ lin_l_w, const float* __restrict__ lin_r_w,
                        const float* __restrict__ gate_w1,
                        __half* __restrict__ W16t, __half* __restrict__ W16g) {
    int i = blockIdx.x * 256 + threadIdx.x;
    if (i < NUM_LAYERS * 128 * 256) {
        int l = i >> 15;
        int rem = i & 32767;
        int n = rem >> 8;
        int k = rem & 255;
        float v = (k < 128) ? lin_l_w[(size_t)l * 16384 + k * 128 + n]
                            : lin_r_w[(size_t)l * 16384 + (k - 128) * 128 + n];
        W16t[(size_t)l * 32768 + n * 256 + k] = __float2half(v);
    } else if (i < NUM_LAYERS * 128 * 256 + 64 * 128) {
        int idx = i - NUM_LAYERS * 128 * 256;
        int n = idx >> 7;      // 0..63
        int k = idx & 127;     // 0..127
        W16g[n * 128 + k] = __float2half(gate_w1[k * 64 + n]);
    }
}

// ---------- tiled fp32 GEMM (COLS=128): h16 = fp16(relu(A[n,K] @ W + bias)) ----------
__global__ __launch_bounds__(256) void k_gemm_proj(const float* __restrict__ A,
                                                   const float* __restrict__ W,
                                                   const float* __restrict__ bias,
                                                   __half* __restrict__ C16,
                                                   int nrows, int K) {
    __shared__ float As_t[32][68];
    __shared__ float Ws[32 * 128];
    int tid = threadIdx.x;
    int row0 = blockIdx.x * 64;
    int tr = tid >> 4;
    int tc = tid & 15;
    int c0 = tc * 8;
    float acc[4][8];
#pragma unroll
    for (int i = 0; i < 4; ++i)
#pragma unroll
        for (int j = 0; j < 8; ++j) acc[i][j] = 0.f;

    for (int kc = 0; kc < K; kc += 32) {
        __syncthreads();
#pragma unroll
        for (int it = 0; it < 2; ++it) {
            int idx = tid + it * 256;
            int r = idx >> 3, c4 = idx & 7;
            int gr = row0 + r;
            float4 v = make_float4(0.f, 0.f, 0.f, 0.f);
            if (gr < nrows) v = *(const float4*)(A + (size_t)gr * K + kc + c4 * 4);
            As_t[c4 * 4 + 0][r] = v.x;
            As_t[c4 * 4 + 1][r] = v.y;
            As_t[c4 * 4 + 2][r] = v.z;
            As_t[c4 * 4 + 3][r] = v.w;
        }
#pragma unroll
        for (int it = 0; it < 4; ++it) {
            int idx = tid + it * 256;
            int r = idx >> 5, c4 = idx & 31;
            *(float4*)(&Ws[r * 128 + c4 * 4]) = *(const float4*)(W + (size_t)(kc + r) * 128 + c4 * 4);
        }
        __syncthreads();
#pragma unroll
        for (int k = 0; k < 32; ++k) {
            float4 a4 = *(const float4*)(&As_t[k][tr * 4]);
            float a[4] = {a4.x, a4.y, a4.z, a4.w};
            float4 w0 = *(const float4*)(&Ws[k * 128 + c0]);
            float4 w1 = *(const float4*)(&Ws[k * 128 + c0 + 4]);
            float w[8] = {w0.x, w0.y, w0.z, w0.w, w1.x, w1.y, w1.z, w1.w};
#pragma unroll
            for (int i = 0; i < 4; ++i)
#pragma unroll
                for (int j = 0; j < 8; ++j) acc[i][j] += a[i] * w[j];
        }
    }
    float bv[8];
#pragma unroll
    for (int j = 0; j < 8; ++j) bv[j] = bias[c0 + j];
#pragma unroll
    for (int i = 0; i < 4; ++i) {
        int gr = row0 + tr * 4 + i;
        if (gr < nrows) {
            float o[8];
#pragma unroll
            for (int j = 0; j < 8; ++j) o[j] = fmaxf(acc[i][j] + bv[j], 0.f);
            __half2 p[4];
#pragma unroll
            for (int j = 0; j < 8; j += 2) p[j / 2] = __floats2half2_rn(o[j], o[j + 1]);
            *(float4*)(C16 + (size_t)gr * 128 + c0) = *(float4*)p;
        }
    }
}

// ---------- MFMA gate (LDS-B): gate[n] = relu(h16[n,:]@W16g^T + b1) . w2 + b2 ----------
__global__ __launch_bounds__(256) void k_gate_mfma(const __half* __restrict__ h16,
                                                   const __half* __restrict__ W16g,
                                                   const float* __restrict__ b1,
                                                   const float* __restrict__ w2,
                                                   const float* __restrict__ b2,
                                                   float* __restrict__ gate) {
    __shared__ __half Bs[64 * BPAD];
    int tid = threadIdx.x;
    int wave = tid >> 6, lane = tid & 63;
    int s = lane & 15, quad = lane >> 4;
    int row0 = blockIdx.x * 64 + wave * 16;
    int arow = row0 + s;
    if (arow >= N_NODES) arow = N_NODES - 1;

    // stage W16g (64 rows x 128 halves) into LDS, padded stride
#pragma unroll
    for (int it = 0; it < 4; ++it) {
        int idx = tid + it * 256;
        int n = idx >> 4, ch = idx & 15;
        *(float4*)(&Bs[n * BPAD + ch * 8]) = *(const float4*)(W16g + (size_t)n * 128 + ch * 8);
    }
    __syncthreads();

    f32x4 acc[4];
#pragma unroll
    for (int c = 0; c < 4; ++c) acc[c] = (f32x4){0.f, 0.f, 0.f, 0.f};

    const __half* aptr = h16 + (size_t)arow * H;
#pragma unroll
    for (int kc = 0; kc < 128; kc += 32) {
        f16x8 afrag = *(const f16x8*)(aptr + kc + quad * 8);
#pragma unroll
        for (int c = 0; c < 4; ++c) {
            f16x8 bfrag = *(const f16x8*)(&Bs[(c * 16 + s) * BPAD + kc + quad * 8]);
            acc[c] = __builtin_amdgcn_mfma_f32_16x16x32_f16(afrag, bfrag, acc[c], 0, 0, 0);
        }
    }
    float part[4] = {0.f, 0.f, 0.f, 0.f};
#pragma unroll
    for (int c = 0; c < 4; ++c) {
        float bv = b1[c * 16 + s];
        float wv = w2[c * 16 + s];
#pragma unroll
        for (int i = 0; i < 4; ++i)
            part[i] += fmaxf(acc[c][i] + bv, 0.f) * wv;
    }
#pragma unroll
    for (int off = 1; off < 16; off <<= 1) {
#pragma unroll
        for (int i = 0; i < 4; ++i) part[i] += __shfl_xor(part[i], off);
    }
    if (s == 0) {
        float b2v = b2[0];
#pragma unroll
        for (int i = 0; i < 4; ++i) {
            int r = row0 + quad * 4 + i;
            if (r < N_NODES) gate[r] = part[i] + b2v;
        }
    }
}

// ---------- per-graph softmax over sorted batch ----------
__global__ __launch_bounds__(64) void k_softmax_g(float* __restrict__ gate,
                                                  const int* __restrict__ batch32,
                                                  float* __restrict__ gsum) {
    int g = blockIdx.x;
    int lane = threadIdx.x;
    int n0 = lower_bound(batch32, N_NODES, g);
    int n1 = lower_bound(batch32, N_NODES, g + 1);
    float m = -INFINITY;
    for (int n = n0 + lane; n < n1; n += 64) m = fmaxf(m, gate[n]);
#pragma unroll
    for (int off = 32; off >= 1; off >>= 1) m = fmaxf(m, __shfl_xor(m, off));
    float s = 0.f;
    for (int n = n0 + lane; n < n1; n += 64) {
        float e = expf(gate[n] - m);
        gate[n] = e;
        s += e;
    }
#pragma unroll
    for (int off = 32; off >= 1; off >>= 1) s += __shfl_xor(s, off);
    if (lane == 0) gsum[g] = s;
}

// ---------- per-graph pooling (no atomics) ----------
__global__ __launch_bounds__(256) void k_pool_g(const __half* __restrict__ h16,
                                                const float* __restrict__ eg,
                                                const float* __restrict__ gsum,
                                                const int* __restrict__ batch32,
                                                float* __restrict__ pooled) {
    __shared__ float sacc[256];
    int g = blockIdx.x;
    int tid = threadIdx.x;
    int c = tid & 127;
    int p = tid >> 7;
    int n0 = lower_bound(batch32, N_NODES, g);
    int n1 = lower_bound(batch32, N_NODES, g + 1);
    float acc = 0.f;
    for (int n = n0 + p; n < n1; n += 2)
        acc += eg[n] * __half2float(h16[(size_t)n * H + c]);
    sacc[tid] = acc;
    __syncthreads();
    if (tid < 128) {
        float s = gsum[g];
        float v = sacc[tid] + sacc[tid + 128];
        pooled[(size_t)g * H + tid] = (n1 > n0) ? v / s : 0.f;
    }
}

// ---------- MFMA fused SAGE layer (LDS-B, staged epilogue) ----------
// h16 = fp16(elu(LN([t16|h16]@[Wl;Wr] + bl)) + h16)
__global__ __launch_bounds__(256) void k_layer_mfma(const __half* __restrict__ t16,
                                                    __half* __restrict__ h16,
                                                    const __half* __restrict__ W16t,
                                                    const float* __restrict__ bl,
                                                    const float* __restrict__ g,
                                                    const float* __restrict__ bb) {
    __shared__ __half Bs[128 * BPAD];   // 34816 B; B-tile, then reused as output staging
    int tid = threadIdx.x;
    int wave = tid >> 6, lane = tid & 63;
    int s = lane & 15, quad = lane >> 4;
    int row0 = blockIdx.x * 64;
    int wrow0 = row0 + wave * 16;
    int arow = wrow0 + s;
    if (arow >= N_NODES) arow = N_NODES - 1;

    f32x4 acc[8];
#pragma unroll
    for (int c = 0; c < 8; ++c) acc[c] = (f32x4){0.f, 0.f, 0.f, 0.f};

#pragma unroll
    for (int ph = 0; ph < 2; ++ph) {
        __syncthreads();
        // stage 128x128-half phase of [Wl;Wr] (W16t[n*256 + ph*128 + k])
#pragma unroll
        for (int it = 0; it < 8; ++it) {
            int idx = tid + it * 256;
            int n = idx >> 4, ch = idx & 15;
            *(float4*)(&Bs[n * BPAD + ch * 8]) =
                *(const float4*)(W16t + (size_t)n * 256 + ph * 128 + ch * 8);
        }
        __syncthreads();
        const __half* aptr = (ph ? h16 : t16) + (size_t)arow * H;
#pragma unroll
        for (int kk = 0; kk < 128; kk += 32) {
            f16x8 afrag = *(const f16x8*)(aptr + kk + quad * 8);
#pragma unroll
            for (int c = 0; c < 8; ++c) {
                f16x8 bfrag = *(const f16x8*)(&Bs[(c * 16 + s) * BPAD + kk + quad * 8]);
                acc[c] = __builtin_amdgcn_mfma_f32_16x16x32_f16(afrag, bfrag, acc[c], 0, 0, 0);
            }
        }
    }

    // bias + LN stats (per row = quad*4+i within the wave's 16 rows)
    float y[8][4];
    float sm[4] = {0.f, 0.f, 0.f, 0.f}, sq[4] = {0.f, 0.f, 0.f, 0.f};
#pragma unroll
    for (int c = 0; c < 8; ++c) {
        float bv = bl[c * 16 + s];
#pragma unroll
        for (int i = 0; i < 4; ++i) {
            float v = acc[c][i] + bv;
            y[c][i] = v;
            sm[i] += v;
            sq[i] += v * v;
        }
    }
#pragma unroll
    for (int off = 1; off < 16; off <<= 1) {
#pragma unroll
        for (int i = 0; i < 4; ++i) {
            sm[i] += __shfl_xor(sm[i], off);
            sq[i] += __shfl_xor(sq[i], off);
        }
    }
    float mean[4], rstd[4];
#pragma unroll
    for (int i = 0; i < 4; ++i) {
        mean[i] = sm[i] * (1.0f / H);
        float var = sq[i] * (1.0f / H) - mean[i] * mean[i];
        rstd[i] = rsqrtf(var + LN_EPS);
    }
    float gv[8], bbv[8];
#pragma unroll
    for (int c = 0; c < 8; ++c) { gv[c] = g[c * 16 + s]; bbv[c] = bb[c * 16 + s]; }

    __syncthreads();   // all waves done reading Bs; reuse as output staging
#pragma unroll
    for (int i = 0; i < 4; ++i) {
        int lr = wave * 16 + quad * 4 + i;   // local row 0..63
#pragma unroll
        for (int c = 0; c < 8; ++c) {
            float yv = (y[c][i] - mean[i]) * rstd[i] * gv[c] + bbv[c];
            yv = yv > 0.f ? yv : expf(yv) - 1.f;
            Bs[lr * BPAD + c * 16 + s] = __float2half(yv);
        }
    }
    __syncthreads();
    // coalesced residual add + writeback
#pragma unroll
    for (int it = 0; it < 4; ++it) {
        int idx = tid + it * 256;            // 0..1023
        int r = idx >> 4, ch = idx & 15;
        int grow = row0 + r;
        if (grow < N_NODES) {
            float4 sv = *(float4*)(&Bs[r * BPAD + ch * 8]);
            float4 hv = *(const float4*)(h16 + (size_t)grow * H + ch * 8);
            __half2* pa = (__half2*)&sv;
            const __half2* pb = (const __half2*)&hv;
#pragma unroll
            for (int j = 0; j < 4; ++j) {
                float2 fa = __half22float2(pa[j]);
                float2 fb = __half22float2(pb[j]);
                pa[j] = __floats2half2_rn(fa.x + fb.x, fa.y + fb.y);
            }
            *(float4*)(h16 + (size_t)grow * H + ch * 8) = sv;
        }
    }
}

// ---------- mean aggregation: wave per node, 32-lane groups, 4 edges in flight each ----------
__global__ __launch_bounds__(256) void k_aggr(const __half* __restrict__ h16,
                                              const int* __restrict__ rowptr,
                                              const int* __restrict__ col,
                                              __half* __restrict__ t16) {
    int lane = threadIdx.x & 63;
    int node = blockIdx.x * 4 + (threadIdx.x >> 6);
    if (node >= N_NODES) return;
    int li = lane & 31;       // covers cols 4li..4li+3 (8 B)
    int pg = lane >> 5;       // edge-parity group
    int e0 = rowptr[node], e1 = rowptr[node + 1];
    float a0[4] = {0.f, 0.f, 0.f, 0.f};
    float b0[4] = {0.f, 0.f, 0.f, 0.f};
    float c0[4] = {0.f, 0.f, 0.f, 0.f};
    float d0[4] = {0.f, 0.f, 0.f, 0.f};
    int e = e0;
    for (; e + 7 < e1; e += 8) {
        int sA = col[e + pg];
        int sB = col[e + 2 + pg];
        int sC = col[e + 4 + pg];
        int sD = col[e + 6 + pg];
        float2 rA = *(const float2*)(h16 + (size_t)sA * H + li * 4);
        float2 rB = *(const float2*)(h16 + (size_t)sB * H + li * 4);
        float2 rC = *(const float2*)(h16 + (size_t)sC * H + li * 4);
        float2 rD = *(const float2*)(h16 + (size_t)sD * H + li * 4);
        const __half2* hA = (const __half2*)&rA;
        const __half2* hB = (const __half2*)&rB;
        const __half2* hC = (const __half2*)&rC;
        const __half2* hD = (const __half2*)&rD;
        float2 f0, f1;
        f0 = __half22float2(hA[0]); f1 = __half22float2(hA[1]);
        a0[0] += f0.x; a0[1] += f0.y; a0[2] += f1.x; a0[3] += f1.y;
        f0 = __half22float2(hB[0]); f1 = __half22float2(hB[1]);
        b0[0] += f0.x; b0[1] += f0.y; b0[2] += f1.x; b0[3] += f1.y;
        f0 = __half22float2(hC[0]); f1 = __half22float2(hC[1]);
        c0[0] += f0.x; c0[1] += f0.y; c0[2] += f1.x; c0[3] += f1.y;
        f0 = __half22float2(hD[0]); f1 = __half22float2(hD[1]);
        d0[0] += f0.x; d0[1] += f0.y; d0[2] += f1.x; d0[3] += f1.y;
    }
    for (; e + 3 < e1; e += 4) {
        int sA = col[e + pg];
        int sB = col[e + 2 + pg];
        float2 rA = *(const float2*)(h16 + (size_t)sA * H + li * 4);
        float2 rB = *(const float2*)(h16 + (size_t)sB * H + li * 4);
        const __half2* hA = (const __half2*)&rA;
        const __half2* hB = (const __half2*)&rB;
        float2 f0, f1;
        f0 = __half22float2(hA[0]); f1 = __half22float2(hA[1]);
        a0[0] += f0.x; a0[1] += f0.y; a0[2] += f1.x; a0[3] += f1.y;
        f0 = __half22float2(hB[0]); f1 = __half22float2(hB[1]);
        b0[0] += f0.x; b0[1] += f0.y; b0[2] += f1.x; b0[3] += f1.y;
    }
    for (; e + 1 < e1; e += 2) {
        int sA = col[e + pg];
        float2 rA = *(const float2*)(h16 + (size_t)sA * H + li * 4);
        const __half2* hA = (const __half2*)&rA;
        float2 f0 = __half22float2(hA[0]), f1 = __half22float2(hA[1]);
        a0[0] += f0.x; a0[1] += f0.y; a0[2] += f1.x; a0[3] += f1.y;
    }
    if (e < e1 && pg == 0) {
        int sA = col[e];
        float2 rA = *(const float2*)(h16 + (size_t)sA * H + li * 4);
        const __half2* hA = (const __half2*)&rA;
        float2 f0 = __half22float2(hA[0]), f1 = __half22float2(hA[1]);
        a0[0] += f0.x; a0[1] += f0.y; a0[2] += f1.x; a0[3] += f1.y;
    }
#pragma unroll
    for (int j = 0; j < 4; ++j) a0[j] += b0[j] + c0[j] + d0[j];
#pragma unroll
    for (int j = 0; j < 4; ++j) a0[j] += __shfl_xor(a0[j], 32);
    if (pg == 0) {
        int d = e1 - e0;
        float inv = 1.0f / (float)(d > 1 ? d : 1);
        __half2 h01 = __floats2half2_rn(a0[0] * inv, a0[1] * inv);
        __half2 h23 = __floats2half2_rn(a0[2] * inv, a0[3] * inv);
        float2 o;
        ((__half2*)&o)[0] = h01;
        ((__half2*)&o)[1] = h23;
        *(float2*)(t16 + (size_t)node * H + li * 4) = o;
    }
}

// ---------- classifier ----------
__global__ __launch_bounds__(64) void k_cls(const float* __restrict__ pooled,
                                            const float* __restrict__ w1,
                                            const float* __restrict__ b1,
                                            const float* __restrict__ w2,
                                            const float* __restrict__ b2,
                                            float* __restrict__ out) {
    __shared__ float sp[64];
    int g = blockIdx.x;
    int lane = threadIdx.x;
    float r0 = pooled[(size_t)g * H + lane];
    float r1 = pooled[(size_t)g * H + 64 + lane];
    float acc = b1[lane];
#pragma unroll 16
    for (int k = 0; k < 64; ++k) acc += __shfl(r0, k) * w1[k * 64 + lane];
#pragma unroll 16
    for (int k = 0; k < 64; ++k) acc += __shfl(r1, k) * w1[(64 + k) * 64 + lane];
    sp[lane] = fmaxf(acc, 0.f);
    __syncthreads();
    if (lane < NUM_CLASSES) {
        float o = b2[lane];
        for (int c = 0; c < 64; ++c) o += sp[c] * w2[c * NUM_CLASSES + lane];
        out[g * NUM_CLASSES + lane] = o;
    }
}

extern "C" void kernel_launch(void* const* d_in, const int* in_sizes, int n_in,
                              void* d_out, int out_size, void* d_ws, size_t ws_size,
                              hipStream_t stream) {
    const float* x       = (const float*)d_in[0];
    const int*   eraw    = (const int*)d_in[1];
    const int*   braw    = (const int*)d_in[2];
    const float* proj_w  = (const float*)d_in[3];
    const float* proj_b  = (const float*)d_in[4];
    const float* lin_l_w = (const float*)d_in[5];
    const float* lin_l_b = (const float*)d_in[6];
    const float* lin_r_w = (const float*)d_in[7];
    const float* ln_g    = (const float*)d_in[8];
    const float* ln_b    = (const float*)d_in[9];
    const float* gate_w1 = (const float*)d_in[10];
    const float* gate_b1 = (const float*)d_in[11];
    const float* gate_w2 = (const float*)d_in[12];
    const float* gate_b2 = (const float*)d_in[13];
    const float* cls_w1  = (const float*)d_in[14];
    const float* cls_b1  = (const float*)d_in[15];
    const float* cls_w2  = (const float*)d_in[16];
    const float* cls_b2  = (const float*)d_in[17];
    float* out = (float*)d_out;

    // workspace layout
    __half* h16    = (__half*)d_ws;                       // N*H f16
    __half* t16    = h16 + (size_t)N_NODES * H;           // N*H f16
    float*  gate   = (float*)(t16 + (size_t)N_NODES * H); // N
    float*  gsum   = gate + N_NODES;                      // 512
    float*  pooled = gsum + NUM_GRAPHS;                   // 512*H
    __half* W16t   = (__half*)(pooled + NUM_GRAPHS * H);  // 3*128*256
    __half* W16g   = W16t + (size_t)NUM_LAYERS * 32768;   // 64*128
    int* flags     = (int*)(W16g + 64 * 128);             // 4
    int* col       = flags + 4;                           // E
    int* batch32   = col + N_EDGES;                       // N
    int* deg       = batch32 + N_NODES;                   // N
    int* rowptr    = deg + N_NODES;                       // N+1
    int* cursor    = rowptr + N_NODES + 1;                // N
    int* bsums     = cursor + N_NODES;                    // 256
    int* bcnt      = bsums + 256;                         // 512
    int* boff      = bcnt + 512;                          // 513
    int* bcursor   = boff + 513;                          // 512
    unsigned int* br = (unsigned int*)(bcursor + 512);    // E packed records

    const int nbN = (N_NODES + 255) / 256;
    const int nbE4 = (N_EDGES + EPB - 1) / EPB;           // 391
    const int nbS = (N_NODES + 511) / 512;                // 196
    const int nbW = (N_NODES + 3) / 4;
    const int nbG = (N_NODES + 63) / 64;                  // 1563
    const int nbP = (NUM_LAYERS * 128 * 256 + 64 * 128 + 255) / 256;

    k_detect<<<1, 1, 0, stream>>>(eraw, braw, flags);
    k_init<<<2, 256, 0, stream>>>(bcnt);
    k_conv_batch<<<nbN, 256, 0, stream>>>(braw, flags, batch32);
    // CSR build (bucketed)
    k_bhist<<<512, 256, 0, stream>>>(eraw, flags, bcnt);
    k_bscan<<<1, 512, 0, stream>>>(bcnt, boff, bcursor);
    k_bucket<<<nbE4, 256, 0, stream>>>(eraw, flags, bcursor, br);
    k_bdeg<<<NBKT, 256, 0, stream>>>(br, boff, deg);
    k_scan1<<<nbS, 256, 0, stream>>>(deg, rowptr, bsums);
    k_scan2<<<1, 256, 0, stream>>>(bsums, nbS);
    k_scan3<<<nbN, 256, 0, stream>>>(rowptr, bsums, cursor);
    k_scatter2<<<NBKT, 256, 0, stream>>>(br, boff, rowptr, cursor, col);
    // weights to fp16 transposed
    k_prepw<<<nbP, 256, 0, stream>>>(lin_l_w, lin_r_w, gate_w1, W16t, W16g);

    // h16 = fp16(relu(x @ proj_w + proj_b))
    k_gemm_proj<<<nbG, 256, 0, stream>>>(x, proj_w, proj_b, h16, N_NODES, NDIM);

    for (int l = 0; l < NUM_LAYERS; ++l) {
        const float* bl  = lin_l_b + (size_t)l * H;
        const float* gl  = ln_g + (size_t)l * H;
        const float* blb = ln_b + (size_t)l * H;
        k_aggr<<<nbW, 256, 0, stream>>>(h16, rowptr, col, t16);
        k_layer_mfma<<<nbG, 256, 0, stream>>>(t16, h16, W16t + (size_t)l * 32768, bl, gl, blb);
    }

    // gate -> per-graph softmax -> per-graph pooling -> classifier
    k_gate_mfma<<<nbG, 256, 0, stream>>>(h16, W16g, gate_b1, gate_w2, gate_b2, gate);
    k_softmax_g<<<NUM_GRAPHS, 64, 0, stream>>>(gate, batch32, gsum);
    k_pool_g<<<NUM_GRAPHS, 256, 0, stream>>>(h16, gate, gsum, batch32, pooled);
    k_cls<<<NUM_GRAPHS, 64, 0, stream>>>(pooled, cls_w1, cls_b1, cls_w2, cls_b2, out);
}